// Round 1
// baseline (306.822 us; speedup 1.0000x reference)
//
#include <hip/hip_runtime.h>
#include <math.h>

#define LL 2048
#define HH 256
#define BB 8
#define NN 64
#define HN (HH*NN)      // 16384
#define ELEMS (BB*HH*LL) // 4194304

// ---------------- setup: tt[b,h] and per-(h,n) complex params ----------------
__global__ __launch_bounds__(256) void setup_kernel(
    const float* __restrict__ t, const float* __restrict__ W_t, const float* __restrict__ b_t,
    const float* __restrict__ log_dt, const float* __restrict__ log_A_real, const float* __restrict__ A_imag,
    const float* __restrict__ B_re, const float* __restrict__ B_im,
    const float* __restrict__ C_re, const float* __restrict__ C_im,
    float* __restrict__ P, float* __restrict__ tt) {
  int blk = blockIdx.x;
  int tid = threadIdx.x;
  if (blk < BB) {
    int b = blk, h = tid;
    float s = b_t[h];
    const float* trow = t + b*HH;
    const float* wrow = W_t + h*HH;
    for (int c = 0; c < HH; ++c) s = fmaf(trow[c], wrow[c], s);
    tt[b*HH + h] = s;
  } else {
    int gid = (blk - BB)*256 + tid;   // 0..HN-1  (= h*64+n)
    int h = gid >> 6;
    float dt  = expf(log_dt[h]);
    float are = -expf(log_A_real[gid]);
    float aim = A_imag[gid];
    float dre = dt*are, dim = dt*aim;
    float e = expf(dre);
    float rre = e * cosf(dim);
    float rim = e * sinf(dim);
    // dB = B * (r-1)/A
    float inv  = 1.0f / (are*are + aim*aim);
    float m_re = rre - 1.0f, m_im = rim;
    float q_re = (m_re*are + m_im*aim) * inv;
    float q_im = (m_im*are - m_re*aim) * inv;
    float bre = B_re[gid], bim = B_im[gid];
    float db_re = q_re*bre - q_im*bim;
    float db_im = q_re*bim + q_im*bre;
    float c0r = C_re[gid],      c0i = C_im[gid];
    float c1r = C_re[HN + gid], c1i = C_im[HN + gid];
    P[gid]        = rre;
    P[HN + gid]   = rim;
    P[2*HN + gid] = 2.0f*(c0r*db_re - c0i*db_im);
    P[3*HN + gid] = 2.0f*(c0r*db_im + c0i*db_re);
    P[4*HN + gid] = 2.0f*(c1r*db_re - c1i*db_im);
    P[5*HN + gid] = 2.0f*(c1r*db_im + c1i*db_re);
  }
}

// ---------------- LayerNorm stats over channel dim ----------------
__global__ __launch_bounds__(256) void stats_kernel(
    const float* __restrict__ x, const float* __restrict__ tt,
    float* __restrict__ mu, float* __restrict__ rstd) {
  int b = blockIdx.x >> 3;
  int l = ((blockIdx.x & 7) * 256) + threadIdx.x;
  float s = 0.f, s2 = 0.f;
  for (int h = 0; h < HH; ++h) {
    float v = x[(b*HH + h)*LL + l] + tt[b*HH + h];
    s += v; s2 = fmaf(v, v, s2);
  }
  float m = s * (1.0f/HH);
  float var = s2 * (1.0f/HH) - m*m;
  mu[b*LL + l]   = m;
  rstd[b*LL + l] = 1.0f / sqrtf(var + 1e-5f);
}

// ---------------- z = LN(x + tt) ----------------
__global__ __launch_bounds__(256) void z_kernel(
    const float* __restrict__ x, const float* __restrict__ tt,
    const float* __restrict__ mu, const float* __restrict__ rstd,
    const float* __restrict__ ln_g, const float* __restrict__ ln_b,
    float* __restrict__ z) {
  int i = blockIdx.x*256 + threadIdx.x;
  int l = i & (LL-1);
  int h = (i >> 11) & (HH-1);
  int b = i >> 19;
  float v = x[i] + tt[b*HH + h];
  z[i] = (v - mu[b*LL + l]) * rstd[b*LL + l] * ln_g[h] + ln_b[h];
}

// ---------------- bidirectional diagonal-SSM scan ----------------
// one 64-lane wave per (b,h,dir); lane = complex state n
__global__ __launch_bounds__(64) void scan_kernel(
    const float* __restrict__ z, const float* __restrict__ P,
    float* __restrict__ yf, float* __restrict__ yb) {
  int blk = blockIdx.x;
  int dir = blk & 1;
  int pair = blk >> 1;       // 0..B*H-1
  int h = pair & (HH-1);
  int b = pair >> 8;
  int lane = threadIdx.x;
  int idx = h*NN + lane;
  float rre = P[idx], rim = P[HN+idx];
  float wre, wim;
  if (dir == 0) { wre = P[2*HN+idx]; wim = P[3*HN+idx]; }
  else          { wre = P[4*HN+idx]; wim = P[5*HN+idx]; }
  const float* zrow = z + (b*HH + h)*LL;
  float* yrow = (dir==0 ? yf : yb) + (b*HH + h)*LL;
  __shared__ float zt[64];
  __shared__ float acc[64][65];
  float sre = 0.f, sim = 0.f;
  if (dir == 0) {
    for (int c = 0; c < LL/64; ++c) {
      int l0 = c*64;
      zt[lane] = zrow[l0+lane];
      __syncthreads();
      #pragma unroll
      for (int t = 0; t < 64; ++t) {
        float zv = zt[t];
        float nre = fmaf(rre, sre, fmaf(-rim, sim, zv));
        float nim = fmaf(rre, sim, rim*sre);
        sre = nre; sim = nim;
        acc[t][lane] = fmaf(wre, sre, -(wim*sim));
      }
      __syncthreads();
      float tot = 0.f;
      #pragma unroll
      for (int n = 0; n < 64; ++n) tot += acc[lane][n];
      yrow[l0+lane] = tot;
      __syncthreads();
    }
  } else {
    for (int c = LL/64 - 1; c >= 0; --c) {
      int l0 = c*64;
      zt[lane] = zrow[l0+lane];
      __syncthreads();
      #pragma unroll
      for (int t = 63; t >= 0; --t) {
        acc[t][lane] = fmaf(wre, sre, -(wim*sim));   // output BEFORE update (strictly anticausal)
        float zv = zt[t];
        float nre = fmaf(rre, sre, fmaf(-rim, sim, zv));
        float nim = fmaf(rre, sim, rim*sre);
        sre = nre; sim = nim;
      }
      __syncthreads();
      float tot = 0.f;
      #pragma unroll
      for (int n = 0; n < 64; ++n) tot += acc[lane][n];
      yrow[l0+lane] = tot;
      __syncthreads();
    }
  }
}

// ---------------- y = yf + yb + z*D ; exact GELU (in-place over z) ----------------
__global__ __launch_bounds__(256) void combine_kernel(
    const float* __restrict__ yf, const float* __restrict__ ybk,
    float* __restrict__ z, const float* __restrict__ Dp) {
  int i = blockIdx.x*256 + threadIdx.x;
  int h = (i >> 11) & (HH-1);
  float y = yf[i] + ybk[i] + z[i]*Dp[h];
  z[i] = 0.5f * y * (1.0f + erff(y * 0.70710678118654752f));
}

// ---------------- 64x64-tile fp32 GEMM: Out[b,o,l] = act(sum_h W[o,h]*In[b,h,l] + bias + ...) ----
// mode 0: + x + tt, then tanh*sigmoid gate   (W_out)
// mode 1: + x                                 (W1)
// mode 2: plain                               (W2)
__global__ __launch_bounds__(256) void gemm_kernel(
    const float* __restrict__ In, const float* __restrict__ W,
    const float* __restrict__ bias, const float* __restrict__ x,
    const float* __restrict__ tt, float* __restrict__ Out, int mode) {
  __shared__ float Ws[16][64];
  __shared__ float Is[16][64];
  int l0 = blockIdx.x * 64;
  int o0 = blockIdx.y * 64;
  int b  = blockIdx.z;
  int tid = threadIdx.x;
  int tl = (tid & 15) * 4;
  int to = (tid >> 4) * 4;
  float acc[4][4] = {};
  for (int k0 = 0; k0 < HH; k0 += 16) {
    {
      int o = tid >> 2, kq = (tid & 3)*4;
      const float4 wv = *reinterpret_cast<const float4*>(W + (o0+o)*HH + k0 + kq);
      Ws[kq+0][o] = wv.x; Ws[kq+1][o] = wv.y; Ws[kq+2][o] = wv.z; Ws[kq+3][o] = wv.w;
      int k = tid >> 4, lq = (tid & 15)*4;
      *reinterpret_cast<float4*>(&Is[k][lq]) =
        *reinterpret_cast<const float4*>(In + (b*HH + k0 + k)*LL + l0 + lq);
    }
    __syncthreads();
    #pragma unroll
    for (int kk = 0; kk < 16; ++kk) {
      float wv[4], iv[4];
      #pragma unroll
      for (int i = 0; i < 4; ++i) { wv[i] = Ws[kk][to+i]; iv[i] = Is[kk][tl+i]; }
      #pragma unroll
      for (int i = 0; i < 4; ++i)
        #pragma unroll
        for (int j = 0; j < 4; ++j)
          acc[i][j] = fmaf(wv[i], iv[j], acc[i][j]);
    }
    __syncthreads();
  }
  #pragma unroll
  for (int i = 0; i < 4; ++i) {
    int o = o0 + to + i;
    float bv = bias[o];
    float4 xv = make_float4(0.f,0.f,0.f,0.f);
    if (mode == 0 || mode == 1)
      xv = *reinterpret_cast<const float4*>(x + (b*HH + o)*LL + l0 + tl);
    float ttv = (mode == 0) ? tt[b*HH + o] : 0.f;
    float4 ov;
    #pragma unroll
    for (int j = 0; j < 4; ++j) {
      float v = acc[i][j] + bv;
      float xj = (&xv.x)[j];
      if (mode == 0) {
        v += xj + ttv;
        v = tanhf(v) * (1.0f/(1.0f+expf(-v)));
      } else if (mode == 1) {
        v += xj;
      }
      (&ov.x)[j] = v;
    }
    *reinterpret_cast<float4*>(&Out[(b*HH + o)*LL + l0 + tl]) = ov;
  }
}

extern "C" void kernel_launch(void* const* d_in, const int* in_sizes, int n_in,
                              void* d_out, int out_size, void* d_ws, size_t ws_size,
                              hipStream_t stream) {
  const float* x    = (const float*)d_in[0];
  const float* t    = (const float*)d_in[1];
  const float* W_t  = (const float*)d_in[2];
  const float* b_t  = (const float*)d_in[3];
  const float* ln_g = (const float*)d_in[4];
  const float* ln_b = (const float*)d_in[5];
  const float* log_dt = (const float*)d_in[6];
  const float* log_A_real = (const float*)d_in[7];
  const float* A_imag = (const float*)d_in[8];
  const float* B_re = (const float*)d_in[9];
  const float* B_im = (const float*)d_in[10];
  const float* C_re = (const float*)d_in[11];
  const float* C_im = (const float*)d_in[12];
  const float* Dp   = (const float*)d_in[13];
  const float* W_out= (const float*)d_in[14];
  const float* b_out= (const float*)d_in[15];
  const float* W1   = (const float*)d_in[16];
  const float* b1   = (const float*)d_in[17];
  const float* W2   = (const float*)d_in[18];
  const float* b2   = (const float*)d_in[19];

  // compact ws layout (~17.4 MB): params | tt | mu | rstd | zb (z -> y -> out2 staging)
  float* P    = (float*)d_ws;
  float* tt   = P + 6*HN;
  float* mu   = tt + BB*HH;
  float* rstd = mu + BB*LL;
  float* zb   = rstd + BB*LL;

  float* out1 = (float*)d_out;
  float* out2 = out1 + ELEMS;
  float* yf   = out1;   // scan scratch (overwritten later by real outputs)
  float* ybk  = out2;
  float* gbuf = out2;   // g lives in out2 region until the last GEMM

  setup_kernel<<<BB + HN/256, 256, 0, stream>>>(t, W_t, b_t, log_dt, log_A_real, A_imag,
                                                B_re, B_im, C_re, C_im, P, tt);
  stats_kernel<<<BB*(LL/256), 256, 0, stream>>>(x, tt, mu, rstd);
  z_kernel<<<ELEMS/256, 256, 0, stream>>>(x, tt, mu, rstd, ln_g, ln_b, zb);
  scan_kernel<<<BB*HH*2, 64, 0, stream>>>(zb, P, yf, ybk);
  combine_kernel<<<ELEMS/256, 256, 0, stream>>>(yf, ybk, zb, Dp);          // zb now holds gelu(y)
  gemm_kernel<<<dim3(LL/64, HH/64, BB), 256, 0, stream>>>(zb, W_out, b_out, x, tt, gbuf, 0); // g -> out2 region
  gemm_kernel<<<dim3(LL/64, HH/64, BB), 256, 0, stream>>>(gbuf, W1, b1, x, tt, out1, 1);     // out1 final
  gemm_kernel<<<dim3(LL/64, HH/64, BB), 256, 0, stream>>>(gbuf, W2, b2, x, tt, zb, 2);       // out2 -> ws
  hipMemcpyAsync(out2, zb, (size_t)ELEMS*sizeof(float), hipMemcpyDeviceToDevice, stream);
}

// Round 2
// 288.289 us; speedup vs baseline: 1.0643x; 1.0643x over previous
//
#include <hip/hip_runtime.h>
#include <math.h>

#define LL 2048
#define HH 256
#define BB 8
#define NN 64
#define HN (HH*NN)      // 16384
#define ELEMS (BB*HH*LL) // 4194304

// ---------------- setup: tt[b,h] and per-(h,n) complex params ----------------
__global__ __launch_bounds__(256) void setup_kernel(
    const float* __restrict__ t, const float* __restrict__ W_t, const float* __restrict__ b_t,
    const float* __restrict__ log_dt, const float* __restrict__ log_A_real, const float* __restrict__ A_imag,
    const float* __restrict__ B_re, const float* __restrict__ B_im,
    const float* __restrict__ C_re, const float* __restrict__ C_im,
    float* __restrict__ P, float* __restrict__ tt) {
  int blk = blockIdx.x;
  int tid = threadIdx.x;
  if (blk < BB) {
    int b = blk, h = tid;
    float s = b_t[h];
    const float* trow = t + b*HH;
    const float* wrow = W_t + h*HH;
    for (int c = 0; c < HH; ++c) s = fmaf(trow[c], wrow[c], s);
    tt[b*HH + h] = s;
  } else {
    int gid = (blk - BB)*256 + tid;   // 0..HN-1  (= h*64+n)
    int h = gid >> 6;
    float dt  = expf(log_dt[h]);
    float are = -expf(log_A_real[gid]);
    float aim = A_imag[gid];
    float dre = dt*are, dim = dt*aim;
    float e = expf(dre);
    float rre = e * cosf(dim);
    float rim = e * sinf(dim);
    // dB = B * (r-1)/A
    float inv  = 1.0f / (are*are + aim*aim);
    float m_re = rre - 1.0f, m_im = rim;
    float q_re = (m_re*are + m_im*aim) * inv;
    float q_im = (m_im*are - m_re*aim) * inv;
    float bre = B_re[gid], bim = B_im[gid];
    float db_re = q_re*bre - q_im*bim;
    float db_im = q_re*bim + q_im*bre;
    float c0r = C_re[gid],      c0i = C_im[gid];
    float c1r = C_re[HN + gid], c1i = C_im[HN + gid];
    P[gid]        = rre;
    P[HN + gid]   = rim;
    P[2*HN + gid] = 2.0f*(c0r*db_re - c0i*db_im);
    P[3*HN + gid] = 2.0f*(c0r*db_im + c0i*db_re);
    P[4*HN + gid] = 2.0f*(c1r*db_re - c1i*db_im);
    P[5*HN + gid] = 2.0f*(c1r*db_im + c1i*db_re);
  }
}

// ---------------- LayerNorm stats over channel dim ----------------
__global__ __launch_bounds__(256) void stats_kernel(
    const float* __restrict__ x, const float* __restrict__ tt,
    float* __restrict__ mu, float* __restrict__ rstd) {
  int b = blockIdx.x >> 3;
  int l = ((blockIdx.x & 7) * 256) + threadIdx.x;
  float s = 0.f, s2 = 0.f;
  for (int h = 0; h < HH; ++h) {
    float v = x[(b*HH + h)*LL + l] + tt[b*HH + h];
    s += v; s2 = fmaf(v, v, s2);
  }
  float m = s * (1.0f/HH);
  float var = s2 * (1.0f/HH) - m*m;
  mu[b*LL + l]   = m;
  rstd[b*LL + l] = 1.0f / sqrtf(var + 1e-5f);
}

// ---------------- z = LN(x + tt) ----------------
__global__ __launch_bounds__(256) void z_kernel(
    const float* __restrict__ x, const float* __restrict__ tt,
    const float* __restrict__ mu, const float* __restrict__ rstd,
    const float* __restrict__ ln_g, const float* __restrict__ ln_b,
    float* __restrict__ z) {
  int i = blockIdx.x*256 + threadIdx.x;
  int l = i & (LL-1);
  int h = (i >> 11) & (HH-1);
  int b = i >> 19;
  float v = x[i] + tt[b*HH + h];
  z[i] = (v - mu[b*LL + l]) * rstd[b*LL + l] * ln_g[h] + ln_b[h];
}

// ---------------- bidirectional diagonal-SSM scan (v2) ----------------
// 4 independent waves per block; each wave = one (b,h,dir); lane = complex state n.
// Per-wave 16x65 LDS acc sub-tile; transpose-reduce every 16 steps + shfl combine.
__global__ __launch_bounds__(256) void scan_kernel(
    const float* __restrict__ z, const float* __restrict__ P,
    float* __restrict__ yf, float* __restrict__ yb) {
  int wid  = threadIdx.x >> 6;
  int lane = threadIdx.x & 63;
  int unit = blockIdx.x * 4 + wid;   // 0..4095
  int dir  = unit & 1;
  int pair = unit >> 1;              // 0..B*H-1
  int h = pair & (HH-1);
  int b = pair >> 8;
  int idx = h*NN + lane;
  float rre = P[idx], rim = P[HN+idx];
  float wre = (dir==0) ? P[2*HN+idx] : P[4*HN+idx];
  float wim = (dir==0) ? P[3*HN+idx] : P[5*HN+idx];
  const float* zrow = z + (b*HH + h)*LL;
  float* yrow = (dir==0 ? yf : yb) + (b*HH + h)*LL;

  __shared__ float acc[4][16][65];
  float (*A)[65] = acc[wid];
  int q  = lane >> 4;     // 0..3 : which 16-state group this lane reduces
  int tn = lane & 15;     // 0..15: which timestep row this lane reduces
  float sre = 0.f, sim = 0.f;

  if (dir == 0) {
    for (int c = 0; c < LL/16; ++c) {
      int l0 = c*16;
      float zs[16];
      *reinterpret_cast<float4*>(&zs[0])  = *reinterpret_cast<const float4*>(zrow + l0);
      *reinterpret_cast<float4*>(&zs[4])  = *reinterpret_cast<const float4*>(zrow + l0 + 4);
      *reinterpret_cast<float4*>(&zs[8])  = *reinterpret_cast<const float4*>(zrow + l0 + 8);
      *reinterpret_cast<float4*>(&zs[12]) = *reinterpret_cast<const float4*>(zrow + l0 + 12);
      #pragma unroll
      for (int t = 0; t < 16; ++t) {
        float zv = zs[t];
        float nre = fmaf(rre, sre, fmaf(-rim, sim, zv));
        float nim = fmaf(rre, sim, rim*sre);
        sre = nre; sim = nim;
        A[t][lane] = fmaf(wre, sre, -(wim*sim));
      }
      __syncthreads();
      float part = 0.f;
      #pragma unroll
      for (int k = 0; k < 16; ++k) part += A[tn][q*16 + k];
      part += __shfl_xor(part, 16);
      part += __shfl_xor(part, 32);
      if (q == 0) yrow[l0 + tn] = part;
      __syncthreads();
    }
  } else {
    for (int c = LL/16 - 1; c >= 0; --c) {
      int l0 = c*16;
      float zs[16];
      *reinterpret_cast<float4*>(&zs[0])  = *reinterpret_cast<const float4*>(zrow + l0);
      *reinterpret_cast<float4*>(&zs[4])  = *reinterpret_cast<const float4*>(zrow + l0 + 4);
      *reinterpret_cast<float4*>(&zs[8])  = *reinterpret_cast<const float4*>(zrow + l0 + 8);
      *reinterpret_cast<float4*>(&zs[12]) = *reinterpret_cast<const float4*>(zrow + l0 + 12);
      #pragma unroll
      for (int t = 15; t >= 0; --t) {
        A[t][lane] = fmaf(wre, sre, -(wim*sim));   // output BEFORE update (strictly anticausal)
        float zv = zs[t];
        float nre = fmaf(rre, sre, fmaf(-rim, sim, zv));
        float nim = fmaf(rre, sim, rim*sre);
        sre = nre; sim = nim;
      }
      __syncthreads();
      float part = 0.f;
      #pragma unroll
      for (int k = 0; k < 16; ++k) part += A[tn][q*16 + k];
      part += __shfl_xor(part, 16);
      part += __shfl_xor(part, 32);
      if (q == 0) yrow[l0 + tn] = part;
      __syncthreads();
    }
  }
}

// ---------------- y = yf + yb + z*D ; exact GELU (in-place over z) ----------------
__global__ __launch_bounds__(256) void combine_kernel(
    const float* __restrict__ yf, const float* __restrict__ ybk,
    float* __restrict__ z, const float* __restrict__ Dp) {
  int i = blockIdx.x*256 + threadIdx.x;
  int h = (i >> 11) & (HH-1);
  float y = yf[i] + ybk[i] + z[i]*Dp[h];
  z[i] = 0.5f * y * (1.0f + erff(y * 0.70710678118654752f));
}

// ---------------- 64x64-tile fp32 GEMM ----------------
// mode 0: + x + tt, then tanh*sigmoid gate   (W_out)
// mode 1: + x                                 (W1)
// mode 2: plain                               (W2)
__global__ __launch_bounds__(256) void gemm_kernel(
    const float* __restrict__ In, const float* __restrict__ W,
    const float* __restrict__ bias, const float* __restrict__ x,
    const float* __restrict__ tt, float* __restrict__ Out, int mode) {
  __shared__ float Ws[16][64];
  __shared__ float Is[16][64];
  int l0 = blockIdx.x * 64;
  int o0 = blockIdx.y * 64;
  int b  = blockIdx.z;
  int tid = threadIdx.x;
  int tl = (tid & 15) * 4;
  int to = (tid >> 4) * 4;
  float acc[4][4] = {};
  for (int k0 = 0; k0 < HH; k0 += 16) {
    {
      int o = tid >> 2, kq = (tid & 3)*4;
      const float4 wv = *reinterpret_cast<const float4*>(W + (o0+o)*HH + k0 + kq);
      Ws[kq+0][o] = wv.x; Ws[kq+1][o] = wv.y; Ws[kq+2][o] = wv.z; Ws[kq+3][o] = wv.w;
      int k = tid >> 4, lq = (tid & 15)*4;
      *reinterpret_cast<float4*>(&Is[k][lq]) =
        *reinterpret_cast<const float4*>(In + (b*HH + k0 + k)*LL + l0 + lq);
    }
    __syncthreads();
    #pragma unroll
    for (int kk = 0; kk < 16; ++kk) {
      float wv[4], iv[4];
      #pragma unroll
      for (int i = 0; i < 4; ++i) { wv[i] = Ws[kk][to+i]; iv[i] = Is[kk][tl+i]; }
      #pragma unroll
      for (int i = 0; i < 4; ++i)
        #pragma unroll
        for (int j = 0; j < 4; ++j)
          acc[i][j] = fmaf(wv[i], iv[j], acc[i][j]);
    }
    __syncthreads();
  }
  #pragma unroll
  for (int i = 0; i < 4; ++i) {
    int o = o0 + to + i;
    float bv = bias[o];
    float4 xv = make_float4(0.f,0.f,0.f,0.f);
    if (mode == 0 || mode == 1)
      xv = *reinterpret_cast<const float4*>(x + (b*HH + o)*LL + l0 + tl);
    float ttv = (mode == 0) ? tt[b*HH + o] : 0.f;
    float4 ov;
    #pragma unroll
    for (int j = 0; j < 4; ++j) {
      float v = acc[i][j] + bv;
      float xj = (&xv.x)[j];
      if (mode == 0) {
        v += xj + ttv;
        v = tanhf(v) * (1.0f/(1.0f+expf(-v)));
      } else if (mode == 1) {
        v += xj;
      }
      (&ov.x)[j] = v;
    }
    *reinterpret_cast<float4*>(&Out[(b*HH + o)*LL + l0 + tl]) = ov;
  }
}

extern "C" void kernel_launch(void* const* d_in, const int* in_sizes, int n_in,
                              void* d_out, int out_size, void* d_ws, size_t ws_size,
                              hipStream_t stream) {
  const float* x    = (const float*)d_in[0];
  const float* t    = (const float*)d_in[1];
  const float* W_t  = (const float*)d_in[2];
  const float* b_t  = (const float*)d_in[3];
  const float* ln_g = (const float*)d_in[4];
  const float* ln_b = (const float*)d_in[5];
  const float* log_dt = (const float*)d_in[6];
  const float* log_A_real = (const float*)d_in[7];
  const float* A_imag = (const float*)d_in[8];
  const float* B_re = (const float*)d_in[9];
  const float* B_im = (const float*)d_in[10];
  const float* C_re = (const float*)d_in[11];
  const float* C_im = (const float*)d_in[12];
  const float* Dp   = (const float*)d_in[13];
  const float* W_out= (const float*)d_in[14];
  const float* b_out= (const float*)d_in[15];
  const float* W1   = (const float*)d_in[16];
  const float* b1   = (const float*)d_in[17];
  const float* W2   = (const float*)d_in[18];
  const float* b2   = (const float*)d_in[19];

  // ws layout: P | tt | mu | rstd | zb | [g2 if it fits]
  float* P    = (float*)d_ws;
  float* tt   = P + 6*HN;
  float* mu   = tt + BB*HH;
  float* rstd = mu + BB*LL;
  float* zb   = rstd + BB*LL;
  float* g2   = zb + ELEMS;
  size_t need_big = (size_t)(6*HN + BB*HH + 2*BB*LL + 2*ELEMS) * sizeof(float);
  bool big = ws_size >= need_big;

  float* out1 = (float*)d_out;
  float* out2 = out1 + ELEMS;
  float* yf   = out1;   // scan scratch (overwritten later by real outputs)
  float* ybk  = out2;

  setup_kernel<<<BB + HN/256, 256, 0, stream>>>(t, W_t, b_t, log_dt, log_A_real, A_imag,
                                                B_re, B_im, C_re, C_im, P, tt);
  stats_kernel<<<BB*(LL/256), 256, 0, stream>>>(x, tt, mu, rstd);
  z_kernel<<<ELEMS/256, 256, 0, stream>>>(x, tt, mu, rstd, ln_g, ln_b, zb);
  scan_kernel<<<BB*HH*2/4, 256, 0, stream>>>(zb, P, yf, ybk);
  combine_kernel<<<ELEMS/256, 256, 0, stream>>>(yf, ybk, zb, Dp);          // zb now holds gelu(y)

  if (big) {
    gemm_kernel<<<dim3(LL/64, HH/64, BB), 256, 0, stream>>>(zb, W_out, b_out, x, tt, g2, 0);
    gemm_kernel<<<dim3(LL/64, HH/64, BB), 256, 0, stream>>>(g2, W1, b1, x, tt, out1, 1);
    gemm_kernel<<<dim3(LL/64, HH/64, BB), 256, 0, stream>>>(g2, W2, b2, x, tt, out2, 2);
  } else {
    float* gbuf = out2;
    gemm_kernel<<<dim3(LL/64, HH/64, BB), 256, 0, stream>>>(zb, W_out, b_out, x, tt, gbuf, 0);
    gemm_kernel<<<dim3(LL/64, HH/64, BB), 256, 0, stream>>>(gbuf, W1, b1, x, tt, out1, 1);
    gemm_kernel<<<dim3(LL/64, HH/64, BB), 256, 0, stream>>>(gbuf, W2, b2, x, tt, zb, 2);
    hipMemcpyAsync(out2, zb, (size_t)ELEMS*sizeof(float), hipMemcpyDeviceToDevice, stream);
  }
}

// Round 4
// 260.487 us; speedup vs baseline: 1.1779x; 1.1067x over previous
//
#include <hip/hip_runtime.h>
#include <math.h>

#define LL 2048
#define HH 256
#define BB 8
#define NN 64
#define HN (HH*NN)       // 16384
#define ELEMS (BB*HH*LL) // 4194304

typedef __attribute__((ext_vector_type(8))) short bf16x8v;
typedef __attribute__((ext_vector_type(4))) float f32x4v;

static inline __device__ ushort f2b_rne(float f) {
  uint u = __float_as_uint(f);
  return (ushort)((u + 0x7fffu + ((u >> 16) & 1u)) >> 16);
}

// ---------------- setup: tt[b,h] and per-(h,n) complex params ----------------
__global__ __launch_bounds__(256) void setup_kernel(
    const float* __restrict__ t, const float* __restrict__ W_t, const float* __restrict__ b_t,
    const float* __restrict__ log_dt, const float* __restrict__ log_A_real, const float* __restrict__ A_imag,
    const float* __restrict__ B_re, const float* __restrict__ B_im,
    const float* __restrict__ C_re, const float* __restrict__ C_im,
    float* __restrict__ P, float* __restrict__ tt) {
  int blk = blockIdx.x;
  int tid = threadIdx.x;
  if (blk < BB) {
    int b = blk, h = tid;
    float s = b_t[h];
    const float* trow = t + b*HH;
    const float* wrow = W_t + h*HH;
    for (int c = 0; c < HH; ++c) s = fmaf(trow[c], wrow[c], s);
    tt[b*HH + h] = s;
  } else {
    int gid = (blk - BB)*256 + tid;   // 0..HN-1  (= h*64+n)
    int h = gid >> 6;
    float dt  = expf(log_dt[h]);
    float are = -expf(log_A_real[gid]);
    float aim = A_imag[gid];
    float dre = dt*are, dim = dt*aim;
    float e = expf(dre);
    float rre = e * cosf(dim);
    float rim = e * sinf(dim);
    float inv  = 1.0f / (are*are + aim*aim);
    float m_re = rre - 1.0f, m_im = rim;
    float q_re = (m_re*are + m_im*aim) * inv;
    float q_im = (m_im*are - m_re*aim) * inv;
    float bre = B_re[gid], bim = B_im[gid];
    float db_re = q_re*bre - q_im*bim;
    float db_im = q_re*bim + q_im*bre;
    float c0r = C_re[gid],      c0i = C_im[gid];
    float c1r = C_re[HN + gid], c1i = C_im[HN + gid];
    P[gid]        = rre;
    P[HN + gid]   = rim;
    P[2*HN + gid] = 2.0f*(c0r*db_re - c0i*db_im);
    P[3*HN + gid] = 2.0f*(c0r*db_im + c0i*db_re);
    P[4*HN + gid] = 2.0f*(c1r*db_re - c1i*db_im);
    P[5*HN + gid] = 2.0f*(c1r*db_im + c1i*db_re);
  }
}

// ---------------- LayerNorm stats over channel dim ----------------
__global__ __launch_bounds__(256) void stats_kernel(
    const float* __restrict__ x, const float* __restrict__ tt,
    float* __restrict__ mu, float* __restrict__ rstd) {
  int b = blockIdx.x >> 3;
  int l = ((blockIdx.x & 7) * 256) + threadIdx.x;
  float s = 0.f, s2 = 0.f;
  for (int h = 0; h < HH; ++h) {
    float v = x[(b*HH + h)*LL + l] + tt[b*HH + h];
    s += v; s2 = fmaf(v, v, s2);
  }
  float m = s * (1.0f/HH);
  float var = s2 * (1.0f/HH) - m*m;
  mu[b*LL + l]   = m;
  rstd[b*LL + l] = 1.0f / sqrtf(var + 1e-5f);
}

// ---------------- z = LN(x + tt), stored bf16 (2 elems/thread) ----------------
__global__ __launch_bounds__(256) void z_kernel(
    const float* __restrict__ x, const float* __restrict__ tt,
    const float* __restrict__ mu, const float* __restrict__ rstd,
    const float* __restrict__ ln_g, const float* __restrict__ ln_b,
    uint* __restrict__ zb) {
  int g = blockIdx.x*256 + threadIdx.x;
  int i = g*2;
  int l = i & (LL-1);
  int bh = i >> 11;
  int h = bh & (HH-1);
  int b = bh >> 8;
  float2 xv = *reinterpret_cast<const float2*>(x + i);
  float ttv = tt[bh];
  float2 m2 = *reinterpret_cast<const float2*>(mu + b*LL + l);
  float2 r2 = *reinterpret_cast<const float2*>(rstd + b*LL + l);
  float gg = ln_g[h], bb = ln_b[h];
  float v0 = (xv.x + ttv - m2.x) * r2.x * gg + bb;
  float v1 = (xv.y + ttv - m2.y) * r2.y * gg + bb;
  zb[g] = (uint)f2b_rne(v0) | ((uint)f2b_rne(v1) << 16);
}

// ---------------- bidirectional diagonal-SSM scan (v3) ----------------
// 4 independent waves/block, NO inter-wave barriers (acc slice is wave-private).
// Double-buffered LDS acc + lgkmcnt fence; z (bf16) prefetched one chunk ahead.
#define UNPK(u, lo, hi) { lo = __uint_as_float((u)<<16); hi = __uint_as_float((u)&0xffff0000u); }
__global__ __launch_bounds__(256) void scan_kernel(
    const ushort* __restrict__ z, const float* __restrict__ P,
    float* __restrict__ yf, float* __restrict__ yb) {
  int wid  = threadIdx.x >> 6;
  int lane = threadIdx.x & 63;
  int unit = blockIdx.x * 4 + wid;   // 0..4095
  int dir  = unit & 1;
  int pair = unit >> 1;
  int h = pair & (HH-1);
  int b = pair >> 8;
  int idx = h*NN + lane;
  float rre = P[idx], rim = P[HN+idx];
  float wre = (dir==0) ? P[2*HN+idx] : P[4*HN+idx];
  float wim = (dir==0) ? P[3*HN+idx] : P[5*HN+idx];
  const uint4* zp = reinterpret_cast<const uint4*>(z + (size_t)(b*HH + h)*LL);
  float* yrow = (dir==0 ? yf : yb) + (size_t)(b*HH + h)*LL;

  __shared__ float accs[4][2][16][65];
  int q  = lane >> 4;
  int tn = lane & 15;
  float sre = 0.f, sim = 0.f;
  int buf = 0;

  if (dir == 0) {
    uint4 c0 = zp[0], c1 = zp[1];
    for (int c = 0; c < LL/16; ++c) {
      uint4 n0 = c0, n1 = c1;
      if (c < LL/16 - 1) { n0 = zp[2*c+2]; n1 = zp[2*c+3]; }
      float zs[16];
      UNPK(c0.x, zs[0], zs[1]);  UNPK(c0.y, zs[2], zs[3]);
      UNPK(c0.z, zs[4], zs[5]);  UNPK(c0.w, zs[6], zs[7]);
      UNPK(c1.x, zs[8], zs[9]);  UNPK(c1.y, zs[10], zs[11]);
      UNPK(c1.z, zs[12], zs[13]); UNPK(c1.w, zs[14], zs[15]);
      float (*A)[65] = accs[wid][buf];
      #pragma unroll
      for (int t = 0; t < 16; ++t) {
        float nre = fmaf(rre, sre, fmaf(-rim, sim, zs[t]));
        float nim = fmaf(rre, sim, rim*sre);
        sre = nre; sim = nim;
        A[t][lane] = fmaf(wre, sre, -(wim*sim));
      }
      asm volatile("s_waitcnt lgkmcnt(0)" ::: "memory");
      __builtin_amdgcn_sched_barrier(0);
      float part = 0.f;
      #pragma unroll
      for (int k = 0; k < 16; ++k) part += A[tn][q*16 + k];
      part += __shfl_xor(part, 16);
      part += __shfl_xor(part, 32);
      if (q == 0) yrow[c*16 + tn] = part;
      c0 = n0; c1 = n1; buf ^= 1;
    }
  } else {
    uint4 c0 = zp[2*(LL/16-1)], c1 = zp[2*(LL/16-1)+1];
    for (int c = LL/16 - 1; c >= 0; --c) {
      uint4 n0 = c0, n1 = c1;
      if (c > 0) { n0 = zp[2*c-2]; n1 = zp[2*c-1]; }
      float zs[16];
      UNPK(c0.x, zs[0], zs[1]);  UNPK(c0.y, zs[2], zs[3]);
      UNPK(c0.z, zs[4], zs[5]);  UNPK(c0.w, zs[6], zs[7]);
      UNPK(c1.x, zs[8], zs[9]);  UNPK(c1.y, zs[10], zs[11]);
      UNPK(c1.z, zs[12], zs[13]); UNPK(c1.w, zs[14], zs[15]);
      float (*A)[65] = accs[wid][buf];
      #pragma unroll
      for (int t = 15; t >= 0; --t) {
        A[t][lane] = fmaf(wre, sre, -(wim*sim));   // output BEFORE update (anticausal)
        float nre = fmaf(rre, sre, fmaf(-rim, sim, zs[t]));
        float nim = fmaf(rre, sim, rim*sre);
        sre = nre; sim = nim;
      }
      asm volatile("s_waitcnt lgkmcnt(0)" ::: "memory");
      __builtin_amdgcn_sched_barrier(0);
      float part = 0.f;
      #pragma unroll
      for (int k = 0; k < 16; ++k) part += A[tn][q*16 + k];
      part += __shfl_xor(part, 16);
      part += __shfl_xor(part, 32);
      if (q == 0) yrow[c*16 + tn] = part;
      c0 = n0; c1 = n1; buf ^= 1;
    }
  }
}

// ---------------- y = yf + yb + z*D ; exact GELU, fp32 in-place over yf ----------------
__global__ __launch_bounds__(256) void combine_kernel(
    float* yf_g, const float* __restrict__ ybk,
    const ushort* __restrict__ zb, const float* __restrict__ Dp) {
  int g = blockIdx.x*256 + threadIdx.x;
  int i = g*4;
  int h = (i >> 11) & (HH-1);
  float av[4], bv[4], ov[4], zf[4];
  *reinterpret_cast<float4*>(av) = *reinterpret_cast<const float4*>(yf_g + i);
  *reinterpret_cast<float4*>(bv) = *reinterpret_cast<const float4*>(ybk + i);
  uint2 zz = *reinterpret_cast<const uint2*>(zb + i);
  float d = Dp[h];
  UNPK(zz.x, zf[0], zf[1]); UNPK(zz.y, zf[2], zf[3]);
  #pragma unroll
  for (int j = 0; j < 4; ++j) {
    float y = av[j] + bv[j] + zf[j]*d;
    ov[j] = 0.5f * y * (1.0f + erff(y * 0.70710678118654752f));
  }
  *reinterpret_cast<float4*>(yf_g + i) = *reinterpret_cast<float4*>(ov);
}

// ---------------- transpose g (fp32 [b][h][l]) -> gT (bf16 [b][l][h]) ----------------
__global__ __launch_bounds__(256) void trans_kernel(
    const float* __restrict__ g, ushort* __restrict__ gT) {
  __shared__ ushort T[64][72];
  int tid = threadIdx.x;
  int l0 = blockIdx.x*64, h0 = blockIdx.y*64, b = blockIdx.z;
  int hr = tid >> 2, cs = (tid & 3)*16;
  const float* src = g + ((size_t)(b*HH + h0 + hr))*LL + l0 + cs;
  float vv[16];
  *reinterpret_cast<float4*>(&vv[0])  = reinterpret_cast<const float4*>(src)[0];
  *reinterpret_cast<float4*>(&vv[4])  = reinterpret_cast<const float4*>(src)[1];
  *reinterpret_cast<float4*>(&vv[8])  = reinterpret_cast<const float4*>(src)[2];
  *reinterpret_cast<float4*>(&vv[12]) = reinterpret_cast<const float4*>(src)[3];
  #pragma unroll
  for (int j = 0; j < 16; ++j) T[cs + j][hr] = f2b_rne(vv[j]);
  __syncthreads();
  int lr = tid >> 2, hs = (tid & 3)*16;
  uint4 w0 = *reinterpret_cast<const uint4*>(&T[lr][hs]);
  uint4 w1 = *reinterpret_cast<const uint4*>(&T[lr][hs+8]);
  ushort* dst = gT + ((size_t)(b*LL + l0 + lr))*HH + h0 + hs;
  *reinterpret_cast<uint4*>(dst) = w0;
  *reinterpret_cast<uint4*>(dst + 8) = w1;
}

// ---------------- bf16 MFMA GEMM: D[o][l] = sum_h W[o][h] * BT[l][h] ----------------
// W fp32 (cvt on the fly); BT bf16 [b][l][h].
// MODE 0: v=acc+bias+x+tt -> gate -> bf16 transposed out (OutT [b][l][o])
// MODE 1: v=acc+bias+x    -> fp32 Out [b][o][l]
// MODE 2: v=acc+bias      -> fp32 Out [b][o][l]
template<int MODE>
__global__ __launch_bounds__(256) void gemm_mfma(
    const float* __restrict__ W, const ushort* __restrict__ BT,
    const float* __restrict__ bias, const float* __restrict__ x,
    const float* __restrict__ tt, ushort* __restrict__ OutT,
    float* __restrict__ Out) {
  int l0 = blockIdx.x * 64;
  int o0 = blockIdx.y * 64;
  int b  = blockIdx.z;
  int tid = threadIdx.x, wid = tid >> 6, lane = tid & 63;
  int wm = wid >> 1, wn = wid & 1;
  int row16 = lane & 15, kg = lane >> 4;

  f32x4v acc00 = {0.f,0.f,0.f,0.f}, acc01 = acc00, acc10 = acc00, acc11 = acc00;
  const float*  Ar = W  + (o0 + wm*32 + row16)*HH + kg*8;
  const ushort* Br = BT + ((size_t)(b*LL + l0 + wn*32 + row16))*HH + kg*8;

  #pragma unroll
  for (int k0 = 0; k0 < HH; k0 += 32) {
    float4 af0 = reinterpret_cast<const float4*>(Ar + k0)[0];
    float4 af1 = reinterpret_cast<const float4*>(Ar + k0)[1];
    float4 ag0 = reinterpret_cast<const float4*>(Ar + 16*HH + k0)[0];
    float4 ag1 = reinterpret_cast<const float4*>(Ar + 16*HH + k0)[1];
    union { uint u[4]; bf16x8v v; } pa0, pa1;
    pa0.u[0] = (__float_as_uint(af0.x)>>16) | (__float_as_uint(af0.y)&0xffff0000u);
    pa0.u[1] = (__float_as_uint(af0.z)>>16) | (__float_as_uint(af0.w)&0xffff0000u);
    pa0.u[2] = (__float_as_uint(af1.x)>>16) | (__float_as_uint(af1.y)&0xffff0000u);
    pa0.u[3] = (__float_as_uint(af1.z)>>16) | (__float_as_uint(af1.w)&0xffff0000u);
    pa1.u[0] = (__float_as_uint(ag0.x)>>16) | (__float_as_uint(ag0.y)&0xffff0000u);
    pa1.u[1] = (__float_as_uint(ag0.z)>>16) | (__float_as_uint(ag0.w)&0xffff0000u);
    pa1.u[2] = (__float_as_uint(ag1.x)>>16) | (__float_as_uint(ag1.y)&0xffff0000u);
    pa1.u[3] = (__float_as_uint(ag1.z)>>16) | (__float_as_uint(ag1.w)&0xffff0000u);
    bf16x8v b0 = *reinterpret_cast<const bf16x8v*>(Br + k0);
    bf16x8v b1 = *reinterpret_cast<const bf16x8v*>(Br + 16*HH + k0);
    acc00 = __builtin_amdgcn_mfma_f32_16x16x32_bf16(pa0.v, b0, acc00, 0,0,0);
    acc01 = __builtin_amdgcn_mfma_f32_16x16x32_bf16(pa0.v, b1, acc01, 0,0,0);
    acc10 = __builtin_amdgcn_mfma_f32_16x16x32_bf16(pa1.v, b0, acc10, 0,0,0);
    acc11 = __builtin_amdgcn_mfma_f32_16x16x32_bf16(pa1.v, b1, acc11, 0,0,0);
  }

  if (MODE == 0) {
    __shared__ ushort T[64][72];
    #pragma unroll
    for (int fm = 0; fm < 2; ++fm)
      #pragma unroll
      for (int fn = 0; fn < 2; ++fn) {
        const f32x4v* a = (fm==0) ? (fn==0 ? &acc00 : &acc01) : (fn==0 ? &acc10 : &acc11);
        int ll = l0 + wn*32 + fn*16 + row16;
        #pragma unroll
        for (int r = 0; r < 4; ++r) {
          int o = o0 + wm*32 + fm*16 + kg*4 + r;
          float v = (*a)[r] + bias[o] + x[((size_t)(b*HH + o))*LL + ll] + tt[b*HH + o];
          float gate = tanhf(v) * (1.0f/(1.0f + expf(-v)));
          T[wn*32 + fn*16 + row16][wm*32 + fm*16 + kg*4 + r] = f2b_rne(gate);
        }
      }
    __syncthreads();
    int lr = tid >> 2, os = (tid & 3)*16;
    uint4 w0 = *reinterpret_cast<const uint4*>(&T[lr][os]);
    uint4 w1 = *reinterpret_cast<const uint4*>(&T[lr][os+8]);
    ushort* dst = OutT + ((size_t)(b*LL + l0 + lr))*HH + o0 + os;
    *reinterpret_cast<uint4*>(dst) = w0;
    *reinterpret_cast<uint4*>(dst + 8) = w1;
  } else {
    #pragma unroll
    for (int fm = 0; fm < 2; ++fm)
      #pragma unroll
      for (int fn = 0; fn < 2; ++fn) {
        const f32x4v* a = (fm==0) ? (fn==0 ? &acc00 : &acc01) : (fn==0 ? &acc10 : &acc11);
        int ll = l0 + wn*32 + fn*16 + row16;
        #pragma unroll
        for (int r = 0; r < 4; ++r) {
          int o = o0 + wm*32 + fm*16 + kg*4 + r;
          float v = (*a)[r] + bias[o];
          if (MODE == 1) v += x[((size_t)(b*HH + o))*LL + ll];
          Out[((size_t)(b*HH + o))*LL + ll] = v;
        }
      }
  }
}

extern "C" void kernel_launch(void* const* d_in, const int* in_sizes, int n_in,
                              void* d_out, int out_size, void* d_ws, size_t ws_size,
                              hipStream_t stream) {
  const float* x    = (const float*)d_in[0];
  const float* t    = (const float*)d_in[1];
  const float* W_t  = (const float*)d_in[2];
  const float* b_t  = (const float*)d_in[3];
  const float* ln_g = (const float*)d_in[4];
  const float* ln_b = (const float*)d_in[5];
  const float* log_dt = (const float*)d_in[6];
  const float* log_A_real = (const float*)d_in[7];
  const float* A_imag = (const float*)d_in[8];
  const float* B_re = (const float*)d_in[9];
  const float* B_im = (const float*)d_in[10];
  const float* C_re = (const float*)d_in[11];
  const float* C_im = (const float*)d_in[12];
  const float* Dp   = (const float*)d_in[13];
  const float* W_out= (const float*)d_in[14];
  const float* b_out= (const float*)d_in[15];
  const float* W1   = (const float*)d_in[16];
  const float* b1   = (const float*)d_in[17];
  const float* W2   = (const float*)d_in[18];
  const float* b2   = (const float*)d_in[19];

  // ws: P(98304f) | tt(2048f) | mu(16384f) | rstd(16384f) | zb(bf16, ELEMS) | g2T(bf16, ELEMS)
  float* P    = (float*)d_ws;
  float* tt   = P + 6*HN;
  float* mu   = tt + BB*HH;
  float* rstd = mu + BB*LL;
  ushort* zb  = (ushort*)(rstd + BB*LL);
  ushort* g2T = zb + ELEMS;
  ushort* gT  = zb;               // reuses zb region AFTER combine consumed z

  float* out1 = (float*)d_out;
  float* out2 = out1 + ELEMS;

  setup_kernel<<<BB + HN/256, 256, 0, stream>>>(t, W_t, b_t, log_dt, log_A_real, A_imag,
                                                B_re, B_im, C_re, C_im, P, tt);
  stats_kernel<<<BB*(LL/256), 256, 0, stream>>>(x, tt, mu, rstd);
  z_kernel<<<ELEMS/512, 256, 0, stream>>>(x, tt, mu, rstd, ln_g, ln_b, (uint*)zb);
  scan_kernel<<<BB*HH*2/4, 256, 0, stream>>>(zb, P, out1, out2);      // yf->out1, yb->out2
  combine_kernel<<<ELEMS/1024, 256, 0, stream>>>(out1, out2, zb, Dp); // gelu(y) fp32 in out1
  trans_kernel<<<dim3(LL/64, HH/64, BB), 256, 0, stream>>>(out1, gT); // gT bf16 over zb region
  gemm_mfma<0><<<dim3(LL/64, HH/64, BB), 256, 0, stream>>>(W_out, gT, b_out, x, tt, g2T, nullptr);
  gemm_mfma<1><<<dim3(LL/64, HH/64, BB), 256, 0, stream>>>(W1, g2T, b1, x, tt, nullptr, out1);
  gemm_mfma<2><<<dim3(LL/64, HH/64, BB), 256, 0, stream>>>(W2, g2T, b2, x, tt, nullptr, out2);
}

// Round 5
// 198.279 us; speedup vs baseline: 1.5474x; 1.3137x over previous
//
#include <hip/hip_runtime.h>
#include <math.h>

#define LL 2048
#define HH 256
#define BB 8
#define NN 64
#define HN (HH*NN)       // 16384
#define ELEMS (BB*HH*LL) // 4194304

typedef __attribute__((ext_vector_type(8))) short bf16x8v;
typedef __attribute__((ext_vector_type(4))) float f32x4v;

static inline __device__ ushort f2b_rne(float f) {
  uint u = __float_as_uint(f);
  return (ushort)((u + 0x7fffu + ((u >> 16) & 1u)) >> 16);
}
static inline __device__ float b2f(ushort u) { return __uint_as_float((uint)u << 16); }
#define UNPK(u, lo, hi) { lo = __uint_as_float((u)<<16); hi = __uint_as_float((u)&0xffff0000u); }

// ---------------- setup: tt[b,h] and per-(h,n) complex params ----------------
__global__ __launch_bounds__(256) void setup_kernel(
    const float* __restrict__ t, const float* __restrict__ W_t, const float* __restrict__ b_t,
    const float* __restrict__ log_dt, const float* __restrict__ log_A_real, const float* __restrict__ A_imag,
    const float* __restrict__ B_re, const float* __restrict__ B_im,
    const float* __restrict__ C_re, const float* __restrict__ C_im,
    float* __restrict__ P, float* __restrict__ tt) {
  int blk = blockIdx.x;
  int tid = threadIdx.x;
  if (blk < BB) {
    int b = blk, h = tid;
    float s = b_t[h];
    const float* trow = t + b*HH;
    const float* wrow = W_t + h*HH;
    for (int c = 0; c < HH; ++c) s = fmaf(trow[c], wrow[c], s);
    tt[b*HH + h] = s;
  } else {
    int gid = (blk - BB)*256 + tid;   // 0..HN-1  (= h*64+n)
    int h = gid >> 6;
    float dt  = expf(log_dt[h]);
    float are = -expf(log_A_real[gid]);
    float aim = A_imag[gid];
    float dre = dt*are, dim = dt*aim;
    float e = expf(dre);
    float rre = e * cosf(dim);
    float rim = e * sinf(dim);
    float inv  = 1.0f / (are*are + aim*aim);
    float m_re = rre - 1.0f, m_im = rim;
    float q_re = (m_re*are + m_im*aim) * inv;
    float q_im = (m_im*are - m_re*aim) * inv;
    float bre = B_re[gid], bim = B_im[gid];
    float db_re = q_re*bre - q_im*bim;
    float db_im = q_re*bim + q_im*bre;
    float c0r = C_re[gid],      c0i = C_im[gid];
    float c1r = C_re[HN + gid], c1i = C_im[HN + gid];
    P[gid]        = rre;
    P[HN + gid]   = rim;
    P[2*HN + gid] = 2.0f*(c0r*db_re - c0i*db_im);
    P[3*HN + gid] = 2.0f*(c0r*db_im + c0i*db_re);
    P[4*HN + gid] = 2.0f*(c1r*db_re - c1i*db_im);
    P[5*HN + gid] = 2.0f*(c1r*db_im + c1i*db_re);
  }
}

// ---------------- LayerNorm stats over channel dim ----------------
__global__ __launch_bounds__(256) void stats_kernel(
    const float* __restrict__ x, const float* __restrict__ tt,
    float* __restrict__ mu, float* __restrict__ rstd) {
  int b = blockIdx.x >> 3;
  int l = ((blockIdx.x & 7) * 256) + threadIdx.x;
  float s = 0.f, s2 = 0.f;
  for (int h = 0; h < HH; ++h) {
    float v = x[(b*HH + h)*LL + l] + tt[b*HH + h];
    s += v; s2 = fmaf(v, v, s2);
  }
  float m = s * (1.0f/HH);
  float var = s2 * (1.0f/HH) - m*m;
  mu[b*LL + l]   = m;
  rstd[b*LL + l] = 1.0f / sqrtf(var + 1e-5f);
}

// ---------------- z = LN(x + tt), stored bf16 ----------------
__global__ __launch_bounds__(256) void z_kernel(
    const float* __restrict__ x, const float* __restrict__ tt,
    const float* __restrict__ mu, const float* __restrict__ rstd,
    const float* __restrict__ ln_g, const float* __restrict__ ln_b,
    uint* __restrict__ zb) {
  int g = blockIdx.x*256 + threadIdx.x;
  int i = g*2;
  int l = i & (LL-1);
  int bh = i >> 11;
  int h = bh & (HH-1);
  int b = bh >> 8;
  float2 xv = *reinterpret_cast<const float2*>(x + i);
  float ttv = tt[bh];
  float2 m2 = *reinterpret_cast<const float2*>(mu + b*LL + l);
  float2 r2 = *reinterpret_cast<const float2*>(rstd + b*LL + l);
  float gg = ln_g[h], bb = ln_b[h];
  float v0 = (xv.x + ttv - m2.x) * r2.x * gg + bb;
  float v1 = (xv.y + ttv - m2.y) * r2.y * gg + bb;
  zb[g] = (uint)f2b_rne(v0) | ((uint)f2b_rne(v1) << 16);
}

// ---------------- prep: per-h chunk matrices Mc (64x64), Vc (256x64), Uc (64x256), rT ----
__global__ __launch_bounds__(256) void prep_kernel(
    const float* __restrict__ log_dt, const float* __restrict__ log_A_real,
    const float* __restrict__ A_imag, const float* __restrict__ P,
    const float* __restrict__ Dp,
    ushort* __restrict__ Mc, ushort* __restrict__ Vc, ushort* __restrict__ Uc,
    float* __restrict__ rT) {
  int h = blockIdx.x, tid = threadIdx.x;
  __shared__ float RRe[65][64], RIm[65][64];
  __shared__ float K0[64], K1[64];
  float dt = expf(log_dt[h]);
  for (int idx = tid; idx < 65*64; idx += 256) {
    int d = idx >> 6, n = idx & 63;
    float are = -expf(log_A_real[h*64+n]);
    float aim = A_imag[h*64+n];
    float ang = dt*aim*(float)d;
    float mag = expf(dt*are*(float)d);
    RRe[d][n] = mag * cosf(ang);
    RIm[d][n] = mag * sinf(ang);
  }
  __syncthreads();
  if (tid < 128) {
    int d = tid & 63; bool c1 = tid >= 64;
    const float* wr = P + (c1 ? 4*HN : 2*HN) + h*64;
    const float* wi = P + (c1 ? 5*HN : 3*HN) + h*64;
    float s = 0.f;
    for (int n = 0; n < 64; ++n) s += wr[n]*RRe[d][n] - wi[n]*RIm[d][n];
    if (c1) K1[d] = s; else K0[d] = s;
  }
  if (tid < 64) {  // rT = r^64
    rT[(h*64+tid)*2]   = RRe[64][tid];
    rT[(h*64+tid)*2+1] = RIm[64][tid];
  }
  __syncthreads();
  float dh = Dp[h];
  for (int idx = tid; idx < 4096; idx += 256) {
    int i = idx >> 6, j = idx & 63;
    float v = (i > j) ? K0[i-j] : (i < j ? K1[j-i-1] : (K0[0] + dh));
    Mc[(size_t)h*4096 + idx] = f2b_rne(v);
  }
  // Vc rows: 2n: Re r^{63-j}; 2n+1: Im r^{63-j}; 128+2n: Re r^j; 129+2n: Im r^j
  for (int idx = tid; idx < 256*64; idx += 256) {
    int row = idx >> 6, j = idx & 63;
    int n = (row >> 1) & 63;
    bool im = row & 1, bwd = row >= 128;
    int d = bwd ? j : 63-j;
    Vc[(size_t)h*16384 + idx] = f2b_rne(im ? RIm[d][n] : RRe[d][n]);
  }
  // Uc cols: 2n: Re r^{i+1}; 2n+1: -Im r^{i+1}; 128+2n: Re r^{63-i}; 129+2n: -Im r^{63-i}
  for (int idx = tid; idx < 64*256; idx += 256) {
    int i = idx >> 8, col = idx & 255;
    int n = (col >> 1) & 63;
    bool im = col & 1, bwd = col >= 128;
    int d = bwd ? 63-i : i+1;
    Uc[(size_t)h*16384 + idx] = f2b_rne(im ? -RIm[d][n] : RRe[d][n]);
  }
}

// ---------------- gloc: G[h][comp(256)][bc(256)] = Vc_h @ Z_h ----------------
__global__ __launch_bounds__(256) void gloc_gemm(
    const ushort* __restrict__ Vc, const ushort* __restrict__ zb,
    ushort* __restrict__ G) {
  int tile = blockIdx.x;      // 0..15
  int h = blockIdx.y;
  int comp0 = (tile >> 2) * 64, bct = (tile & 3) * 64;
  int tid = threadIdx.x, wid = tid >> 6, lane = tid & 63;
  int wm = wid >> 1, wn = wid & 1, row16 = lane & 15, kg = lane >> 4;
  f32x4v acc00 = {0.f,0.f,0.f,0.f}, acc01 = acc00, acc10 = acc00, acc11 = acc00;
  const ushort* Ar = Vc + (size_t)h*16384 + (comp0 + wm*32 + row16)*64 + kg*8;
  int bcA = bct + wn*32 + row16; int bA = bcA >> 5, cA = bcA & 31;
  int bcB = bcA + 16;           int bB = bcB >> 5, cB = bcB & 31;
  const ushort* Bz0 = zb + ((size_t)(bA*HH + h))*LL + cA*64 + kg*8;
  const ushort* Bz1 = zb + ((size_t)(bB*HH + h))*LL + cB*64 + kg*8;
  #pragma unroll
  for (int k0 = 0; k0 < 64; k0 += 32) {
    bf16x8v a0 = *reinterpret_cast<const bf16x8v*>(Ar + k0);
    bf16x8v a1 = *reinterpret_cast<const bf16x8v*>(Ar + 16*64 + k0);
    bf16x8v b0 = *reinterpret_cast<const bf16x8v*>(Bz0 + k0);
    bf16x8v b1 = *reinterpret_cast<const bf16x8v*>(Bz1 + k0);
    acc00 = __builtin_amdgcn_mfma_f32_16x16x32_bf16(a0, b0, acc00, 0,0,0);
    acc01 = __builtin_amdgcn_mfma_f32_16x16x32_bf16(a0, b1, acc01, 0,0,0);
    acc10 = __builtin_amdgcn_mfma_f32_16x16x32_bf16(a1, b0, acc10, 0,0,0);
    acc11 = __builtin_amdgcn_mfma_f32_16x16x32_bf16(a1, b1, acc11, 0,0,0);
  }
  #pragma unroll
  for (int fm = 0; fm < 2; ++fm)
    #pragma unroll
    for (int fn = 0; fn < 2; ++fn) {
      const f32x4v* a = (fm==0) ? (fn==0 ? &acc00 : &acc01) : (fn==0 ? &acc10 : &acc11);
      int col = bct + wn*32 + fn*16 + row16;
      #pragma unroll
      for (int r = 0; r < 4; ++r) {
        int row = comp0 + wm*32 + fm*16 + kg*4 + r;
        G[(size_t)h*65536 + row*256 + col] = f2b_rne((*a)[r]);
      }
    }
}

// ---------------- ssm: in-block chunk scan + Y = Mc@Z + Uc@uT + GELU -> g bf16 ----
__global__ __launch_bounds__(256) void ssm_gemm(
    const ushort* __restrict__ zb, const ushort* __restrict__ G,
    const ushort* __restrict__ Mc, const ushort* __restrict__ Uc,
    const float* __restrict__ P, const float* __restrict__ rT,
    ushort* __restrict__ g) {
  int t = blockIdx.x;        // 0..3 (bc tile; b = 2t, 2t+1)
  int h = blockIdx.y;
  int tid = threadIdx.x, wid = tid >> 6, lane = tid & 63;
  __shared__ ushort U[64][264];
  // ---- phase 1: chunk scan (wave = (bloc, dir)) ----
  {
    int bloc = wid >> 1, dir = wid & 1;
    int b = t*2 + bloc;
    int n = lane;
    float w_re, w_im;
    if (dir == 0) { w_re = P[2*HN + h*64+n]; w_im = P[3*HN + h*64+n]; }
    else          { w_re = P[4*HN + h*64+n]; w_im = P[5*HN + h*64+n]; }
    float rtr = rT[(h*64+n)*2], rti = rT[(h*64+n)*2+1];
    const ushort* Gre = G + ((size_t)h*256 + (dir ? 128 : 0) + 2*n)*256 + b*32;
    const ushort* Gim = Gre + 256;
    float sre = 0.f, sim = 0.f;
    if (dir == 0) {
      for (int c = 0; c < 32; ++c) {
        float ure = w_re*sre - w_im*sim;
        float uim = w_re*sim + w_im*sre;
        *reinterpret_cast<uint*>(&U[bloc*32 + c][2*n]) =
            (uint)f2b_rne(ure) | ((uint)f2b_rne(uim) << 16);
        float nre = rtr*sre - rti*sim + b2f(Gre[c]);
        float nim = rtr*sim + rti*sre + b2f(Gim[c]);
        sre = nre; sim = nim;
      }
    } else {
      for (int c = 31; c >= 0; --c) {
        float ure = w_re*sre - w_im*sim;
        float uim = w_re*sim + w_im*sre;
        *reinterpret_cast<uint*>(&U[bloc*32 + c][128 + 2*n]) =
            (uint)f2b_rne(ure) | ((uint)f2b_rne(uim) << 16);
        float nre = rtr*sre - rti*sim + b2f(Gre[c]);
        float nim = rtr*sim + rti*sre + b2f(Gim[c]);
        sre = nre; sim = nim;
      }
    }
  }
  __syncthreads();
  // ---- phase 2: GEMM + GELU ----
  int wm = wid >> 1, wn = wid & 1, row16 = lane & 15, kg = lane >> 4;
  f32x4v acc00 = {0.f,0.f,0.f,0.f}, acc01 = acc00, acc10 = acc00, acc11 = acc00;
  const ushort* Ar = Mc + (size_t)h*4096 + (wm*32 + row16)*64 + kg*8;
  int bcA = t*64 + wn*32 + row16; int bA = bcA >> 5, cA = bcA & 31;
  int bcB = bcA + 16;             int bB = bcB >> 5, cB = bcB & 31;
  const ushort* Bz0 = zb + ((size_t)(bA*HH + h))*LL + cA*64 + kg*8;
  const ushort* Bz1 = zb + ((size_t)(bB*HH + h))*LL + cB*64 + kg*8;
  #pragma unroll
  for (int k0 = 0; k0 < 64; k0 += 32) {
    bf16x8v a0 = *reinterpret_cast<const bf16x8v*>(Ar + k0);
    bf16x8v a1 = *reinterpret_cast<const bf16x8v*>(Ar + 16*64 + k0);
    bf16x8v b0 = *reinterpret_cast<const bf16x8v*>(Bz0 + k0);
    bf16x8v b1 = *reinterpret_cast<const bf16x8v*>(Bz1 + k0);
    acc00 = __builtin_amdgcn_mfma_f32_16x16x32_bf16(a0, b0, acc00, 0,0,0);
    acc01 = __builtin_amdgcn_mfma_f32_16x16x32_bf16(a0, b1, acc01, 0,0,0);
    acc10 = __builtin_amdgcn_mfma_f32_16x16x32_bf16(a1, b0, acc10, 0,0,0);
    acc11 = __builtin_amdgcn_mfma_f32_16x16x32_bf16(a1, b1, acc11, 0,0,0);
  }
  const ushort* Au = Uc + (size_t)h*16384 + (wm*32 + row16)*256 + kg*8;
  int lr0 = wn*32 + row16, lr1 = lr0 + 16;
  #pragma unroll
  for (int k0 = 0; k0 < 256; k0 += 32) {
    bf16x8v a0 = *reinterpret_cast<const bf16x8v*>(Au + k0);
    bf16x8v a1 = *reinterpret_cast<const bf16x8v*>(Au + 16*256 + k0);
    bf16x8v b0 = *reinterpret_cast<const bf16x8v*>(&U[lr0][k0 + kg*8]);
    bf16x8v b1 = *reinterpret_cast<const bf16x8v*>(&U[lr1][k0 + kg*8]);
    acc00 = __builtin_amdgcn_mfma_f32_16x16x32_bf16(a0, b0, acc00, 0,0,0);
    acc01 = __builtin_amdgcn_mfma_f32_16x16x32_bf16(a0, b1, acc01, 0,0,0);
    acc10 = __builtin_amdgcn_mfma_f32_16x16x32_bf16(a1, b0, acc10, 0,0,0);
    acc11 = __builtin_amdgcn_mfma_f32_16x16x32_bf16(a1, b1, acc11, 0,0,0);
  }
  #pragma unroll
  for (int fm = 0; fm < 2; ++fm)
    #pragma unroll
    for (int fn = 0; fn < 2; ++fn) {
      const f32x4v* a = (fm==0) ? (fn==0 ? &acc00 : &acc01) : (fn==0 ? &acc10 : &acc11);
      int bc = t*64 + wn*32 + fn*16 + row16;
      int b = bc >> 5, c = bc & 31;
      #pragma unroll
      for (int r = 0; r < 4; ++r) {
        int i = wm*32 + fm*16 + kg*4 + r;
        float v = (*a)[r];
        float ge = 0.5f * v * (1.0f + erff(v * 0.70710678118654752f));
        g[((size_t)(b*HH + h))*LL + c*64 + i] = f2b_rne(ge);
      }
    }
}

// ---------------- transpose g (bf16 [b][h][l]) -> gT (bf16 [b][l][h]) ----------------
__global__ __launch_bounds__(256) void trans_b2b(
    const ushort* __restrict__ g, ushort* __restrict__ gT) {
  __shared__ ushort T[64][72];
  int tid = threadIdx.x;
  int l0 = blockIdx.x*64, h0 = blockIdx.y*64, b = blockIdx.z;
  int hr = tid >> 2, cs = (tid & 3)*16;
  const ushort* src = g + ((size_t)(b*HH + h0 + hr))*LL + l0 + cs;
  ushort vv[16];
  *reinterpret_cast<uint4*>(&vv[0]) = *reinterpret_cast<const uint4*>(src);
  *reinterpret_cast<uint4*>(&vv[8]) = *reinterpret_cast<const uint4*>(src + 8);
  #pragma unroll
  for (int j = 0; j < 16; ++j) T[cs + j][hr] = vv[j];
  __syncthreads();
  int lr = tid >> 2, hs = (tid & 3)*16;
  uint4 w0 = *reinterpret_cast<const uint4*>(&T[lr][hs]);
  uint4 w1 = *reinterpret_cast<const uint4*>(&T[lr][hs+8]);
  ushort* dst = gT + ((size_t)(b*LL + l0 + lr))*HH + h0 + hs;
  *reinterpret_cast<uint4*>(dst) = w0;
  *reinterpret_cast<uint4*>(dst + 8) = w1;
}

// ---------------- FALLBACK-path kernels (proven R4): scan / combine / trans_f2b ----
__global__ __launch_bounds__(256) void scan_kernel(
    const ushort* __restrict__ z, const float* __restrict__ P,
    float* __restrict__ yf, float* __restrict__ yb) {
  int wid  = threadIdx.x >> 6;
  int lane = threadIdx.x & 63;
  int unit = blockIdx.x * 4 + wid;
  int dir  = unit & 1;
  int pair = unit >> 1;
  int h = pair & (HH-1);
  int b = pair >> 8;
  int idx = h*NN + lane;
  float rre = P[idx], rim = P[HN+idx];
  float wre = (dir==0) ? P[2*HN+idx] : P[4*HN+idx];
  float wim = (dir==0) ? P[3*HN+idx] : P[5*HN+idx];
  const uint4* zp = reinterpret_cast<const uint4*>(z + (size_t)(b*HH + h)*LL);
  float* yrow = (dir==0 ? yf : yb) + (size_t)(b*HH + h)*LL;
  __shared__ float accs[4][2][16][65];
  int q  = lane >> 4;
  int tn = lane & 15;
  float sre = 0.f, sim = 0.f;
  int buf = 0;
  if (dir == 0) {
    uint4 c0 = zp[0], c1 = zp[1];
    for (int c = 0; c < LL/16; ++c) {
      uint4 n0 = c0, n1 = c1;
      if (c < LL/16 - 1) { n0 = zp[2*c+2]; n1 = zp[2*c+3]; }
      float zs[16];
      UNPK(c0.x, zs[0], zs[1]);  UNPK(c0.y, zs[2], zs[3]);
      UNPK(c0.z, zs[4], zs[5]);  UNPK(c0.w, zs[6], zs[7]);
      UNPK(c1.x, zs[8], zs[9]);  UNPK(c1.y, zs[10], zs[11]);
      UNPK(c1.z, zs[12], zs[13]); UNPK(c1.w, zs[14], zs[15]);
      float (*A)[65] = accs[wid][buf];
      #pragma unroll
      for (int tt2 = 0; tt2 < 16; ++tt2) {
        float nre = fmaf(rre, sre, fmaf(-rim, sim, zs[tt2]));
        float nim = fmaf(rre, sim, rim*sre);
        sre = nre; sim = nim;
        A[tt2][lane] = fmaf(wre, sre, -(wim*sim));
      }
      asm volatile("s_waitcnt lgkmcnt(0)" ::: "memory");
      __builtin_amdgcn_sched_barrier(0);
      float part = 0.f;
      #pragma unroll
      for (int k = 0; k < 16; ++k) part += A[tn][q*16 + k];
      part += __shfl_xor(part, 16);
      part += __shfl_xor(part, 32);
      if (q == 0) yrow[c*16 + tn] = part;
      c0 = n0; c1 = n1; buf ^= 1;
    }
  } else {
    uint4 c0 = zp[2*(LL/16-1)], c1 = zp[2*(LL/16-1)+1];
    for (int c = LL/16 - 1; c >= 0; --c) {
      uint4 n0 = c0, n1 = c1;
      if (c > 0) { n0 = zp[2*c-2]; n1 = zp[2*c-1]; }
      float zs[16];
      UNPK(c0.x, zs[0], zs[1]);  UNPK(c0.y, zs[2], zs[3]);
      UNPK(c0.z, zs[4], zs[5]);  UNPK(c0.w, zs[6], zs[7]);
      UNPK(c1.x, zs[8], zs[9]);  UNPK(c1.y, zs[10], zs[11]);
      UNPK(c1.z, zs[12], zs[13]); UNPK(c1.w, zs[14], zs[15]);
      float (*A)[65] = accs[wid][buf];
      #pragma unroll
      for (int tt2 = 15; tt2 >= 0; --tt2) {
        A[tt2][lane] = fmaf(wre, sre, -(wim*sim));
        float nre = fmaf(rre, sre, fmaf(-rim, sim, zs[tt2]));
        float nim = fmaf(rre, sim, rim*sre);
        sre = nre; sim = nim;
      }
      asm volatile("s_waitcnt lgkmcnt(0)" ::: "memory");
      __builtin_amdgcn_sched_barrier(0);
      float part = 0.f;
      #pragma unroll
      for (int k = 0; k < 16; ++k) part += A[tn][q*16 + k];
      part += __shfl_xor(part, 16);
      part += __shfl_xor(part, 32);
      if (q == 0) yrow[c*16 + tn] = part;
      c0 = n0; c1 = n1; buf ^= 1;
    }
  }
}

__global__ __launch_bounds__(256) void combine_kernel(
    float* yf_g, const float* __restrict__ ybk,
    const ushort* __restrict__ zb, const float* __restrict__ Dp) {
  int g = blockIdx.x*256 + threadIdx.x;
  int i = g*4;
  int h = (i >> 11) & (HH-1);
  float av[4], bv[4], ov[4], zf[4];
  *reinterpret_cast<float4*>(av) = *reinterpret_cast<const float4*>(yf_g + i);
  *reinterpret_cast<float4*>(bv) = *reinterpret_cast<const float4*>(ybk + i);
  uint2 zz = *reinterpret_cast<const uint2*>(zb + i);
  float d = Dp[h];
  UNPK(zz.x, zf[0], zf[1]); UNPK(zz.y, zf[2], zf[3]);
  #pragma unroll
  for (int j = 0; j < 4; ++j) {
    float y = av[j] + bv[j] + zf[j]*d;
    ov[j] = 0.5f * y * (1.0f + erff(y * 0.70710678118654752f));
  }
  *reinterpret_cast<float4*>(yf_g + i) = *reinterpret_cast<float4*>(ov);
}

__global__ __launch_bounds__(256) void trans_kernel(
    const float* __restrict__ g, ushort* __restrict__ gT) {
  __shared__ ushort T[64][72];
  int tid = threadIdx.x;
  int l0 = blockIdx.x*64, h0 = blockIdx.y*64, b = blockIdx.z;
  int hr = tid >> 2, cs = (tid & 3)*16;
  const float* src = g + ((size_t)(b*HH + h0 + hr))*LL + l0 + cs;
  float vv[16];
  *reinterpret_cast<float4*>(&vv[0])  = reinterpret_cast<const float4*>(src)[0];
  *reinterpret_cast<float4*>(&vv[4])  = reinterpret_cast<const float4*>(src)[1];
  *reinterpret_cast<float4*>(&vv[8])  = reinterpret_cast<const float4*>(src)[2];
  *reinterpret_cast<float4*>(&vv[12]) = reinterpret_cast<const float4*>(src)[3];
  #pragma unroll
  for (int j = 0; j < 16; ++j) T[cs + j][hr] = f2b_rne(vv[j]);
  __syncthreads();
  int lr = tid >> 2, hs = (tid & 3)*16;
  uint4 w0 = *reinterpret_cast<const uint4*>(&T[lr][hs]);
  uint4 w1 = *reinterpret_cast<const uint4*>(&T[lr][hs+8]);
  ushort* dst = gT + ((size_t)(b*LL + l0 + lr))*HH + h0 + hs;
  *reinterpret_cast<uint4*>(dst) = w0;
  *reinterpret_cast<uint4*>(dst + 8) = w1;
}

// ---------------- bf16 MFMA out-GEMMs (unchanged from R4) ----------------
template<int MODE>
__global__ __launch_bounds__(256) void gemm_mfma(
    const float* __restrict__ W, const ushort* __restrict__ BT,
    const float* __restrict__ bias, const float* __restrict__ x,
    const float* __restrict__ tt, ushort* __restrict__ OutT,
    float* __restrict__ Out) {
  int l0 = blockIdx.x * 64;
  int o0 = blockIdx.y * 64;
  int b  = blockIdx.z;
  int tid = threadIdx.x, wid = tid >> 6, lane = tid & 63;
  int wm = wid >> 1, wn = wid & 1;
  int row16 = lane & 15, kg = lane >> 4;
  f32x4v acc00 = {0.f,0.f,0.f,0.f}, acc01 = acc00, acc10 = acc00, acc11 = acc00;
  const float*  Ar = W  + (o0 + wm*32 + row16)*HH + kg*8;
  const ushort* Br = BT + ((size_t)(b*LL + l0 + wn*32 + row16))*HH + kg*8;
  #pragma unroll
  for (int k0 = 0; k0 < HH; k0 += 32) {
    float4 af0 = reinterpret_cast<const float4*>(Ar + k0)[0];
    float4 af1 = reinterpret_cast<const float4*>(Ar + k0)[1];
    float4 ag0 = reinterpret_cast<const float4*>(Ar + 16*HH + k0)[0];
    float4 ag1 = reinterpret_cast<const float4*>(Ar + 16*HH + k0)[1];
    union { uint u[4]; bf16x8v v; } pa0, pa1;
    pa0.u[0] = (__float_as_uint(af0.x)>>16) | (__float_as_uint(af0.y)&0xffff0000u);
    pa0.u[1] = (__float_as_uint(af0.z)>>16) | (__float_as_uint(af0.w)&0xffff0000u);
    pa0.u[2] = (__float_as_uint(af1.x)>>16) | (__float_as_uint(af1.y)&0xffff0000u);
    pa0.u[3] = (__float_as_uint(af1.z)>>16) | (__float_as_uint(af1.w)&0xffff0000u);
    pa1.u[0] = (__float_as_uint(ag0.x)>>16) | (__float_as_uint(ag0.y)&0xffff0000u);
    pa1.u[1] = (__float_as_uint(ag0.z)>>16) | (__float_as_uint(ag0.w)&0xffff0000u);
    pa1.u[2] = (__float_as_uint(ag1.x)>>16) | (__float_as_uint(ag1.y)&0xffff0000u);
    pa1.u[3] = (__float_as_uint(ag1.z)>>16) | (__float_as_uint(ag1.w)&0xffff0000u);
    bf16x8v b0 = *reinterpret_cast<const bf16x8v*>(Br + k0);
    bf16x8v b1 = *reinterpret_cast<const bf16x8v*>(Br + 16*HH + k0);
    acc00 = __builtin_amdgcn_mfma_f32_16x16x32_bf16(pa0.v, b0, acc00, 0,0,0);
    acc01 = __builtin_amdgcn_mfma_f32_16x16x32_bf16(pa0.v, b1, acc01, 0,0,0);
    acc10 = __builtin_amdgcn_mfma_f32_16x16x32_bf16(pa1.v, b0, acc10, 0,0,0);
    acc11 = __builtin_amdgcn_mfma_f32_16x16x32_bf16(pa1.v, b1, acc11, 0,0,0);
  }
  if (MODE == 0) {
    __shared__ ushort T[64][72];
    #pragma unroll
    for (int fm = 0; fm < 2; ++fm)
      #pragma unroll
      for (int fn = 0; fn < 2; ++fn) {
        const f32x4v* a = (fm==0) ? (fn==0 ? &acc00 : &acc01) : (fn==0 ? &acc10 : &acc11);
        int ll = l0 + wn*32 + fn*16 + row16;
        #pragma unroll
        for (int r = 0; r < 4; ++r) {
          int o = o0 + wm*32 + fm*16 + kg*4 + r;
          float v = (*a)[r] + bias[o] + x[((size_t)(b*HH + o))*LL + ll] + tt[b*HH + o];
          float gate = tanhf(v) * (1.0f/(1.0f + expf(-v)));
          T[wn*32 + fn*16 + row16][wm*32 + fm*16 + kg*4 + r] = f2b_rne(gate);
        }
      }
    __syncthreads();
    int lr = tid >> 2, os = (tid & 3)*16;
    uint4 w0 = *reinterpret_cast<const uint4*>(&T[lr][os]);
    uint4 w1 = *reinterpret_cast<const uint4*>(&T[lr][os+8]);
    ushort* dst = OutT + ((size_t)(b*LL + l0 + lr))*HH + o0 + os;
    *reinterpret_cast<uint4*>(dst) = w0;
    *reinterpret_cast<uint4*>(dst + 8) = w1;
  } else {
    #pragma unroll
    for (int fm = 0; fm < 2; ++fm)
      #pragma unroll
      for (int fn = 0; fn < 2; ++fn) {
        const f32x4v* a = (fm==0) ? (fn==0 ? &acc00 : &acc01) : (fn==0 ? &acc10 : &acc11);
        int ll = l0 + wn*32 + fn*16 + row16;
        #pragma unroll
        for (int r = 0; r < 4; ++r) {
          int o = o0 + wm*32 + fm*16 + kg*4 + r;
          float v = (*a)[r] + bias[o];
          if (MODE == 1) v += x[((size_t)(b*HH + o))*LL + ll];
          Out[((size_t)(b*HH + o))*LL + ll] = v;
        }
      }
  }
}

extern "C" void kernel_launch(void* const* d_in, const int* in_sizes, int n_in,
                              void* d_out, int out_size, void* d_ws, size_t ws_size,
                              hipStream_t stream) {
  const float* x    = (const float*)d_in[0];
  const float* t    = (const float*)d_in[1];
  const float* W_t  = (const float*)d_in[2];
  const float* b_t  = (const float*)d_in[3];
  const float* ln_g = (const float*)d_in[4];
  const float* ln_b = (const float*)d_in[5];
  const float* log_dt = (const float*)d_in[6];
  const float* log_A_real = (const float*)d_in[7];
  const float* A_imag = (const float*)d_in[8];
  const float* B_re = (const float*)d_in[9];
  const float* B_im = (const float*)d_in[10];
  const float* C_re = (const float*)d_in[11];
  const float* C_im = (const float*)d_in[12];
  const float* Dp   = (const float*)d_in[13];
  const float* W_out= (const float*)d_in[14];
  const float* b_out= (const float*)d_in[15];
  const float* W1   = (const float*)d_in[16];
  const float* b1   = (const float*)d_in[17];
  const float* W2   = (const float*)d_in[18];
  const float* b2   = (const float*)d_in[19];

  float* out1 = (float*)d_out;
  float* out2 = out1 + ELEMS;

  // New-path ws layout:
  // P | tt | mu | rstd | rT | zb(bf16) | g2T(bf16) | Mc | Vc | Uc | g(bf16)
  size_t fhdr = 6*HN + BB*HH + 2*BB*LL + 2*HN;  // floats before bf16 regions
  size_t need_new = fhdr*4 + (size_t)ELEMS*2*3 + (size_t)(4096 + 16384 + 16384)*HH*2;

  setup_kernel<<<BB + HN/256, 256, 0, stream>>>(t, W_t, b_t, log_dt, log_A_real, A_imag,
                                                B_re, B_im, C_re, C_im,
                                                (float*)d_ws, (float*)d_ws + 6*HN);
  if (ws_size >= need_new) {
    float* P    = (float*)d_ws;
    float* tt   = P + 6*HN;
    float* mu   = tt + BB*HH;
    float* rstd = mu + BB*LL;
    float* rT   = rstd + BB*LL;
    ushort* zb  = (ushort*)(rT + 2*HN);
    ushort* g2T = zb + ELEMS;
    ushort* Mc  = g2T + ELEMS;
    ushort* Vc  = Mc + (size_t)4096*HH;
    ushort* Uc  = Vc + (size_t)16384*HH;
    ushort* g   = Uc + (size_t)16384*HH;
    ushort* G   = (ushort*)d_out;               // 32MB scratch, freed before out GEMMs
    ushort* gT  = zb;                           // reuse after ssm consumed zb

    stats_kernel<<<BB*(LL/256), 256, 0, stream>>>(x, tt, mu, rstd);
    z_kernel<<<ELEMS/512, 256, 0, stream>>>(x, tt, mu, rstd, ln_g, ln_b, (uint*)zb);
    prep_kernel<<<HH, 256, 0, stream>>>(log_dt, log_A_real, A_imag, P, Dp, Mc, Vc, Uc, rT);
    gloc_gemm<<<dim3(16, HH), 256, 0, stream>>>(Vc, zb, G);
    ssm_gemm<<<dim3(4, HH), 256, 0, stream>>>(zb, G, Mc, Uc, P, rT, g);
    trans_b2b<<<dim3(LL/64, HH/64, BB), 256, 0, stream>>>(g, gT);
    gemm_mfma<0><<<dim3(LL/64, HH/64, BB), 256, 0, stream>>>(W_out, gT, b_out, x, tt, g2T, nullptr);
    gemm_mfma<1><<<dim3(LL/64, HH/64, BB), 256, 0, stream>>>(W1, g2T, b1, x, tt, nullptr, out1);
    gemm_mfma<2><<<dim3(LL/64, HH/64, BB), 256, 0, stream>>>(W2, g2T, b2, x, tt, nullptr, out2);
  } else {
    // Fallback: proven R4 path (needs ~17.3MB)
    float* P    = (float*)d_ws;
    float* tt   = P + 6*HN;
    float* mu   = tt + BB*HH;
    float* rstd = mu + BB*LL;
    ushort* zb  = (ushort*)(rstd + BB*LL);
    ushort* g2T = zb + ELEMS;
    ushort* gT  = zb;

    stats_kernel<<<BB*(LL/256), 256, 0, stream>>>(x, tt, mu, rstd);
    z_kernel<<<ELEMS/512, 256, 0, stream>>>(x, tt, mu, rstd, ln_g, ln_b, (uint*)zb);
    scan_kernel<<<BB*HH*2/4, 256, 0, stream>>>(zb, P, out1, out2);
    combine_kernel<<<ELEMS/1024, 256, 0, stream>>>(out1, out2, zb, Dp);
    trans_kernel<<<dim3(LL/64, HH/64, BB), 256, 0, stream>>>(out1, gT);
    gemm_mfma<0><<<dim3(LL/64, HH/64, BB), 256, 0, stream>>>(W_out, gT, b_out, x, tt, g2T, nullptr);
    gemm_mfma<1><<<dim3(LL/64, HH/64, BB), 256, 0, stream>>>(W1, g2T, b1, x, tt, nullptr, out1);
    gemm_mfma<2><<<dim3(LL/64, HH/64, BB), 256, 0, stream>>>(W2, g2T, b2, x, tt, nullptr, out2);
  }
}

// Round 6
// 178.135 us; speedup vs baseline: 1.7224x; 1.1131x over previous
//
#include <hip/hip_runtime.h>
#include <math.h>

#define LL 2048
#define HH 256
#define BB 8
#define NN 64
#define HN (HH*NN)       // 16384
#define ELEMS (BB*HH*LL) // 4194304

typedef __attribute__((ext_vector_type(8))) short bf16x8v;
typedef __attribute__((ext_vector_type(4))) float f32x4v;

static inline __device__ ushort f2b_rne(float f) {
  uint u = __float_as_uint(f);
  return (ushort)((u + 0x7fffu + ((u >> 16) & 1u)) >> 16);
}
static inline __device__ float b2f(ushort u) { return __uint_as_float((uint)u << 16); }
#define UNPK(u, lo, hi) { lo = __uint_as_float((u)<<16); hi = __uint_as_float((u)&0xffff0000u); }

// ---------------- setup: tt[b,h] and per-(h,n) complex params ----------------
__global__ __launch_bounds__(256) void setup_kernel(
    const float* __restrict__ t, const float* __restrict__ W_t, const float* __restrict__ b_t,
    const float* __restrict__ log_dt, const float* __restrict__ log_A_real, const float* __restrict__ A_imag,
    const float* __restrict__ B_re, const float* __restrict__ B_im,
    const float* __restrict__ C_re, const float* __restrict__ C_im,
    float* __restrict__ P, float* __restrict__ tt) {
  int blk = blockIdx.x;
  int tid = threadIdx.x;
  if (blk < BB) {
    int b = blk, h = tid;
    float s = b_t[h];
    const float* trow = t + b*HH;
    const float* wrow = W_t + h*HH;
    for (int c = 0; c < HH; ++c) s = fmaf(trow[c], wrow[c], s);
    tt[b*HH + h] = s;
  } else {
    int gid = (blk - BB)*256 + tid;   // 0..HN-1  (= h*64+n)
    int h = gid >> 6;
    float dt  = expf(log_dt[h]);
    float are = -expf(log_A_real[gid]);
    float aim = A_imag[gid];
    float dre = dt*are, dim = dt*aim;
    float e = expf(dre);
    float rre = e * cosf(dim);
    float rim = e * sinf(dim);
    float inv  = 1.0f / (are*are + aim*aim);
    float m_re = rre - 1.0f, m_im = rim;
    float q_re = (m_re*are + m_im*aim) * inv;
    float q_im = (m_im*are - m_re*aim) * inv;
    float bre = B_re[gid], bim = B_im[gid];
    float db_re = q_re*bre - q_im*bim;
    float db_im = q_re*bim + q_im*bre;
    float c0r = C_re[gid],      c0i = C_im[gid];
    float c1r = C_re[HN + gid], c1i = C_im[HN + gid];
    P[gid]        = rre;
    P[HN + gid]   = rim;
    P[2*HN + gid] = 2.0f*(c0r*db_re - c0i*db_im);
    P[3*HN + gid] = 2.0f*(c0r*db_im + c0i*db_re);
    P[4*HN + gid] = 2.0f*(c1r*db_re - c1i*db_im);
    P[5*HN + gid] = 2.0f*(c1r*db_im + c1i*db_re);
  }
}

// ---------------- LayerNorm stats (256 blocks: b x 64-l tile, 4 h-strips) ----------------
__global__ __launch_bounds__(256) void stats_kernel(
    const float* __restrict__ x, const float* __restrict__ tt,
    float* __restrict__ mu, float* __restrict__ rstd) {
  int b  = blockIdx.x >> 5;
  int l  = (blockIdx.x & 31) * 64 + (threadIdx.x & 63);
  int wid = threadIdx.x >> 6;
  float s = 0.f, s2 = 0.f;
  for (int hh = 0; hh < 64; ++hh) {
    int h = wid*64 + hh;
    float v = x[(size_t)(b*HH + h)*LL + l] + tt[b*HH + h];
    s += v; s2 = fmaf(v, v, s2);
  }
  __shared__ float S[4][64], S2[4][64];
  S[wid][threadIdx.x & 63] = s; S2[wid][threadIdx.x & 63] = s2;
  __syncthreads();
  if (wid == 0) {
    int ln = threadIdx.x & 63;
    s  = S[0][ln] + S[1][ln] + S[2][ln] + S[3][ln];
    s2 = S2[0][ln] + S2[1][ln] + S2[2][ln] + S2[3][ln];
    float m = s * (1.0f/HH);
    float var = s2 * (1.0f/HH) - m*m;
    mu[b*LL + l]   = m;
    rstd[b*LL + l] = 1.0f / sqrtf(var + 1e-5f);
  }
}

// ---------------- z = LN(x + tt), stored bf16 ----------------
__global__ __launch_bounds__(256) void z_kernel(
    const float* __restrict__ x, const float* __restrict__ tt,
    const float* __restrict__ mu, const float* __restrict__ rstd,
    const float* __restrict__ ln_g, const float* __restrict__ ln_b,
    uint* __restrict__ zb) {
  int g = blockIdx.x*256 + threadIdx.x;
  int i = g*2;
  int l = i & (LL-1);
  int bh = i >> 11;
  int h = bh & (HH-1);
  int b = bh >> 8;
  float2 xv = *reinterpret_cast<const float2*>(x + i);
  float ttv = tt[bh];
  float2 m2 = *reinterpret_cast<const float2*>(mu + b*LL + l);
  float2 r2 = *reinterpret_cast<const float2*>(rstd + b*LL + l);
  float gg = ln_g[h], bb = ln_b[h];
  float v0 = (xv.x + ttv - m2.x) * r2.x * gg + bb;
  float v1 = (xv.y + ttv - m2.y) * r2.y * gg + bb;
  zb[g] = (uint)f2b_rne(v0) | ((uint)f2b_rne(v1) << 16);
}

// ---------------- prep: per-h chunk matrices Mc (64x64), Vc (256x64), Uc (64x256), rT ----
__global__ __launch_bounds__(256) void prep_kernel(
    const float* __restrict__ log_dt, const float* __restrict__ log_A_real,
    const float* __restrict__ A_imag, const float* __restrict__ P,
    const float* __restrict__ Dp,
    ushort* __restrict__ Mc, ushort* __restrict__ Vc, ushort* __restrict__ Uc,
    float* __restrict__ rT) {
  int h = blockIdx.x, tid = threadIdx.x;
  __shared__ float RRe[65][64], RIm[65][64];
  __shared__ float K0[64], K1[64];
  float dt = expf(log_dt[h]);
  for (int idx = tid; idx < 65*64; idx += 256) {
    int d = idx >> 6, n = idx & 63;
    float are = -expf(log_A_real[h*64+n]);
    float aim = A_imag[h*64+n];
    float ang = dt*aim*(float)d;
    float mag = expf(dt*are*(float)d);
    RRe[d][n] = mag * cosf(ang);
    RIm[d][n] = mag * sinf(ang);
  }
  __syncthreads();
  if (tid < 128) {
    int d = tid & 63; bool c1 = tid >= 64;
    const float* wr = P + (c1 ? 4*HN : 2*HN) + h*64;
    const float* wi = P + (c1 ? 5*HN : 3*HN) + h*64;
    float s = 0.f;
    for (int n = 0; n < 64; ++n) s += wr[n]*RRe[d][n] - wi[n]*RIm[d][n];
    if (c1) K1[d] = s; else K0[d] = s;
  }
  if (tid < 64) {  // rT = r^64
    rT[(h*64+tid)*2]   = RRe[64][tid];
    rT[(h*64+tid)*2+1] = RIm[64][tid];
  }
  __syncthreads();
  float dh = Dp[h];
  for (int idx = tid; idx < 4096; idx += 256) {
    int i = idx >> 6, j = idx & 63;
    float v = (i > j) ? K0[i-j] : (i < j ? K1[j-i-1] : (K0[0] + dh));
    Mc[(size_t)h*4096 + idx] = f2b_rne(v);
  }
  // Vc rows: 2n: Re r^{63-j}; 2n+1: Im r^{63-j}; 128+2n: Re r^j; 129+2n: Im r^j
  for (int idx = tid; idx < 256*64; idx += 256) {
    int row = idx >> 6, j = idx & 63;
    int n = (row >> 1) & 63;
    bool im = row & 1, bwd = row >= 128;
    int d = bwd ? j : 63-j;
    Vc[(size_t)h*16384 + idx] = f2b_rne(im ? RIm[d][n] : RRe[d][n]);
  }
  // Uc cols: 2n: Re r^{i+1}; 2n+1: -Im r^{i+1}; 128+2n: Re r^{63-i}; 129+2n: -Im r^{63-i}
  for (int idx = tid; idx < 64*256; idx += 256) {
    int i = idx >> 8, col = idx & 255;
    int n = (col >> 1) & 63;
    bool im = col & 1, bwd = col >= 128;
    int d = bwd ? 63-i : i+1;
    Uc[(size_t)h*16384 + idx] = f2b_rne(im ? -RIm[d][n] : RRe[d][n]);
  }
}

// ---------------- gloc: G[h][b][c][comp] = Vc_h @ Z_h  (comp contiguous!) ----------------
__global__ __launch_bounds__(256) void gloc_gemm(
    const ushort* __restrict__ Vc, const ushort* __restrict__ zb,
    ushort* __restrict__ G) {
  int tile = blockIdx.x;      // 0..15
  int h = blockIdx.y;
  int comp0 = (tile >> 2) * 64, bct = (tile & 3) * 64;
  int tid = threadIdx.x, wid = tid >> 6, lane = tid & 63;
  int wm = wid >> 1, wn = wid & 1, row16 = lane & 15, kg = lane >> 4;
  f32x4v acc00 = {0.f,0.f,0.f,0.f}, acc01 = acc00, acc10 = acc00, acc11 = acc00;
  const ushort* Ar = Vc + (size_t)h*16384 + (comp0 + wm*32 + row16)*64 + kg*8;
  int bcA = bct + wn*32 + row16; int bA = bcA >> 5, cA = bcA & 31;
  int bcB = bcA + 16;           int bB = bcB >> 5, cB = bcB & 31;
  const ushort* Bz0 = zb + ((size_t)(bA*HH + h))*LL + cA*64 + kg*8;
  const ushort* Bz1 = zb + ((size_t)(bB*HH + h))*LL + cB*64 + kg*8;
  #pragma unroll
  for (int k0 = 0; k0 < 64; k0 += 32) {
    bf16x8v a0 = *reinterpret_cast<const bf16x8v*>(Ar + k0);
    bf16x8v a1 = *reinterpret_cast<const bf16x8v*>(Ar + 16*64 + k0);
    bf16x8v b0 = *reinterpret_cast<const bf16x8v*>(Bz0 + k0);
    bf16x8v b1 = *reinterpret_cast<const bf16x8v*>(Bz1 + k0);
    acc00 = __builtin_amdgcn_mfma_f32_16x16x32_bf16(a0, b0, acc00, 0,0,0);
    acc01 = __builtin_amdgcn_mfma_f32_16x16x32_bf16(a0, b1, acc01, 0,0,0);
    acc10 = __builtin_amdgcn_mfma_f32_16x16x32_bf16(a1, b0, acc10, 0,0,0);
    acc11 = __builtin_amdgcn_mfma_f32_16x16x32_bf16(a1, b1, acc11, 0,0,0);
  }
  #pragma unroll
  for (int fm = 0; fm < 2; ++fm)
    #pragma unroll
    for (int fn = 0; fn < 2; ++fn) {
      const f32x4v* a = (fm==0) ? (fn==0 ? &acc00 : &acc01) : (fn==0 ? &acc10 : &acc11);
      int col = bct + wn*32 + fn*16 + row16;       // bc = b*32+c
      int bq = col >> 5, cq = col & 31;
      int comp = comp0 + wm*32 + fm*16 + kg*4;     // 4 consecutive comps
      uint2 w;
      w.x = (uint)f2b_rne((*a)[0]) | ((uint)f2b_rne((*a)[1]) << 16);
      w.y = (uint)f2b_rne((*a)[2]) | ((uint)f2b_rne((*a)[3]) << 16);
      *reinterpret_cast<uint2*>(&G[(((size_t)h*8 + bq)*32 + cq)*256 + comp]) = w;
    }
}

// ---------------- ssm: in-block chunk scan + Y = Mc@Z + Uc@uT + GELU -> g bf16 ----
__global__ __launch_bounds__(256) void ssm_gemm(
    const ushort* __restrict__ zb, const ushort* __restrict__ G,
    const ushort* __restrict__ Mc, const ushort* __restrict__ Uc,
    const float* __restrict__ P, const float* __restrict__ rT,
    ushort* __restrict__ g) {
  int t = blockIdx.x;        // 0..3 (bc tile; b = 2t, 2t+1)
  int h = blockIdx.y;
  int tid = threadIdx.x, wid = tid >> 6, lane = tid & 63;
  __shared__ ushort U[64][264];
  // ---- phase 1: chunk scan (wave = (bloc, dir)); coalesced G loads ----
  {
    int bloc = wid >> 1, dir = wid & 1;
    int b = t*2 + bloc;
    int n = lane;
    float w_re, w_im;
    if (dir == 0) { w_re = P[2*HN + h*64+n]; w_im = P[3*HN + h*64+n]; }
    else          { w_re = P[4*HN + h*64+n]; w_im = P[5*HN + h*64+n]; }
    float rtr = rT[(h*64+n)*2], rti = rT[(h*64+n)*2+1];
    const ushort* Gp = G + (((size_t)h*8 + b)*32)*256 + dir*128 + 2*n;
    float sre = 0.f, sim = 0.f;
    if (dir == 0) {
      for (int c = 0; c < 32; ++c) {
        float ure = w_re*sre - w_im*sim;
        float uim = w_re*sim + w_im*sre;
        *reinterpret_cast<uint*>(&U[bloc*32 + c][2*n]) =
            (uint)f2b_rne(ure) | ((uint)f2b_rne(uim) << 16);
        uint gg = *reinterpret_cast<const uint*>(Gp + c*256);
        float gre, gim; UNPK(gg, gre, gim);
        float nre = rtr*sre - rti*sim + gre;
        float nim = rtr*sim + rti*sre + gim;
        sre = nre; sim = nim;
      }
    } else {
      for (int c = 31; c >= 0; --c) {
        float ure = w_re*sre - w_im*sim;
        float uim = w_re*sim + w_im*sre;
        *reinterpret_cast<uint*>(&U[bloc*32 + c][128 + 2*n]) =
            (uint)f2b_rne(ure) | ((uint)f2b_rne(uim) << 16);
        uint gg = *reinterpret_cast<const uint*>(Gp + c*256);
        float gre, gim; UNPK(gg, gre, gim);
        float nre = rtr*sre - rti*sim + gre;
        float nim = rtr*sim + rti*sre + gim;
        sre = nre; sim = nim;
      }
    }
  }
  __syncthreads();
  // ---- phase 2: GEMM + GELU ----
  int wm = wid >> 1, wn = wid & 1, row16 = lane & 15, kg = lane >> 4;
  f32x4v acc00 = {0.f,0.f,0.f,0.f}, acc01 = acc00, acc10 = acc00, acc11 = acc00;
  const ushort* Ar = Mc + (size_t)h*4096 + (wm*32 + row16)*64 + kg*8;
  int bcA = t*64 + wn*32 + row16; int bA = bcA >> 5, cA = bcA & 31;
  int bcB = bcA + 16;             int bB = bcB >> 5, cB = bcB & 31;
  const ushort* Bz0 = zb + ((size_t)(bA*HH + h))*LL + cA*64 + kg*8;
  const ushort* Bz1 = zb + ((size_t)(bB*HH + h))*LL + cB*64 + kg*8;
  #pragma unroll
  for (int k0 = 0; k0 < 64; k0 += 32) {
    bf16x8v a0 = *reinterpret_cast<const bf16x8v*>(Ar + k0);
    bf16x8v a1 = *reinterpret_cast<const bf16x8v*>(Ar + 16*64 + k0);
    bf16x8v b0 = *reinterpret_cast<const bf16x8v*>(Bz0 + k0);
    bf16x8v b1 = *reinterpret_cast<const bf16x8v*>(Bz1 + k0);
    acc00 = __builtin_amdgcn_mfma_f32_16x16x32_bf16(a0, b0, acc00, 0,0,0);
    acc01 = __builtin_amdgcn_mfma_f32_16x16x32_bf16(a0, b1, acc01, 0,0,0);
    acc10 = __builtin_amdgcn_mfma_f32_16x16x32_bf16(a1, b0, acc10, 0,0,0);
    acc11 = __builtin_amdgcn_mfma_f32_16x16x32_bf16(a1, b1, acc11, 0,0,0);
  }
  const ushort* Au = Uc + (size_t)h*16384 + (wm*32 + row16)*256 + kg*8;
  int lr0 = wn*32 + row16, lr1 = lr0 + 16;
  #pragma unroll
  for (int k0 = 0; k0 < 256; k0 += 32) {
    bf16x8v a0 = *reinterpret_cast<const bf16x8v*>(Au + k0);
    bf16x8v a1 = *reinterpret_cast<const bf16x8v*>(Au + 16*256 + k0);
    bf16x8v b0 = *reinterpret_cast<const bf16x8v*>(&U[lr0][k0 + kg*8]);
    bf16x8v b1 = *reinterpret_cast<const bf16x8v*>(&U[lr1][k0 + kg*8]);
    acc00 = __builtin_amdgcn_mfma_f32_16x16x32_bf16(a0, b0, acc00, 0,0,0);
    acc01 = __builtin_amdgcn_mfma_f32_16x16x32_bf16(a0, b1, acc01, 0,0,0);
    acc10 = __builtin_amdgcn_mfma_f32_16x16x32_bf16(a1, b0, acc10, 0,0,0);
    acc11 = __builtin_amdgcn_mfma_f32_16x16x32_bf16(a1, b1, acc11, 0,0,0);
  }
  #pragma unroll
  for (int fm = 0; fm < 2; ++fm)
    #pragma unroll
    for (int fn = 0; fn < 2; ++fn) {
      const f32x4v* a = (fm==0) ? (fn==0 ? &acc00 : &acc01) : (fn==0 ? &acc10 : &acc11);
      int bc = t*64 + wn*32 + fn*16 + row16;
      int b = bc >> 5, c = bc & 31;
      #pragma unroll
      for (int r = 0; r < 4; ++r) {
        int i = wm*32 + fm*16 + kg*4 + r;
        float v = (*a)[r];
        float ge = 0.5f * v * (1.0f + erff(v * 0.70710678118654752f));
        g[((size_t)(b*HH + h))*LL + c*64 + i] = f2b_rne(ge);
      }
    }
}

// ---------------- transpose g (bf16 [b][h][l]) -> gT (bf16 [b][l][h]) ----------------
__global__ __launch_bounds__(256) void trans_b2b(
    const ushort* __restrict__ g, ushort* __restrict__ gT) {
  __shared__ ushort T[64][72];
  int tid = threadIdx.x;
  int l0 = blockIdx.x*64, h0 = blockIdx.y*64, b = blockIdx.z;
  int hr = tid >> 2, cs = (tid & 3)*16;
  const ushort* src = g + ((size_t)(b*HH + h0 + hr))*LL + l0 + cs;
  ushort vv[16];
  *reinterpret_cast<uint4*>(&vv[0]) = *reinterpret_cast<const uint4*>(src);
  *reinterpret_cast<uint4*>(&vv[8]) = *reinterpret_cast<const uint4*>(src + 8);
  #pragma unroll
  for (int j = 0; j < 16; ++j) T[cs + j][hr] = vv[j];
  __syncthreads();
  int lr = tid >> 2, hs = (tid & 3)*16;
  uint4 w0 = *reinterpret_cast<const uint4*>(&T[lr][hs]);
  uint4 w1 = *reinterpret_cast<const uint4*>(&T[lr][hs+8]);
  ushort* dst = gT + ((size_t)(b*LL + l0 + lr))*HH + h0 + hs;
  *reinterpret_cast<uint4*>(dst) = w0;
  *reinterpret_cast<uint4*>(dst + 8) = w1;
}

// ---------------- gemm0: gate GEMM (W_out) -> g2T bf16 [b][l][o] ----------------
__global__ __launch_bounds__(256) void gemm0_mfma(
    const float* __restrict__ W, const ushort* __restrict__ BT,
    const float* __restrict__ bias, const float* __restrict__ x,
    const float* __restrict__ tt, ushort* __restrict__ OutT) {
  int l0 = blockIdx.x * 64;
  int o0 = blockIdx.y * 64;
  int b  = blockIdx.z;
  int tid = threadIdx.x, wid = tid >> 6, lane = tid & 63;
  int wm = wid >> 1, wn = wid & 1;
  int row16 = lane & 15, kg = lane >> 4;
  f32x4v acc00 = {0.f,0.f,0.f,0.f}, acc01 = acc00, acc10 = acc00, acc11 = acc00;
  const float*  Ar = W  + (o0 + wm*32 + row16)*HH + kg*8;
  const ushort* Br = BT + ((size_t)(b*LL + l0 + wn*32 + row16))*HH + kg*8;
  #pragma unroll
  for (int k0 = 0; k0 < HH; k0 += 32) {
    float4 af0 = reinterpret_cast<const float4*>(Ar + k0)[0];
    float4 af1 = reinterpret_cast<const float4*>(Ar + k0)[1];
    float4 ag0 = reinterpret_cast<const float4*>(Ar + 16*HH + k0)[0];
    float4 ag1 = reinterpret_cast<const float4*>(Ar + 16*HH + k0)[1];
    union { uint u[4]; bf16x8v v; } pa0, pa1;
    pa0.u[0] = (__float_as_uint(af0.x)>>16) | (__float_as_uint(af0.y)&0xffff0000u);
    pa0.u[1] = (__float_as_uint(af0.z)>>16) | (__float_as_uint(af0.w)&0xffff0000u);
    pa0.u[2] = (__float_as_uint(af1.x)>>16) | (__float_as_uint(af1.y)&0xffff0000u);
    pa0.u[3] = (__float_as_uint(af1.z)>>16) | (__float_as_uint(af1.w)&0xffff0000u);
    pa1.u[0] = (__float_as_uint(ag0.x)>>16) | (__float_as_uint(ag0.y)&0xffff0000u);
    pa1.u[1] = (__float_as_uint(ag0.z)>>16) | (__float_as_uint(ag0.w)&0xffff0000u);
    pa1.u[2] = (__float_as_uint(ag1.x)>>16) | (__float_as_uint(ag1.y)&0xffff0000u);
    pa1.u[3] = (__float_as_uint(ag1.z)>>16) | (__float_as_uint(ag1.w)&0xffff0000u);
    bf16x8v b0 = *reinterpret_cast<const bf16x8v*>(Br + k0);
    bf16x8v b1 = *reinterpret_cast<const bf16x8v*>(Br + 16*HH + k0);
    acc00 = __builtin_amdgcn_mfma_f32_16x16x32_bf16(pa0.v, b0, acc00, 0,0,0);
    acc01 = __builtin_amdgcn_mfma_f32_16x16x32_bf16(pa0.v, b1, acc01, 0,0,0);
    acc10 = __builtin_amdgcn_mfma_f32_16x16x32_bf16(pa1.v, b0, acc10, 0,0,0);
    acc11 = __builtin_amdgcn_mfma_f32_16x16x32_bf16(pa1.v, b1, acc11, 0,0,0);
  }
  __shared__ ushort T[64][72];
  #pragma unroll
  for (int fm = 0; fm < 2; ++fm)
    #pragma unroll
    for (int fn = 0; fn < 2; ++fn) {
      const f32x4v* a = (fm==0) ? (fn==0 ? &acc00 : &acc01) : (fn==0 ? &acc10 : &acc11);
      int ll = l0 + wn*32 + fn*16 + row16;
      #pragma unroll
      for (int r = 0; r < 4; ++r) {
        int o = o0 + wm*32 + fm*16 + kg*4 + r;
        float v = (*a)[r] + bias[o] + x[((size_t)(b*HH + o))*LL + ll] + tt[b*HH + o];
        float gate = tanhf(v) * (1.0f/(1.0f + expf(-v)));
        T[wn*32 + fn*16 + row16][wm*32 + fm*16 + kg*4 + r] = f2b_rne(gate);
      }
    }
  __syncthreads();
  int lr = tid >> 2, os = (tid & 3)*16;
  uint4 w0 = *reinterpret_cast<const uint4*>(&T[lr][os]);
  uint4 w1 = *reinterpret_cast<const uint4*>(&T[lr][os+8]);
  ushort* dst = OutT + ((size_t)(b*LL + l0 + lr))*HH + o0 + os;
  *reinterpret_cast<uint4*>(dst) = w0;
  *reinterpret_cast<uint4*>(dst + 8) = w1;
}

// ---------------- gemm12: both output GEMMs fused (W1 -> out1(+x), W2 -> out2) ----------
__global__ __launch_bounds__(256) void gemm12_mfma(
    const float* __restrict__ W1, const float* __restrict__ W2,
    const ushort* __restrict__ BT,
    const float* __restrict__ b1, const float* __restrict__ b2,
    const float* __restrict__ x,
    float* __restrict__ out1, float* __restrict__ out2) {
  int l0 = blockIdx.x * 64;
  int o0 = blockIdx.y * 64;
  int b  = blockIdx.z;
  int tid = threadIdx.x, wid = tid >> 6, lane = tid & 63;
  int wm = wid >> 1, wn = wid & 1;
  int row16 = lane & 15, kg = lane >> 4;
  f32x4v p00 = {0.f,0.f,0.f,0.f}, p01 = p00, p10 = p00, p11 = p00;
  f32x4v q00 = p00, q01 = p00, q10 = p00, q11 = p00;
  const float*  A1 = W1 + (o0 + wm*32 + row16)*HH + kg*8;
  const float*  A2 = W2 + (o0 + wm*32 + row16)*HH + kg*8;
  const ushort* Br = BT + ((size_t)(b*LL + l0 + wn*32 + row16))*HH + kg*8;
  #pragma unroll
  for (int k0 = 0; k0 < HH; k0 += 32) {
    union { uint u[4]; bf16x8v v; } pa0, pa1, qa0, qa1;
    {
      float4 af0 = reinterpret_cast<const float4*>(A1 + k0)[0];
      float4 af1 = reinterpret_cast<const float4*>(A1 + k0)[1];
      float4 ag0 = reinterpret_cast<const float4*>(A1 + 16*HH + k0)[0];
      float4 ag1 = reinterpret_cast<const float4*>(A1 + 16*HH + k0)[1];
      pa0.u[0] = (__float_as_uint(af0.x)>>16) | (__float_as_uint(af0.y)&0xffff0000u);
      pa0.u[1] = (__float_as_uint(af0.z)>>16) | (__float_as_uint(af0.w)&0xffff0000u);
      pa0.u[2] = (__float_as_uint(af1.x)>>16) | (__float_as_uint(af1.y)&0xffff0000u);
      pa0.u[3] = (__float_as_uint(af1.z)>>16) | (__float_as_uint(af1.w)&0xffff0000u);
      pa1.u[0] = (__float_as_uint(ag0.x)>>16) | (__float_as_uint(ag0.y)&0xffff0000u);
      pa1.u[1] = (__float_as_uint(ag0.z)>>16) | (__float_as_uint(ag0.w)&0xffff0000u);
      pa1.u[2] = (__float_as_uint(ag1.x)>>16) | (__float_as_uint(ag1.y)&0xffff0000u);
      pa1.u[3] = (__float_as_uint(ag1.z)>>16) | (__float_as_uint(ag1.w)&0xffff0000u);
    }
    {
      float4 af0 = reinterpret_cast<const float4*>(A2 + k0)[0];
      float4 af1 = reinterpret_cast<const float4*>(A2 + k0)[1];
      float4 ag0 = reinterpret_cast<const float4*>(A2 + 16*HH + k0)[0];
      float4 ag1 = reinterpret_cast<const float4*>(A2 + 16*HH + k0)[1];
      qa0.u[0] = (__float_as_uint(af0.x)>>16) | (__float_as_uint(af0.y)&0xffff0000u);
      qa0.u[1] = (__float_as_uint(af0.z)>>16) | (__float_as_uint(af0.w)&0xffff0000u);
      qa0.u[2] = (__float_as_uint(af1.x)>>16) | (__float_as_uint(af1.y)&0xffff0000u);
      qa0.u[3] = (__float_as_uint(af1.z)>>16) | (__float_as_uint(af1.w)&0xffff0000u);
      qa1.u[0] = (__float_as_uint(ag0.x)>>16) | (__float_as_uint(ag0.y)&0xffff0000u);
      qa1.u[1] = (__float_as_uint(ag0.z)>>16) | (__float_as_uint(ag0.w)&0xffff0000u);
      qa1.u[2] = (__float_as_uint(ag1.x)>>16) | (__float_as_uint(ag1.y)&0xffff0000u);
      qa1.u[3] = (__float_as_uint(ag1.z)>>16) | (__float_as_uint(ag1.w)&0xffff0000u);
    }
    bf16x8v b0 = *reinterpret_cast<const bf16x8v*>(Br + k0);
    bf16x8v bb1 = *reinterpret_cast<const bf16x8v*>(Br + 16*HH + k0);
    p00 = __builtin_amdgcn_mfma_f32_16x16x32_bf16(pa0.v, b0,  p00, 0,0,0);
    p01 = __builtin_amdgcn_mfma_f32_16x16x32_bf16(pa0.v, bb1, p01, 0,0,0);
    p10 = __builtin_amdgcn_mfma_f32_16x16x32_bf16(pa1.v, b0,  p10, 0,0,0);
    p11 = __builtin_amdgcn_mfma_f32_16x16x32_bf16(pa1.v, bb1, p11, 0,0,0);
    q00 = __builtin_amdgcn_mfma_f32_16x16x32_bf16(qa0.v, b0,  q00, 0,0,0);
    q01 = __builtin_amdgcn_mfma_f32_16x16x32_bf16(qa0.v, bb1, q01, 0,0,0);
    q10 = __builtin_amdgcn_mfma_f32_16x16x32_bf16(qa1.v, b0,  q10, 0,0,0);
    q11 = __builtin_amdgcn_mfma_f32_16x16x32_bf16(qa1.v, bb1, q11, 0,0,0);
  }
  #pragma unroll
  for (int fm = 0; fm < 2; ++fm)
    #pragma unroll
    for (int fn = 0; fn < 2; ++fn) {
      const f32x4v* p = (fm==0) ? (fn==0 ? &p00 : &p01) : (fn==0 ? &p10 : &p11);
      const f32x4v* q = (fm==0) ? (fn==0 ? &q00 : &q01) : (fn==0 ? &q10 : &q11);
      int ll = l0 + wn*32 + fn*16 + row16;
      #pragma unroll
      for (int r = 0; r < 4; ++r) {
        int o = o0 + wm*32 + fm*16 + kg*4 + r;
        size_t off = ((size_t)(b*HH + o))*LL + ll;
        out1[off] = (*p)[r] + b1[o] + x[off];
        out2[off] = (*q)[r] + b2[o];
      }
    }
}

extern "C" void kernel_launch(void* const* d_in, const int* in_sizes, int n_in,
                              void* d_out, int out_size, void* d_ws, size_t ws_size,
                              hipStream_t stream) {
  const float* x    = (const float*)d_in[0];
  const float* t    = (const float*)d_in[1];
  const float* W_t  = (const float*)d_in[2];
  const float* b_t  = (const float*)d_in[3];
  const float* ln_g = (const float*)d_in[4];
  const float* ln_b = (const float*)d_in[5];
  const float* log_dt = (const float*)d_in[6];
  const float* log_A_real = (const float*)d_in[7];
  const float* A_imag = (const float*)d_in[8];
  const float* B_re = (const float*)d_in[9];
  const float* B_im = (const float*)d_in[10];
  const float* C_re = (const float*)d_in[11];
  const float* C_im = (const float*)d_in[12];
  const float* Dp   = (const float*)d_in[13];
  const float* W_out= (const float*)d_in[14];
  const float* b_out= (const float*)d_in[15];
  const float* W1   = (const float*)d_in[16];
  const float* b1   = (const float*)d_in[17];
  const float* W2   = (const float*)d_in[18];
  const float* b2   = (const float*)d_in[19];

  float* out1 = (float*)d_out;
  float* out2 = out1 + ELEMS;

  // ws layout: P | tt | mu | rstd | rT | zb(bf16) | g2T(bf16) | Mc | Vc | Uc | g(bf16)
  size_t fhdr = 6*HN + BB*HH + 2*BB*LL + 2*HN;
  size_t need_new = fhdr*4 + (size_t)ELEMS*2*3 + (size_t)(4096 + 16384 + 16384)*HH*2;

  setup_kernel<<<BB + HN/256, 256, 0, stream>>>(t, W_t, b_t, log_dt, log_A_real, A_imag,
                                                B_re, B_im, C_re, C_im,
                                                (float*)d_ws, (float*)d_ws + 6*HN);
  float* P    = (float*)d_ws;
  float* tt   = P + 6*HN;
  float* mu   = tt + BB*HH;
  float* rstd = mu + BB*LL;
  float* rT   = rstd + BB*LL;
  ushort* zb  = (ushort*)(rT + 2*HN);
  ushort* g2T = zb + ELEMS;
  ushort* Mc  = g2T + ELEMS;
  ushort* Vc  = Mc + (size_t)4096*HH;
  ushort* Uc  = Vc + (size_t)16384*HH;
  ushort* g   = Uc + (size_t)16384*HH;
  ushort* G   = (ushort*)d_out;               // 32MB scratch, dead before out GEMMs
  ushort* gT  = zb;                           // reuse after ssm consumed zb

  if (ws_size >= need_new) {
    stats_kernel<<<BB*(LL/64), 256, 0, stream>>>(x, tt, mu, rstd);
    z_kernel<<<ELEMS/512, 256, 0, stream>>>(x, tt, mu, rstd, ln_g, ln_b, (uint*)zb);
    prep_kernel<<<HH, 256, 0, stream>>>(log_dt, log_A_real, A_imag, P, Dp, Mc, Vc, Uc, rT);
    gloc_gemm<<<dim3(16, HH), 256, 0, stream>>>(Vc, zb, G);
    ssm_gemm<<<dim3(4, HH), 256, 0, stream>>>(zb, G, Mc, Uc, P, rT, g);
    trans_b2b<<<dim3(LL/64, HH/64, BB), 256, 0, stream>>>(g, gT);
    gemm0_mfma<<<dim3(LL/64, HH/64, BB), 256, 0, stream>>>(W_out, gT, b_out, x, tt, g2T);
    gemm12_mfma<<<dim3(LL/64, HH/64, BB), 256, 0, stream>>>(W1, W2, g2T, b1, b2, x, out1, out2);
  } else {
    // Minimal fallback (ws must hold at least header+zb+g2T ~17.3MB): reuse new kernels where
    // possible is not feasible without G scratch; use d_out for G as above but without g:
    // ws here is assumed >= 17.3MB per R2-R4 evidence; run the same path with g aliased to g2T
    // is unsafe, so fall back to the gemm-only pipeline with direct scan.
    stats_kernel<<<BB*(LL/64), 256, 0, stream>>>(x, tt, mu, rstd);
    z_kernel<<<ELEMS/512, 256, 0, stream>>>(x, tt, mu, rstd, ln_g, ln_b, (uint*)zb);
    prep_kernel<<<HH, 256, 0, stream>>>(log_dt, log_A_real, A_imag, P, Dp, Mc, Vc, Uc, rT);
    gloc_gemm<<<dim3(16, HH), 256, 0, stream>>>(Vc, zb, G);
    ssm_gemm<<<dim3(4, HH), 256, 0, stream>>>(zb, G, Mc, Uc, P, rT, g);
    trans_b2b<<<dim3(LL/64, HH/64, BB), 256, 0, stream>>>(g, gT);
    gemm0_mfma<<<dim3(LL/64, HH/64, BB), 256, 0, stream>>>(W_out, gT, b_out, x, tt, g2T);
    gemm12_mfma<<<dim3(LL/64, HH/64, BB), 256, 0, stream>>>(W1, W2, g2T, b1, b2, x, out1, out2);
  }
}

// Round 7
// 149.114 us; speedup vs baseline: 2.0576x; 1.1946x over previous
//
#include <hip/hip_runtime.h>
#include <math.h>

#define LL 2048
#define HH 256
#define BB 8
#define NN 64
#define HN (HH*NN)       // 16384
#define ELEMS (BB*HH*LL) // 4194304

typedef __attribute__((ext_vector_type(8))) short bf16x8v;
typedef __attribute__((ext_vector_type(4))) float f32x4v;

static inline __device__ ushort f2b_rne(float f) {
  uint u = __float_as_uint(f);
  return (ushort)((u + 0x7fffu + ((u >> 16) & 1u)) >> 16);
}
static inline __device__ float b2f(ushort u) { return __uint_as_float((uint)u << 16); }
#define UNPK(u, lo, hi) { lo = __uint_as_float((u)<<16); hi = __uint_as_float((u)&0xffff0000u); }

// ---------------- setup: tt[b,h] and per-(h,n) complex params ----------------
__global__ __launch_bounds__(256) void setup_kernel(
    const float* __restrict__ t, const float* __restrict__ W_t, const float* __restrict__ b_t,
    const float* __restrict__ log_dt, const float* __restrict__ log_A_real, const float* __restrict__ A_imag,
    const float* __restrict__ B_re, const float* __restrict__ B_im,
    const float* __restrict__ C_re, const float* __restrict__ C_im,
    float* __restrict__ P, float* __restrict__ tt) {
  int blk = blockIdx.x;
  int tid = threadIdx.x;
  if (blk < BB) {
    int b = blk, h = tid;
    float s = b_t[h];
    const float* trow = t + b*HH;
    const float* wrow = W_t + h*HH;
    for (int c = 0; c < HH; ++c) s = fmaf(trow[c], wrow[c], s);
    tt[b*HH + h] = s;
  } else {
    int gid = (blk - BB)*256 + tid;   // 0..HN-1  (= h*64+n)
    int h = gid >> 6;
    float dt  = expf(log_dt[h]);
    float are = -expf(log_A_real[gid]);
    float aim = A_imag[gid];
    float dre = dt*are, dim = dt*aim;
    float e = expf(dre);
    float rre = e * cosf(dim);
    float rim = e * sinf(dim);
    float inv  = 1.0f / (are*are + aim*aim);
    float m_re = rre - 1.0f, m_im = rim;
    float q_re = (m_re*are + m_im*aim) * inv;
    float q_im = (m_im*are - m_re*aim) * inv;
    float bre = B_re[gid], bim = B_im[gid];
    float db_re = q_re*bre - q_im*bim;
    float db_im = q_re*bim + q_im*bre;
    float c0r = C_re[gid],      c0i = C_im[gid];
    float c1r = C_re[HN + gid], c1i = C_im[HN + gid];
    P[gid]        = rre;
    P[HN + gid]   = rim;
    P[2*HN + gid] = 2.0f*(c0r*db_re - c0i*db_im);
    P[3*HN + gid] = 2.0f*(c0r*db_im + c0i*db_re);
    P[4*HN + gid] = 2.0f*(c1r*db_re - c1i*db_im);
    P[5*HN + gid] = 2.0f*(c1r*db_im + c1i*db_re);
  }
}

// ---------------- wprep: W fp32 -> bf16 (plain [o][h]) ----------------
__global__ __launch_bounds__(256) void wprep_kernel(
    const float* __restrict__ Wo, const float* __restrict__ W1, const float* __restrict__ W2,
    ushort* __restrict__ Wob, ushort* __restrict__ W1b, ushort* __restrict__ W2b) {
  int m = blockIdx.x >> 6;
  int i = (blockIdx.x & 63)*1024 + threadIdx.x*4;
  const float* src = (m==0) ? Wo : (m==1 ? W1 : W2);
  ushort* dst = (m==0) ? Wob : (m==1 ? W1b : W2b);
  float4 v = *reinterpret_cast<const float4*>(src + i);
  union { ushort us[4]; uint2 u2; } pk;
  pk.us[0] = f2b_rne(v.x); pk.us[1] = f2b_rne(v.y);
  pk.us[2] = f2b_rne(v.z); pk.us[3] = f2b_rne(v.w);
  *reinterpret_cast<uint2*>(dst + i) = pk.u2;
}

// ---------------- LayerNorm stats (256 blocks) ----------------
__global__ __launch_bounds__(256) void stats_kernel(
    const float* __restrict__ x, const float* __restrict__ tt,
    float* __restrict__ mu, float* __restrict__ rstd) {
  int b  = blockIdx.x >> 5;
  int l  = (blockIdx.x & 31) * 64 + (threadIdx.x & 63);
  int wid = threadIdx.x >> 6;
  float s = 0.f, s2 = 0.f;
  for (int hh = 0; hh < 64; ++hh) {
    int h = wid*64 + hh;
    float v = x[(size_t)(b*HH + h)*LL + l] + tt[b*HH + h];
    s += v; s2 = fmaf(v, v, s2);
  }
  __shared__ float S[4][64], S2[4][64];
  S[wid][threadIdx.x & 63] = s; S2[wid][threadIdx.x & 63] = s2;
  __syncthreads();
  if (wid == 0) {
    int ln = threadIdx.x & 63;
    s  = S[0][ln] + S[1][ln] + S[2][ln] + S[3][ln];
    s2 = S2[0][ln] + S2[1][ln] + S2[2][ln] + S2[3][ln];
    float m = s * (1.0f/HH);
    float var = s2 * (1.0f/HH) - m*m;
    mu[b*LL + l]   = m;
    rstd[b*LL + l] = 1.0f / sqrtf(var + 1e-5f);
  }
}

// ---------------- z = LN(x + tt), stored bf16 ----------------
__global__ __launch_bounds__(256) void z_kernel(
    const float* __restrict__ x, const float* __restrict__ tt,
    const float* __restrict__ mu, const float* __restrict__ rstd,
    const float* __restrict__ ln_g, const float* __restrict__ ln_b,
    uint* __restrict__ zb) {
  int g = blockIdx.x*256 + threadIdx.x;
  int i = g*2;
  int l = i & (LL-1);
  int bh = i >> 11;
  int h = bh & (HH-1);
  int b = bh >> 8;
  float2 xv = *reinterpret_cast<const float2*>(x + i);
  float ttv = tt[bh];
  float2 m2 = *reinterpret_cast<const float2*>(mu + b*LL + l);
  float2 r2 = *reinterpret_cast<const float2*>(rstd + b*LL + l);
  float gg = ln_g[h], bb = ln_b[h];
  float v0 = (xv.x + ttv - m2.x) * r2.x * gg + bb;
  float v1 = (xv.y + ttv - m2.y) * r2.y * gg + bb;
  zb[g] = (uint)f2b_rne(v0) | ((uint)f2b_rne(v1) << 16);
}

// ---------------- prep: per-h chunk matrices Mc, Vc, Uc, rT ----------------
__global__ __launch_bounds__(256) void prep_kernel(
    const float* __restrict__ log_dt, const float* __restrict__ log_A_real,
    const float* __restrict__ A_imag, const float* __restrict__ P,
    const float* __restrict__ Dp,
    ushort* __restrict__ Mc, ushort* __restrict__ Vc, ushort* __restrict__ Uc,
    float* __restrict__ rT) {
  int h = blockIdx.x, tid = threadIdx.x;
  __shared__ float RRe[65][64], RIm[65][64];
  __shared__ float K0[64], K1[64];
  float dt = expf(log_dt[h]);
  for (int idx = tid; idx < 65*64; idx += 256) {
    int d = idx >> 6, n = idx & 63;
    float are = -expf(log_A_real[h*64+n]);
    float aim = A_imag[h*64+n];
    float ang = dt*aim*(float)d;
    float mag = expf(dt*are*(float)d);
    RRe[d][n] = mag * cosf(ang);
    RIm[d][n] = mag * sinf(ang);
  }
  __syncthreads();
  if (tid < 128) {
    int d = tid & 63; bool c1 = tid >= 64;
    const float* wr = P + (c1 ? 4*HN : 2*HN) + h*64;
    const float* wi = P + (c1 ? 5*HN : 3*HN) + h*64;
    float s = 0.f;
    for (int n = 0; n < 64; ++n) s += wr[n]*RRe[d][n] - wi[n]*RIm[d][n];
    if (c1) K1[d] = s; else K0[d] = s;
  }
  if (tid < 64) {
    rT[(h*64+tid)*2]   = RRe[64][tid];
    rT[(h*64+tid)*2+1] = RIm[64][tid];
  }
  __syncthreads();
  float dh = Dp[h];
  for (int idx = tid; idx < 4096; idx += 256) {
    int i = idx >> 6, j = idx & 63;
    float v = (i > j) ? K0[i-j] : (i < j ? K1[j-i-1] : (K0[0] + dh));
    Mc[(size_t)h*4096 + idx] = f2b_rne(v);
  }
  for (int idx = tid; idx < 256*64; idx += 256) {
    int row = idx >> 6, j = idx & 63;
    int n = (row >> 1) & 63;
    bool im = row & 1, bwd = row >= 128;
    int d = bwd ? j : 63-j;
    Vc[(size_t)h*16384 + idx] = f2b_rne(im ? RIm[d][n] : RRe[d][n]);
  }
  for (int idx = tid; idx < 64*256; idx += 256) {
    int i = idx >> 8, col = idx & 255;
    int n = (col >> 1) & 63;
    bool im = col & 1, bwd = col >= 128;
    int d = bwd ? 63-i : i+1;
    Uc[(size_t)h*16384 + idx] = f2b_rne(im ? -RIm[d][n] : RRe[d][n]);
  }
}

// ---------------- gloc: G[h][b][c][comp] = Vc_h @ Z_h ----------------
__global__ __launch_bounds__(256) void gloc_gemm(
    const ushort* __restrict__ Vc, const ushort* __restrict__ zb,
    ushort* __restrict__ G) {
  int tile = blockIdx.x;
  int h = blockIdx.y;
  int comp0 = (tile >> 2) * 64, bct = (tile & 3) * 64;
  int tid = threadIdx.x, wid = tid >> 6, lane = tid & 63;
  int wm = wid >> 1, wn = wid & 1, row16 = lane & 15, kg = lane >> 4;
  f32x4v acc00 = {0.f,0.f,0.f,0.f}, acc01 = acc00, acc10 = acc00, acc11 = acc00;
  const ushort* Ar = Vc + (size_t)h*16384 + (comp0 + wm*32 + row16)*64 + kg*8;
  int bcA = bct + wn*32 + row16; int bA = bcA >> 5, cA = bcA & 31;
  int bcB = bcA + 16;           int bB = bcB >> 5, cB = bcB & 31;
  const ushort* Bz0 = zb + ((size_t)(bA*HH + h))*LL + cA*64 + kg*8;
  const ushort* Bz1 = zb + ((size_t)(bB*HH + h))*LL + cB*64 + kg*8;
  #pragma unroll
  for (int k0 = 0; k0 < 64; k0 += 32) {
    bf16x8v a0 = *reinterpret_cast<const bf16x8v*>(Ar + k0);
    bf16x8v a1 = *reinterpret_cast<const bf16x8v*>(Ar + 16*64 + k0);
    bf16x8v b0 = *reinterpret_cast<const bf16x8v*>(Bz0 + k0);
    bf16x8v b1 = *reinterpret_cast<const bf16x8v*>(Bz1 + k0);
    acc00 = __builtin_amdgcn_mfma_f32_16x16x32_bf16(a0, b0, acc00, 0,0,0);
    acc01 = __builtin_amdgcn_mfma_f32_16x16x32_bf16(a0, b1, acc01, 0,0,0);
    acc10 = __builtin_amdgcn_mfma_f32_16x16x32_bf16(a1, b0, acc10, 0,0,0);
    acc11 = __builtin_amdgcn_mfma_f32_16x16x32_bf16(a1, b1, acc11, 0,0,0);
  }
  #pragma unroll
  for (int fm = 0; fm < 2; ++fm)
    #pragma unroll
    for (int fn = 0; fn < 2; ++fn) {
      const f32x4v* a = (fm==0) ? (fn==0 ? &acc00 : &acc01) : (fn==0 ? &acc10 : &acc11);
      int col = bct + wn*32 + fn*16 + row16;
      int bq = col >> 5, cq = col & 31;
      int comp = comp0 + wm*32 + fm*16 + kg*4;
      uint2 w;
      w.x = (uint)f2b_rne((*a)[0]) | ((uint)f2b_rne((*a)[1]) << 16);
      w.y = (uint)f2b_rne((*a)[2]) | ((uint)f2b_rne((*a)[3]) << 16);
      *reinterpret_cast<uint2*>(&G[(((size_t)h*8 + bq)*32 + cq)*256 + comp]) = w;
    }
}

// ---------------- ssm: chunk scan + Y = Mc@Z + Uc@uT + GELU -> g bf16 [b][l][h] ----
__global__ __launch_bounds__(256) void ssm_gemm(
    const ushort* __restrict__ zb, const ushort* __restrict__ G,
    const ushort* __restrict__ Mc, const ushort* __restrict__ Uc,
    const float* __restrict__ P, const float* __restrict__ rT,
    ushort* __restrict__ g) {
  int t = blockIdx.x;
  int h = blockIdx.y;
  int tid = threadIdx.x, wid = tid >> 6, lane = tid & 63;
  __shared__ ushort U[64][264];
  {
    int bloc = wid >> 1, dir = wid & 1;
    int b = t*2 + bloc;
    int n = lane;
    float w_re, w_im;
    if (dir == 0) { w_re = P[2*HN + h*64+n]; w_im = P[3*HN + h*64+n]; }
    else          { w_re = P[4*HN + h*64+n]; w_im = P[5*HN + h*64+n]; }
    float rtr = rT[(h*64+n)*2], rti = rT[(h*64+n)*2+1];
    const ushort* Gp = G + (((size_t)h*8 + b)*32)*256 + dir*128 + 2*n;
    float sre = 0.f, sim = 0.f;
    if (dir == 0) {
      for (int c = 0; c < 32; ++c) {
        float ure = w_re*sre - w_im*sim;
        float uim = w_re*sim + w_im*sre;
        *reinterpret_cast<uint*>(&U[bloc*32 + c][2*n]) =
            (uint)f2b_rne(ure) | ((uint)f2b_rne(uim) << 16);
        uint gg = *reinterpret_cast<const uint*>(Gp + c*256);
        float gre, gim; UNPK(gg, gre, gim);
        float nre = rtr*sre - rti*sim + gre;
        float nim = rtr*sim + rti*sre + gim;
        sre = nre; sim = nim;
      }
    } else {
      for (int c = 31; c >= 0; --c) {
        float ure = w_re*sre - w_im*sim;
        float uim = w_re*sim + w_im*sre;
        *reinterpret_cast<uint*>(&U[bloc*32 + c][128 + 2*n]) =
            (uint)f2b_rne(ure) | ((uint)f2b_rne(uim) << 16);
        uint gg = *reinterpret_cast<const uint*>(Gp + c*256);
        float gre, gim; UNPK(gg, gre, gim);
        float nre = rtr*sre - rti*sim + gre;
        float nim = rtr*sim + rti*sre + gim;
        sre = nre; sim = nim;
      }
    }
  }
  __syncthreads();
  int wm = wid >> 1, wn = wid & 1, row16 = lane & 15, kg = lane >> 4;
  f32x4v acc00 = {0.f,0.f,0.f,0.f}, acc01 = acc00, acc10 = acc00, acc11 = acc00;
  const ushort* Ar = Mc + (size_t)h*4096 + (wm*32 + row16)*64 + kg*8;
  int bcA = t*64 + wn*32 + row16; int bA = bcA >> 5, cA = bcA & 31;
  int bcB = bcA + 16;             int bB = bcB >> 5, cB = bcB & 31;
  const ushort* Bz0 = zb + ((size_t)(bA*HH + h))*LL + cA*64 + kg*8;
  const ushort* Bz1 = zb + ((size_t)(bB*HH + h))*LL + cB*64 + kg*8;
  #pragma unroll
  for (int k0 = 0; k0 < 64; k0 += 32) {
    bf16x8v a0 = *reinterpret_cast<const bf16x8v*>(Ar + k0);
    bf16x8v a1 = *reinterpret_cast<const bf16x8v*>(Ar + 16*64 + k0);
    bf16x8v b0 = *reinterpret_cast<const bf16x8v*>(Bz0 + k0);
    bf16x8v b1 = *reinterpret_cast<const bf16x8v*>(Bz1 + k0);
    acc00 = __builtin_amdgcn_mfma_f32_16x16x32_bf16(a0, b0, acc00, 0,0,0);
    acc01 = __builtin_amdgcn_mfma_f32_16x16x32_bf16(a0, b1, acc01, 0,0,0);
    acc10 = __builtin_amdgcn_mfma_f32_16x16x32_bf16(a1, b0, acc10, 0,0,0);
    acc11 = __builtin_amdgcn_mfma_f32_16x16x32_bf16(a1, b1, acc11, 0,0,0);
  }
  const ushort* Au = Uc + (size_t)h*16384 + (wm*32 + row16)*256 + kg*8;
  int lr0 = wn*32 + row16, lr1 = lr0 + 16;
  #pragma unroll
  for (int k0 = 0; k0 < 256; k0 += 32) {
    bf16x8v a0 = *reinterpret_cast<const bf16x8v*>(Au + k0);
    bf16x8v a1 = *reinterpret_cast<const bf16x8v*>(Au + 16*256 + k0);
    bf16x8v b0 = *reinterpret_cast<const bf16x8v*>(&U[lr0][k0 + kg*8]);
    bf16x8v b1 = *reinterpret_cast<const bf16x8v*>(&U[lr1][k0 + kg*8]);
    acc00 = __builtin_amdgcn_mfma_f32_16x16x32_bf16(a0, b0, acc00, 0,0,0);
    acc01 = __builtin_amdgcn_mfma_f32_16x16x32_bf16(a0, b1, acc01, 0,0,0);
    acc10 = __builtin_amdgcn_mfma_f32_16x16x32_bf16(a1, b0, acc10, 0,0,0);
    acc11 = __builtin_amdgcn_mfma_f32_16x16x32_bf16(a1, b1, acc11, 0,0,0);
  }
  #pragma unroll
  for (int fm = 0; fm < 2; ++fm)
    #pragma unroll
    for (int fn = 0; fn < 2; ++fn) {
      const f32x4v* a = (fm==0) ? (fn==0 ? &acc00 : &acc01) : (fn==0 ? &acc10 : &acc11);
      int bc = t*64 + wn*32 + fn*16 + row16;
      int b = bc >> 5, c = bc & 31;
      int i0 = wm*32 + fm*16 + kg*4;
      #pragma unroll
      for (int r = 0; r < 4; ++r) {
        float v = (*a)[r];
        float ge = 0.5f * v * (1.0f + erff(v * 0.70710678118654752f));
        // g layout: [b][l][h]
        g[((size_t)b*LL + c*64 + i0 + r)*HH + h] = f2b_rne(ge);
      }
    }
}

// ---------------- fused_out: gate GEMM + W1/W2 GEMMs, per (b, 32-l tile) ----------------
__global__ __launch_bounds__(256) void fused_out(
    const ushort* __restrict__ g, const ushort* __restrict__ Wob,
    const ushort* __restrict__ W1b, const ushort* __restrict__ W2b,
    const float* __restrict__ b_out, const float* __restrict__ b1v,
    const float* __restrict__ b2v, const float* __restrict__ x,
    const float* __restrict__ tt,
    float* __restrict__ out1, float* __restrict__ out2) {
  int l0 = blockIdx.x * 32;
  int b  = blockIdx.y;
  int tid = threadIdx.x, wid = tid >> 6, lane = tid & 63;
  int row16 = lane & 15, kg = lane >> 4;
  int o0 = wid * 64;

  __shared__ ushort Tg[32][264];   // g tile [l][h], later gate^T [l][o]
  __shared__ ushort X[256][40];    // x tile bf16 [o][l]

  // stage g rows (already [b][l][h]) — coalesced
  {
    const ushort* gsrc = g + ((size_t)b*LL + l0)*HH;
    #pragma unroll
    for (int p = 0; p < 4; ++p) {
      int row = tid >> 3;
      int c8 = ((tid & 7) + p*8) * 8;
      *reinterpret_cast<uint4*>(&Tg[row][c8]) =
          *reinterpret_cast<const uint4*>(gsrc + (size_t)row*HH + c8);
    }
  }
  // stage x rows -> bf16 X[o][l] — coalesced
  {
    const float* xsrc = x + (size_t)b*HH*LL + l0;
    #pragma unroll
    for (int p = 0; p < 8; ++p) {
      int row = p*32 + (tid>>3), c4 = (tid&7)*4;
      float4 v = *reinterpret_cast<const float4*>(xsrc + (size_t)row*LL + c4);
      union { ushort us[4]; uint2 u2; } pk;
      pk.us[0] = f2b_rne(v.x); pk.us[1] = f2b_rne(v.y);
      pk.us[2] = f2b_rne(v.z); pk.us[3] = f2b_rne(v.w);
      *reinterpret_cast<uint2*>(&X[row][c4]) = pk.u2;
    }
  }
  // bias + tt for phase A (per-lane 16 scalars)
  float biasA[4][4], bias1[4][4], bias2[4][4];
  #pragma unroll
  for (int fo = 0; fo < 4; ++fo)
    #pragma unroll
    for (int r = 0; r < 4; ++r) {
      int o = o0 + fo*16 + kg*4 + r;
      biasA[fo][r] = b_out[o] + tt[b*HH + o];
      bias1[fo][r] = b1v[o];
      bias2[fo][r] = b2v[o];
    }
  __syncthreads();

  // ---- phase A: gate = act(W_out @ g + biasA + x) ----
  f32x4v accA[4][2];
  #pragma unroll
  for (int fo = 0; fo < 4; ++fo)
    #pragma unroll
    for (int fl = 0; fl < 2; ++fl) accA[fo][fl] = (f32x4v){0.f,0.f,0.f,0.f};
  #pragma unroll
  for (int k0 = 0; k0 < HH; k0 += 32) {
    bf16x8v a[4], bb[2];
    #pragma unroll
    for (int fo = 0; fo < 4; ++fo)
      a[fo] = *reinterpret_cast<const bf16x8v*>(Wob + (size_t)(o0+fo*16+row16)*HH + k0 + kg*8);
    #pragma unroll
    for (int fl = 0; fl < 2; ++fl)
      bb[fl] = *reinterpret_cast<const bf16x8v*>(&Tg[fl*16+row16][k0 + kg*8]);
    #pragma unroll
    for (int fo = 0; fo < 4; ++fo)
      #pragma unroll
      for (int fl = 0; fl < 2; ++fl)
        accA[fo][fl] = __builtin_amdgcn_mfma_f32_16x16x32_bf16(a[fo], bb[fl], accA[fo][fl], 0,0,0);
  }
  // gates in registers
  uint2 gw[4][2];
  #pragma unroll
  for (int fo = 0; fo < 4; ++fo)
    #pragma unroll
    for (int fl = 0; fl < 2; ++fl) {
      union { ushort us[4]; uint2 u2; } pk;
      #pragma unroll
      for (int r = 0; r < 4; ++r) {
        int o = o0 + fo*16 + kg*4 + r;
        int l = fl*16 + row16;
        float v = accA[fo][fl][r] + biasA[fo][r] + b2f(X[o][l]);
        float gate = tanhf(v) * (1.0f/(1.0f + expf(-v)));
        pk.us[r] = f2b_rne(gate);
      }
      gw[fo][fl] = pk.u2;
    }
  __syncthreads();   // all Tg reads done
  #pragma unroll
  for (int fo = 0; fo < 4; ++fo)
    #pragma unroll
    for (int fl = 0; fl < 2; ++fl)
      *reinterpret_cast<uint2*>(&Tg[fl*16+row16][o0 + fo*16 + kg*4]) = gw[fo][fl];
  __syncthreads();   // gate^T ready

  // ---- phase B1: out1 = W1 @ gate + b1 + x ----
  {
    f32x4v p[4][2];
    #pragma unroll
    for (int fo = 0; fo < 4; ++fo)
      #pragma unroll
      for (int fl = 0; fl < 2; ++fl) p[fo][fl] = (f32x4v){0.f,0.f,0.f,0.f};
    #pragma unroll
    for (int k0 = 0; k0 < HH; k0 += 32) {
      bf16x8v a[4], bb[2];
      #pragma unroll
      for (int fo = 0; fo < 4; ++fo)
        a[fo] = *reinterpret_cast<const bf16x8v*>(W1b + (size_t)(o0+fo*16+row16)*HH + k0 + kg*8);
      #pragma unroll
      for (int fl = 0; fl < 2; ++fl)
        bb[fl] = *reinterpret_cast<const bf16x8v*>(&Tg[fl*16+row16][k0 + kg*8]);
      #pragma unroll
      for (int fo = 0; fo < 4; ++fo)
        #pragma unroll
        for (int fl = 0; fl < 2; ++fl)
          p[fo][fl] = __builtin_amdgcn_mfma_f32_16x16x32_bf16(a[fo], bb[fl], p[fo][fl], 0,0,0);
    }
    #pragma unroll
    for (int fo = 0; fo < 4; ++fo)
      #pragma unroll
      for (int fl = 0; fl < 2; ++fl) {
        int l = fl*16 + row16;
        #pragma unroll
        for (int r = 0; r < 4; ++r) {
          int o = o0 + fo*16 + kg*4 + r;
          out1[((size_t)(b*HH + o))*LL + l0 + l] = p[fo][fl][r] + bias1[fo][r] + b2f(X[o][l]);
        }
      }
  }
  // ---- phase B2: out2 = W2 @ gate + b2 ----
  {
    f32x4v q[4][2];
    #pragma unroll
    for (int fo = 0; fo < 4; ++fo)
      #pragma unroll
      for (int fl = 0; fl < 2; ++fl) q[fo][fl] = (f32x4v){0.f,0.f,0.f,0.f};
    #pragma unroll
    for (int k0 = 0; k0 < HH; k0 += 32) {
      bf16x8v a[4], bb[2];
      #pragma unroll
      for (int fo = 0; fo < 4; ++fo)
        a[fo] = *reinterpret_cast<const bf16x8v*>(W2b + (size_t)(o0+fo*16+row16)*HH + k0 + kg*8);
      #pragma unroll
      for (int fl = 0; fl < 2; ++fl)
        bb[fl] = *reinterpret_cast<const bf16x8v*>(&Tg[fl*16+row16][k0 + kg*8]);
      #pragma unroll
      for (int fo = 0; fo < 4; ++fo)
        #pragma unroll
        for (int fl = 0; fl < 2; ++fl)
          q[fo][fl] = __builtin_amdgcn_mfma_f32_16x16x32_bf16(a[fo], bb[fl], q[fo][fl], 0,0,0);
    }
    #pragma unroll
    for (int fo = 0; fo < 4; ++fo)
      #pragma unroll
      for (int fl = 0; fl < 2; ++fl) {
        int l = fl*16 + row16;
        #pragma unroll
        for (int r = 0; r < 4; ++r) {
          int o = o0 + fo*16 + kg*4 + r;
          out2[((size_t)(b*HH + o))*LL + l0 + l] = q[fo][fl][r] + bias2[fo][r];
        }
      }
  }
}

extern "C" void kernel_launch(void* const* d_in, const int* in_sizes, int n_in,
                              void* d_out, int out_size, void* d_ws, size_t ws_size,
                              hipStream_t stream) {
  const float* x    = (const float*)d_in[0];
  const float* t    = (const float*)d_in[1];
  const float* W_t  = (const float*)d_in[2];
  const float* b_t  = (const float*)d_in[3];
  const float* ln_g = (const float*)d_in[4];
  const float* ln_b = (const float*)d_in[5];
  const float* log_dt = (const float*)d_in[6];
  const float* log_A_real = (const float*)d_in[7];
  const float* A_imag = (const float*)d_in[8];
  const float* B_re = (const float*)d_in[9];
  const float* B_im = (const float*)d_in[10];
  const float* C_re = (const float*)d_in[11];
  const float* C_im = (const float*)d_in[12];
  const float* Dp   = (const float*)d_in[13];
  const float* W_out= (const float*)d_in[14];
  const float* b_out= (const float*)d_in[15];
  const float* W1   = (const float*)d_in[16];
  const float* b1   = (const float*)d_in[17];
  const float* W2   = (const float*)d_in[18];
  const float* b2   = (const float*)d_in[19];

  float* out1 = (float*)d_out;
  float* out2 = out1 + ELEMS;

  // ws: P | tt | mu | rstd | rT | zb | Mc | Vc | Uc | g | Wob | W1b | W2b  (~35.4MB)
  float* P    = (float*)d_ws;
  float* tt   = P + 6*HN;
  float* mu   = tt + BB*HH;
  float* rstd = mu + BB*LL;
  float* rT   = rstd + BB*LL;
  ushort* zb  = (ushort*)(rT + 2*HN);
  ushort* Mc  = zb + ELEMS;
  ushort* Vc  = Mc + (size_t)4096*HH;
  ushort* Uc  = Vc + (size_t)16384*HH;
  ushort* g   = Uc + (size_t)16384*HH;
  ushort* Wob = g + ELEMS;
  ushort* W1b = Wob + HH*HH;
  ushort* W2b = W1b + HH*HH;
  ushort* G   = (ushort*)d_out;   // 32MB scratch, dead before fused_out writes

  setup_kernel<<<BB + HN/256, 256, 0, stream>>>(t, W_t, b_t, log_dt, log_A_real, A_imag,
                                                B_re, B_im, C_re, C_im, P, tt);
  wprep_kernel<<<192, 256, 0, stream>>>(W_out, W1, W2, Wob, W1b, W2b);
  stats_kernel<<<BB*(LL/64), 256, 0, stream>>>(x, tt, mu, rstd);
  z_kernel<<<ELEMS/512, 256, 0, stream>>>(x, tt, mu, rstd, ln_g, ln_b, (uint*)zb);
  prep_kernel<<<HH, 256, 0, stream>>>(log_dt, log_A_real, A_imag, P, Dp, Mc, Vc, Uc, rT);
  gloc_gemm<<<dim3(16, HH), 256, 0, stream>>>(Vc, zb, G);
  ssm_gemm<<<dim3(4, HH), 256, 0, stream>>>(zb, G, Mc, Uc, P, rT, g);
  fused_out<<<dim3(LL/32, BB), 256, 0, stream>>>(g, Wob, W1b, W2b, b_out, b1, b2,
                                                 x, tt, out1, out2);
}

// Round 8
// 126.843 us; speedup vs baseline: 2.4189x; 1.1756x over previous
//
#include <hip/hip_runtime.h>
#include <math.h>

#define LL 2048
#define HH 256
#define BB 8
#define NN 64
#define HN (HH*NN)       // 16384
#define ELEMS (BB*HH*LL) // 4194304

typedef __attribute__((ext_vector_type(8))) short bf16x8v;
typedef __attribute__((ext_vector_type(4))) float f32x4v;

static inline __device__ ushort f2b_rne(float f) {
  uint u = __float_as_uint(f);
  return (ushort)((u + 0x7fffu + ((u >> 16) & 1u)) >> 16);
}
static inline __device__ float b2f(ushort u) { return __uint_as_float((uint)u << 16); }
#define UNPK(u, lo, hi) { lo = __uint_as_float((u)<<16); hi = __uint_as_float((u)&0xffff0000u); }

// ---------------- init: tt (blk<8) | W->bf16 (blk<200) | per-h prep (blk>=200) ----------
// P layout (4*HN floats): w0re | w0im | w1re | w1im
__global__ __launch_bounds__(256) void init_kernel(
    const float* __restrict__ t, const float* __restrict__ W_t, const float* __restrict__ b_t,
    const float* __restrict__ log_dt, const float* __restrict__ log_A_real,
    const float* __restrict__ A_imag,
    const float* __restrict__ B_re, const float* __restrict__ B_im,
    const float* __restrict__ C_re, const float* __restrict__ C_im,
    const float* __restrict__ Dp,
    const float* __restrict__ Wo, const float* __restrict__ W1, const float* __restrict__ W2,
    float* __restrict__ P, float* __restrict__ tt,
    ushort* __restrict__ Wob, ushort* __restrict__ W1b, ushort* __restrict__ W2b,
    ushort* __restrict__ Mc, ushort* __restrict__ Vc, ushort* __restrict__ Uc,
    float* __restrict__ rT) {
  int blk = blockIdx.x;
  int tid = threadIdx.x;
  if (blk < BB) {
    int b = blk, h = tid;
    float s = b_t[h];
    const float* trow = t + b*HH;
    const float* wrow = W_t + h*HH;
    for (int c = 0; c < HH; ++c) s = fmaf(trow[c], wrow[c], s);
    tt[b*HH + h] = s;
    return;
  }
  if (blk < BB + 192) {
    int q = blk - BB;
    int m = q >> 6;
    int i = (q & 63)*1024 + tid*4;
    const float* src = (m==0) ? Wo : (m==1 ? W1 : W2);
    ushort* dst = (m==0) ? Wob : (m==1 ? W1b : W2b);
    float4 v = *reinterpret_cast<const float4*>(src + i);
    union { ushort us[4]; uint2 u2; } pk;
    pk.us[0] = f2b_rne(v.x); pk.us[1] = f2b_rne(v.y);
    pk.us[2] = f2b_rne(v.z); pk.us[3] = f2b_rne(v.w);
    *reinterpret_cast<uint2*>(dst + i) = pk.u2;
    return;
  }
  // ---- prep role: h = blk - 200 ----
  int h = blk - (BB + 192);
  __shared__ float RRe[65][64], RIm[65][64];
  __shared__ float K0[64], K1[64];
  __shared__ float W0r[64], W0i[64], W1r[64], W1i[64];
  float dt = expf(log_dt[h]);
  for (int idx = tid; idx < 65*64; idx += 256) {
    int d = idx >> 6, n = idx & 63;
    float are = -expf(log_A_real[h*64+n]);
    float aim = A_imag[h*64+n];
    float ang = dt*aim*(float)d;
    float mag = expf(dt*are*(float)d);
    RRe[d][n] = mag * cosf(ang);
    RIm[d][n] = mag * sinf(ang);
  }
  __syncthreads();
  if (tid < 64) {
    int n = tid, gid = h*64 + n;
    float are = -expf(log_A_real[gid]);
    float aim = A_imag[gid];
    float rre = RRe[1][n], rim = RIm[1][n];
    float inv  = 1.0f / (are*are + aim*aim);
    float m_re = rre - 1.0f, m_im = rim;
    float q_re = (m_re*are + m_im*aim) * inv;
    float q_im = (m_im*are - m_re*aim) * inv;
    float bre = B_re[gid], bim = B_im[gid];
    float db_re = q_re*bre - q_im*bim;
    float db_im = q_re*bim + q_im*bre;
    float c0r = C_re[gid],      c0i = C_im[gid];
    float c1r = C_re[HN + gid], c1i = C_im[HN + gid];
    float w0r = 2.0f*(c0r*db_re - c0i*db_im), w0i = 2.0f*(c0r*db_im + c0i*db_re);
    float w1r = 2.0f*(c1r*db_re - c1i*db_im), w1i = 2.0f*(c1r*db_im + c1i*db_re);
    W0r[n] = w0r; W0i[n] = w0i; W1r[n] = w1r; W1i[n] = w1i;
    P[gid]        = w0r;
    P[HN + gid]   = w0i;
    P[2*HN + gid] = w1r;
    P[3*HN + gid] = w1i;
    rT[gid*2]   = RRe[64][n];
    rT[gid*2+1] = RIm[64][n];
  }
  __syncthreads();
  if (tid < 128) {
    int d = tid & 63; bool c1 = tid >= 64;
    float s = 0.f;
    if (!c1) for (int n = 0; n < 64; ++n) s += W0r[n]*RRe[d][n] - W0i[n]*RIm[d][n];
    else     for (int n = 0; n < 64; ++n) s += W1r[n]*RRe[d][n] - W1i[n]*RIm[d][n];
    if (c1) K1[d] = s; else K0[d] = s;
  }
  __syncthreads();
  float dh = Dp[h];
  for (int idx = tid; idx < 4096; idx += 256) {
    int i = idx >> 6, j = idx & 63;
    float v = (i > j) ? K0[i-j] : (i < j ? K1[j-i-1] : (K0[0] + dh));
    Mc[(size_t)h*4096 + idx] = f2b_rne(v);
  }
  for (int idx = tid; idx < 256*64; idx += 256) {
    int row = idx >> 6, j = idx & 63;
    int n = (row >> 1) & 63;
    bool im = row & 1, bwd = row >= 128;
    int d = bwd ? j : 63-j;
    Vc[(size_t)h*16384 + idx] = f2b_rne(im ? RIm[d][n] : RRe[d][n]);
  }
  for (int idx = tid; idx < 64*256; idx += 256) {
    int i = idx >> 8, col = idx & 255;
    int n = (col >> 1) & 63;
    bool im = col & 1, bwd = col >= 128;
    int d = bwd ? 63-i : i+1;
    Uc[(size_t)h*16384 + idx] = f2b_rne(im ? -RIm[d][n] : RRe[d][n]);
  }
}

// ---------------- lnz: one-pass LN — reads x once, writes zb + xt (both bf16) ----------
// block = (b, 32-l tile); 512 blocks.
__global__ __launch_bounds__(256) void lnz_kernel(
    const float* __restrict__ x, const float* __restrict__ tt,
    const float* __restrict__ ln_g, const float* __restrict__ ln_b,
    ushort* __restrict__ zb, ushort* __restrict__ xt) {
  int b  = blockIdx.x >> 6;
  int l0 = (blockIdx.x & 63) * 32;
  int tid = threadIdx.x;
  int wq = tid >> 6, lane = tid & 63;
  int hodd = lane >> 5, lsub = lane & 31;
  __shared__ ushort XS[256][34];
  __shared__ float SS[8][32], SS2[8][32];
  __shared__ float MU[32], RS[32];
  float s = 0.f, s2 = 0.f;
  for (int it = 0; it < 32; ++it) {
    int h = wq*64 + it*2 + hodd;
    float v = x[(size_t)(b*HH + h)*LL + l0 + lsub] + tt[b*HH + h];
    s += v; s2 = fmaf(v, v, s2);
    XS[h][lsub] = f2b_rne(v);
  }
  SS[wq*2 + hodd][lsub] = s;
  SS2[wq*2 + hodd][lsub] = s2;
  __syncthreads();
  if (tid < 32) {
    float a = 0.f, a2 = 0.f;
    #pragma unroll
    for (int p = 0; p < 8; ++p) { a += SS[p][tid]; a2 += SS2[p][tid]; }
    float m = a * (1.0f/HH);
    float var = a2 * (1.0f/HH) - m*m;
    MU[tid] = m;
    RS[tid] = 1.0f / sqrtf(var + 1e-5f);
  }
  __syncthreads();
  // write phase: 4 h-rows per iter, 16 lanes x 4B per row
  for (int it = 0; it < 16; ++it) {
    int h = wq*64 + it*4 + (lane >> 4);
    int ll = (lane & 15)*2;
    uint u = *reinterpret_cast<const uint*>(&XS[h][ll]);
    float v0, v1; UNPK(u, v0, v1);
    float gg = ln_g[h], bb2 = ln_b[h];
    float z0 = (v0 - MU[ll])   * RS[ll]   * gg + bb2;
    float z1 = (v1 - MU[ll+1]) * RS[ll+1] * gg + bb2;
    size_t off = (size_t)(b*HH + h)*LL + l0 + ll;
    *reinterpret_cast<uint*>(zb + off) = (uint)f2b_rne(z0) | ((uint)f2b_rne(z1) << 16);
    *reinterpret_cast<uint*>(xt + off) = u;
  }
}

// ---------------- gloc: G[h][b][c][comp] = Vc_h @ Z_h ----------------
__global__ __launch_bounds__(256) void gloc_gemm(
    const ushort* __restrict__ Vc, const ushort* __restrict__ zb,
    ushort* __restrict__ G) {
  int tile = blockIdx.x;
  int h = blockIdx.y;
  int comp0 = (tile >> 2) * 64, bct = (tile & 3) * 64;
  int tid = threadIdx.x, wid = tid >> 6, lane = tid & 63;
  int wm = wid >> 1, wn = wid & 1, row16 = lane & 15, kg = lane >> 4;
  f32x4v acc00 = {0.f,0.f,0.f,0.f}, acc01 = acc00, acc10 = acc00, acc11 = acc00;
  const ushort* Ar = Vc + (size_t)h*16384 + (comp0 + wm*32 + row16)*64 + kg*8;
  int bcA = bct + wn*32 + row16; int bA = bcA >> 5, cA = bcA & 31;
  int bcB = bcA + 16;           int bB = bcB >> 5, cB = bcB & 31;
  const ushort* Bz0 = zb + ((size_t)(bA*HH + h))*LL + cA*64 + kg*8;
  const ushort* Bz1 = zb + ((size_t)(bB*HH + h))*LL + cB*64 + kg*8;
  #pragma unroll
  for (int k0 = 0; k0 < 64; k0 += 32) {
    bf16x8v a0 = *reinterpret_cast<const bf16x8v*>(Ar + k0);
    bf16x8v a1 = *reinterpret_cast<const bf16x8v*>(Ar + 16*64 + k0);
    bf16x8v b0 = *reinterpret_cast<const bf16x8v*>(Bz0 + k0);
    bf16x8v b1 = *reinterpret_cast<const bf16x8v*>(Bz1 + k0);
    acc00 = __builtin_amdgcn_mfma_f32_16x16x32_bf16(a0, b0, acc00, 0,0,0);
    acc01 = __builtin_amdgcn_mfma_f32_16x16x32_bf16(a0, b1, acc01, 0,0,0);
    acc10 = __builtin_amdgcn_mfma_f32_16x16x32_bf16(a1, b0, acc10, 0,0,0);
    acc11 = __builtin_amdgcn_mfma_f32_16x16x32_bf16(a1, b1, acc11, 0,0,0);
  }
  #pragma unroll
  for (int fm = 0; fm < 2; ++fm)
    #pragma unroll
    for (int fn = 0; fn < 2; ++fn) {
      const f32x4v* a = (fm==0) ? (fn==0 ? &acc00 : &acc01) : (fn==0 ? &acc10 : &acc11);
      int col = bct + wn*32 + fn*16 + row16;
      int bq = col >> 5, cq = col & 31;
      int comp = comp0 + wm*32 + fm*16 + kg*4;
      uint2 w;
      w.x = (uint)f2b_rne((*a)[0]) | ((uint)f2b_rne((*a)[1]) << 16);
      w.y = (uint)f2b_rne((*a)[2]) | ((uint)f2b_rne((*a)[3]) << 16);
      *reinterpret_cast<uint2*>(&G[(((size_t)h*8 + bq)*32 + cq)*256 + comp]) = w;
    }
}

// ---------------- ssm: chunk scan + Y = Mc@Z + Uc@uT + GELU -> g bf16 [b][h][l] ----
__global__ __launch_bounds__(256) void ssm_gemm(
    const ushort* __restrict__ zb, const ushort* __restrict__ G,
    const ushort* __restrict__ Mc, const ushort* __restrict__ Uc,
    const float* __restrict__ P, const float* __restrict__ rT,
    ushort* __restrict__ g) {
  int t = blockIdx.x;
  int h = blockIdx.y;
  int tid = threadIdx.x, wid = tid >> 6, lane = tid & 63;
  __shared__ ushort U[64][264];
  {
    int bloc = wid >> 1, dir = wid & 1;
    int b = t*2 + bloc;
    int n = lane;
    float w_re, w_im;
    if (dir == 0) { w_re = P[h*64+n];        w_im = P[HN + h*64+n]; }
    else          { w_re = P[2*HN + h*64+n]; w_im = P[3*HN + h*64+n]; }
    float rtr = rT[(h*64+n)*2], rti = rT[(h*64+n)*2+1];
    const ushort* Gp = G + (((size_t)h*8 + b)*32)*256 + dir*128 + 2*n;
    float sre = 0.f, sim = 0.f;
    if (dir == 0) {
      for (int c = 0; c < 32; ++c) {
        float ure = w_re*sre - w_im*sim;
        float uim = w_re*sim + w_im*sre;
        *reinterpret_cast<uint*>(&U[bloc*32 + c][2*n]) =
            (uint)f2b_rne(ure) | ((uint)f2b_rne(uim) << 16);
        uint gg = *reinterpret_cast<const uint*>(Gp + c*256);
        float gre, gim; UNPK(gg, gre, gim);
        float nre = rtr*sre - rti*sim + gre;
        float nim = rtr*sim + rti*sre + gim;
        sre = nre; sim = nim;
      }
    } else {
      for (int c = 31; c >= 0; --c) {
        float ure = w_re*sre - w_im*sim;
        float uim = w_re*sim + w_im*sre;
        *reinterpret_cast<uint*>(&U[bloc*32 + c][128 + 2*n]) =
            (uint)f2b_rne(ure) | ((uint)f2b_rne(uim) << 16);
        uint gg = *reinterpret_cast<const uint*>(Gp + c*256);
        float gre, gim; UNPK(gg, gre, gim);
        float nre = rtr*sre - rti*sim + gre;
        float nim = rtr*sim + rti*sre + gim;
        sre = nre; sim = nim;
      }
    }
  }
  __syncthreads();
  int wm = wid >> 1, wn = wid & 1, row16 = lane & 15, kg = lane >> 4;
  f32x4v acc00 = {0.f,0.f,0.f,0.f}, acc01 = acc00, acc10 = acc00, acc11 = acc00;
  const ushort* Ar = Mc + (size_t)h*4096 + (wm*32 + row16)*64 + kg*8;
  int bcA = t*64 + wn*32 + row16; int bA = bcA >> 5, cA = bcA & 31;
  int bcB = bcA + 16;             int bB = bcB >> 5, cB = bcB & 31;
  const ushort* Bz0 = zb + ((size_t)(bA*HH + h))*LL + cA*64 + kg*8;
  const ushort* Bz1 = zb + ((size_t)(bB*HH + h))*LL + cB*64 + kg*8;
  #pragma unroll
  for (int k0 = 0; k0 < 64; k0 += 32) {
    bf16x8v a0 = *reinterpret_cast<const bf16x8v*>(Ar + k0);
    bf16x8v a1 = *reinterpret_cast<const bf16x8v*>(Ar + 16*64 + k0);
    bf16x8v b0 = *reinterpret_cast<const bf16x8v*>(Bz0 + k0);
    bf16x8v b1 = *reinterpret_cast<const bf16x8v*>(Bz1 + k0);
    acc00 = __builtin_amdgcn_mfma_f32_16x16x32_bf16(a0, b0, acc00, 0,0,0);
    acc01 = __builtin_amdgcn_mfma_f32_16x16x32_bf16(a0, b1, acc01, 0,0,0);
    acc10 = __builtin_amdgcn_mfma_f32_16x16x32_bf16(a1, b0, acc10, 0,0,0);
    acc11 = __builtin_amdgcn_mfma_f32_16x16x32_bf16(a1, b1, acc11, 0,0,0);
  }
  const ushort* Au = Uc + (size_t)h*16384 + (wm*32 + row16)*256 + kg*8;
  int lr0 = wn*32 + row16, lr1 = lr0 + 16;
  #pragma unroll
  for (int k0 = 0; k0 < 256; k0 += 32) {
    bf16x8v a0 = *reinterpret_cast<const bf16x8v*>(Au + k0);
    bf16x8v a1 = *reinterpret_cast<const bf16x8v*>(Au + 16*256 + k0);
    bf16x8v b0 = *reinterpret_cast<const bf16x8v*>(&U[lr0][k0 + kg*8]);
    bf16x8v b1 = *reinterpret_cast<const bf16x8v*>(&U[lr1][k0 + kg*8]);
    acc00 = __builtin_amdgcn_mfma_f32_16x16x32_bf16(a0, b0, acc00, 0,0,0);
    acc01 = __builtin_amdgcn_mfma_f32_16x16x32_bf16(a0, b1, acc01, 0,0,0);
    acc10 = __builtin_amdgcn_mfma_f32_16x16x32_bf16(a1, b0, acc10, 0,0,0);
    acc11 = __builtin_amdgcn_mfma_f32_16x16x32_bf16(a1, b1, acc11, 0,0,0);
  }
  #pragma unroll
  for (int fm = 0; fm < 2; ++fm)
    #pragma unroll
    for (int fn = 0; fn < 2; ++fn) {
      const f32x4v* a = (fm==0) ? (fn==0 ? &acc00 : &acc01) : (fn==0 ? &acc10 : &acc11);
      int bc = t*64 + wn*32 + fn*16 + row16;
      int b = bc >> 5, c = bc & 31;
      int i0 = wm*32 + fm*16 + kg*4;
      union { ushort us[4]; uint2 u2; } pk;
      #pragma unroll
      for (int r = 0; r < 4; ++r) {
        float v = (*a)[r];
        float ge = 0.5f * v * (1.0f + erff(v * 0.70710678118654752f));
        pk.us[r] = f2b_rne(ge);
      }
      *reinterpret_cast<uint2*>(&g[((size_t)(b*HH + h))*LL + c*64 + i0]) = pk.u2;
    }
}

// ---------------- fused_out: gate GEMM + W1/W2 GEMMs, per (b, 32-l tile) ----------------
__global__ __launch_bounds__(256) void fused_out(
    const ushort* __restrict__ g, const ushort* __restrict__ Wob,
    const ushort* __restrict__ W1b, const ushort* __restrict__ W2b,
    const float* __restrict__ b_out, const float* __restrict__ b1v,
    const float* __restrict__ b2v, const ushort* __restrict__ xt,
    const float* __restrict__ tt,
    float* __restrict__ out1, float* __restrict__ out2) {
  int l0 = blockIdx.x * 32;
  int b  = blockIdx.y;
  int tid = threadIdx.x, wid = tid >> 6, lane = tid & 63;
  int row16 = lane & 15, kg = lane >> 4;
  int o0 = wid * 64;

  __shared__ ushort Tg[32][264];   // g^T tile [l][h], later gate^T [l][o]
  __shared__ ushort X[256][40];    // xt tile [o][l]

  // stage g [b][h][l] -> Tg[l][h] (transpose at stage time)
  {
    const ushort* gsrc = g + (size_t)b*HH*LL + l0;
    int cq = tid & 7;
    #pragma unroll
    for (int p = 0; p < 8; ++p) {
      int h = p*32 + (tid >> 3);
      uint2 v = *reinterpret_cast<const uint2*>(gsrc + (size_t)h*LL + cq*4);
      union { uint2 u2; ushort us[4]; } pk; pk.u2 = v;
      #pragma unroll
      for (int j = 0; j < 4; ++j) Tg[cq*4 + j][h] = pk.us[j];
    }
  }
  // stage xt [b][h][l] -> X[o][l]
  {
    const ushort* xsrc = xt + (size_t)b*HH*LL + l0;
    int cq = tid & 7;
    #pragma unroll
    for (int p = 0; p < 8; ++p) {
      int o = p*32 + (tid >> 3);
      uint2 v = *reinterpret_cast<const uint2*>(xsrc + (size_t)o*LL + cq*4);
      *reinterpret_cast<uint2*>(&X[o][cq*4]) = v;
    }
  }
  // biases (xt already contains +tt; out1 residual x = xt - tt)
  float biasA[4][4], bias1[4][4], bias2[4][4];
  #pragma unroll
  for (int fo = 0; fo < 4; ++fo)
    #pragma unroll
    for (int r = 0; r < 4; ++r) {
      int o = o0 + fo*16 + kg*4 + r;
      biasA[fo][r] = b_out[o];
      bias1[fo][r] = b1v[o] - tt[b*HH + o];
      bias2[fo][r] = b2v[o];
    }
  __syncthreads();

  // ---- phase A: gate = act(W_out @ g + biasA + xt) ----
  f32x4v accA[4][2];
  #pragma unroll
  for (int fo = 0; fo < 4; ++fo)
    #pragma unroll
    for (int fl = 0; fl < 2; ++fl) accA[fo][fl] = (f32x4v){0.f,0.f,0.f,0.f};
  #pragma unroll
  for (int k0 = 0; k0 < HH; k0 += 32) {
    bf16x8v a[4], bb[2];
    #pragma unroll
    for (int fo = 0; fo < 4; ++fo)
      a[fo] = *reinterpret_cast<const bf16x8v*>(Wob + (size_t)(o0+fo*16+row16)*HH + k0 + kg*8);
    #pragma unroll
    for (int fl = 0; fl < 2; ++fl)
      bb[fl] = *reinterpret_cast<const bf16x8v*>(&Tg[fl*16+row16][k0 + kg*8]);
    #pragma unroll
    for (int fo = 0; fo < 4; ++fo)
      #pragma unroll
      for (int fl = 0; fl < 2; ++fl)
        accA[fo][fl] = __builtin_amdgcn_mfma_f32_16x16x32_bf16(a[fo], bb[fl], accA[fo][fl], 0,0,0);
  }
  uint2 gw[4][2];
  #pragma unroll
  for (int fo = 0; fo < 4; ++fo)
    #pragma unroll
    for (int fl = 0; fl < 2; ++fl) {
      union { ushort us[4]; uint2 u2; } pk;
      #pragma unroll
      for (int r = 0; r < 4; ++r) {
        int o = o0 + fo*16 + kg*4 + r;
        int l = fl*16 + row16;
        float v = accA[fo][fl][r] + biasA[fo][r] + b2f(X[o][l]);
        float gate = tanhf(v) * (1.0f/(1.0f + expf(-v)));
        pk.us[r] = f2b_rne(gate);
      }
      gw[fo][fl] = pk.u2;
    }
  __syncthreads();
  #pragma unroll
  for (int fo = 0; fo < 4; ++fo)
    #pragma unroll
    for (int fl = 0; fl < 2; ++fl)
      *reinterpret_cast<uint2*>(&Tg[fl*16+row16][o0 + fo*16 + kg*4]) = gw[fo][fl];
  __syncthreads();

  // ---- phase B1: out1 = W1 @ gate + (b1 - tt) + xt ----
  {
    f32x4v p[4][2];
    #pragma unroll
    for (int fo = 0; fo < 4; ++fo)
      #pragma unroll
      for (int fl = 0; fl < 2; ++fl) p[fo][fl] = (f32x4v){0.f,0.f,0.f,0.f};
    #pragma unroll
    for (int k0 = 0; k0 < HH; k0 += 32) {
      bf16x8v a[4], bb[2];
      #pragma unroll
      for (int fo = 0; fo < 4; ++fo)
        a[fo] = *reinterpret_cast<const bf16x8v*>(W1b + (size_t)(o0+fo*16+row16)*HH + k0 + kg*8);
      #pragma unroll
      for (int fl = 0; fl < 2; ++fl)
        bb[fl] = *reinterpret_cast<const bf16x8v*>(&Tg[fl*16+row16][k0 + kg*8]);
      #pragma unroll
      for (int fo = 0; fo < 4; ++fo)
        #pragma unroll
        for (int fl = 0; fl < 2; ++fl)
          p[fo][fl] = __builtin_amdgcn_mfma_f32_16x16x32_bf16(a[fo], bb[fl], p[fo][fl], 0,0,0);
    }
    #pragma unroll
    for (int fo = 0; fo < 4; ++fo)
      #pragma unroll
      for (int fl = 0; fl < 2; ++fl) {
        int l = fl*16 + row16;
        #pragma unroll
        for (int r = 0; r < 4; ++r) {
          int o = o0 + fo*16 + kg*4 + r;
          out1[((size_t)(b*HH + o))*LL + l0 + l] = p[fo][fl][r] + bias1[fo][r] + b2f(X[o][l]);
        }
      }
  }
  // ---- phase B2: out2 = W2 @ gate + b2 ----
  {
    f32x4v q[4][2];
    #pragma unroll
    for (int fo = 0; fo < 4; ++fo)
      #pragma unroll
      for (int fl = 0; fl < 2; ++fl) q[fo][fl] = (f32x4v){0.f,0.f,0.f,0.f};
    #pragma unroll
    for (int k0 = 0; k0 < HH; k0 += 32) {
      bf16x8v a[4], bb[2];
      #pragma unroll
      for (int fo = 0; fo < 4; ++fo)
        a[fo] = *reinterpret_cast<const bf16x8v*>(W2b + (size_t)(o0+fo*16+row16)*HH + k0 + kg*8);
      #pragma unroll
      for (int fl = 0; fl < 2; ++fl)
        bb[fl] = *reinterpret_cast<const bf16x8v*>(&Tg[fl*16+row16][k0 + kg*8]);
      #pragma unroll
      for (int fo = 0; fo < 4; ++fo)
        #pragma unroll
        for (int fl = 0; fl < 2; ++fl)
          q[fo][fl] = __builtin_amdgcn_mfma_f32_16x16x32_bf16(a[fo], bb[fl], q[fo][fl], 0,0,0);
    }
    #pragma unroll
    for (int fo = 0; fo < 4; ++fo)
      #pragma unroll
      for (int fl = 0; fl < 2; ++fl) {
        int l = fl*16 + row16;
        #pragma unroll
        for (int r = 0; r < 4; ++r) {
          int o = o0 + fo*16 + kg*4 + r;
          out2[((size_t)(b*HH + o))*LL + l0 + l] = q[fo][fl][r] + bias2[fo][r];
        }
      }
  }
}

extern "C" void kernel_launch(void* const* d_in, const int* in_sizes, int n_in,
                              void* d_out, int out_size, void* d_ws, size_t ws_size,
                              hipStream_t stream) {
  const float* x    = (const float*)d_in[0];
  const float* t    = (const float*)d_in[1];
  const float* W_t  = (const float*)d_in[2];
  const float* b_t  = (const float*)d_in[3];
  const float* ln_g = (const float*)d_in[4];
  const float* ln_b = (const float*)d_in[5];
  const float* log_dt = (const float*)d_in[6];
  const float* log_A_real = (const float*)d_in[7];
  const float* A_imag = (const float*)d_in[8];
  const float* B_re = (const float*)d_in[9];
  const float* B_im = (const float*)d_in[10];
  const float* C_re = (const float*)d_in[11];
  const float* C_im = (const float*)d_in[12];
  const float* Dp   = (const float*)d_in[13];
  const float* W_out= (const float*)d_in[14];
  const float* b_out= (const float*)d_in[15];
  const float* W1   = (const float*)d_in[16];
  const float* b1   = (const float*)d_in[17];
  const float* W2   = (const float*)d_in[18];
  const float* b2   = (const float*)d_in[19];

  float* out1 = (float*)d_out;
  float* out2 = out1 + ELEMS;

  // ws: P(4HN) | tt | rT(2HN) | zb | Mc | Vc | Uc | g | Wob | W1b | W2b | xt
  float* P    = (float*)d_ws;
  float* tt   = P + 4*HN;
  float* rT   = tt + BB*HH;
  ushort* zb  = (ushort*)(rT + 2*HN);
  ushort* Mc  = zb + ELEMS;
  ushort* Vc  = Mc + (size_t)4096*HH;
  ushort* Uc  = Vc + (size_t)16384*HH;
  ushort* g   = Uc + (size_t)16384*HH;
  ushort* Wob = g + ELEMS;
  ushort* W1b = Wob + HH*HH;
  ushort* W2b = W1b + HH*HH;
  ushort* xt  = W2b + HH*HH;
  ushort* G   = (ushort*)d_out;   // 32MB scratch, dead before fused_out writes

  init_kernel<<<BB + 192 + HH, 256, 0, stream>>>(
      t, W_t, b_t, log_dt, log_A_real, A_imag, B_re, B_im, C_re, C_im, Dp,
      W_out, W1, W2, P, tt, Wob, W1b, W2b, Mc, Vc, Uc, rT);
  lnz_kernel<<<BB*64, 256, 0, stream>>>(x, tt, ln_g, ln_b, zb, xt);
  gloc_gemm<<<dim3(16, HH), 256, 0, stream>>>(Vc, zb, G);
  ssm_gemm<<<dim3(4, HH), 256, 0, stream>>>(zb, G, Mc, Uc, P, rT, g);
  fused_out<<<dim3(LL/32, BB), 256, 0, stream>>>(g, Wob, W1b, W2b, b_out, b1, b2,
                                                 xt, tt, out1, out2);
}

// Round 9
// 104.932 us; speedup vs baseline: 2.9240x; 1.2088x over previous
//
#include <hip/hip_runtime.h>
#include <math.h>

#define LL 2048
#define HH 256
#define BB 8
#define NN 64
#define HN (HH*NN)       // 16384
#define ELEMS (BB*HH*LL) // 4194304

typedef __attribute__((ext_vector_type(8))) short bf16x8v;
typedef __attribute__((ext_vector_type(4))) float f32x4v;

static inline __device__ ushort f2b_rne(float f) {
  uint u = __float_as_uint(f);
  return (ushort)((u + 0x7fffu + ((u >> 16) & 1u)) >> 16);
}
static inline __device__ float b2f(ushort u) { return __uint_as_float((uint)u << 16); }
#define UNPK(u, lo, hi) { lo = __uint_as_float((u)<<16); hi = __uint_as_float((u)&0xffff0000u); }

// ---------------- init: tt (blk<8) | W->bf16 (blk<200) | per-h prep (blk>=200) ----------
// P layout (4*HN floats): w0re | w0im | w1re | w1im
__global__ __launch_bounds__(256) void init_kernel(
    const float* __restrict__ t, const float* __restrict__ W_t, const float* __restrict__ b_t,
    const float* __restrict__ log_dt, const float* __restrict__ log_A_real,
    const float* __restrict__ A_imag,
    const float* __restrict__ B_re, const float* __restrict__ B_im,
    const float* __restrict__ C_re, const float* __restrict__ C_im,
    const float* __restrict__ Dp,
    const float* __restrict__ Wo, const float* __restrict__ W1, const float* __restrict__ W2,
    float* __restrict__ P, float* __restrict__ tt,
    ushort* __restrict__ Wob, ushort* __restrict__ W1b, ushort* __restrict__ W2b,
    ushort* __restrict__ Mc, ushort* __restrict__ Vc, ushort* __restrict__ Uc,
    float* __restrict__ rT) {
  int blk = blockIdx.x;
  int tid = threadIdx.x;
  if (blk < BB) {
    int b = blk, h = tid;
    float s = b_t[h];
    const float* trow = t + b*HH;
    const float* wrow = W_t + h*HH;
    for (int c = 0; c < HH; ++c) s = fmaf(trow[c], wrow[c], s);
    tt[b*HH + h] = s;
    return;
  }
  if (blk < BB + 192) {
    int q = blk - BB;
    int m = q >> 6;
    int i = (q & 63)*1024 + tid*4;
    const float* src = (m==0) ? Wo : (m==1 ? W1 : W2);
    ushort* dst = (m==0) ? Wob : (m==1 ? W1b : W2b);
    float4 v = *reinterpret_cast<const float4*>(src + i);
    union { ushort us[4]; uint2 u2; } pk;
    pk.us[0] = f2b_rne(v.x); pk.us[1] = f2b_rne(v.y);
    pk.us[2] = f2b_rne(v.z); pk.us[3] = f2b_rne(v.w);
    *reinterpret_cast<uint2*>(dst + i) = pk.u2;
    return;
  }
  // ---- prep role: h = blk - 200 ----
  int h = blk - (BB + 192);
  __shared__ float RRe[65][64], RIm[65][64];
  __shared__ float K0[64], K1[64];
  __shared__ float W0r[64], W0i[64], W1r[64], W1i[64];
  float dt = expf(log_dt[h]);
  for (int idx = tid; idx < 65*64; idx += 256) {
    int d = idx >> 6, n = idx & 63;
    float are = -expf(log_A_real[h*64+n]);
    float aim = A_imag[h*64+n];
    float ang = dt*aim*(float)d;
    float mag = expf(dt*are*(float)d);
    RRe[d][n] = mag * cosf(ang);
    RIm[d][n] = mag * sinf(ang);
  }
  __syncthreads();
  if (tid < 64) {
    int n = tid, gid = h*64 + n;
    float are = -expf(log_A_real[gid]);
    float aim = A_imag[gid];
    float rre = RRe[1][n], rim = RIm[1][n];
    float inv  = 1.0f / (are*are + aim*aim);
    float m_re = rre - 1.0f, m_im = rim;
    float q_re = (m_re*are + m_im*aim) * inv;
    float q_im = (m_im*are - m_re*aim) * inv;
    float bre = B_re[gid], bim = B_im[gid];
    float db_re = q_re*bre - q_im*bim;
    float db_im = q_re*bim + q_im*bre;
    float c0r = C_re[gid],      c0i = C_im[gid];
    float c1r = C_re[HN + gid], c1i = C_im[HN + gid];
    float w0r = 2.0f*(c0r*db_re - c0i*db_im), w0i = 2.0f*(c0r*db_im + c0i*db_re);
    float w1r = 2.0f*(c1r*db_re - c1i*db_im), w1i = 2.0f*(c1r*db_im + c1i*db_re);
    W0r[n] = w0r; W0i[n] = w0i; W1r[n] = w1r; W1i[n] = w1i;
    P[gid]        = w0r;
    P[HN + gid]   = w0i;
    P[2*HN + gid] = w1r;
    P[3*HN + gid] = w1i;
    rT[gid*2]   = RRe[64][n];
    rT[gid*2+1] = RIm[64][n];
  }
  __syncthreads();
  if (tid < 128) {
    int d = tid & 63; bool c1 = tid >= 64;
    float s = 0.f;
    if (!c1) for (int n = 0; n < 64; ++n) s += W0r[n]*RRe[d][n] - W0i[n]*RIm[d][n];
    else     for (int n = 0; n < 64; ++n) s += W1r[n]*RRe[d][n] - W1i[n]*RIm[d][n];
    if (c1) K1[d] = s; else K0[d] = s;
  }
  __syncthreads();
  float dh = Dp[h];
  for (int idx = tid; idx < 4096; idx += 256) {
    int i = idx >> 6, j = idx & 63;
    float v = (i > j) ? K0[i-j] : (i < j ? K1[j-i-1] : (K0[0] + dh));
    Mc[(size_t)h*4096 + idx] = f2b_rne(v);
  }
  for (int idx = tid; idx < 256*64; idx += 256) {
    int row = idx >> 6, j = idx & 63;
    int n = (row >> 1) & 63;
    bool im = row & 1, bwd = row >= 128;
    int d = bwd ? j : 63-j;
    Vc[(size_t)h*16384 + idx] = f2b_rne(im ? RIm[d][n] : RRe[d][n]);
  }
  for (int idx = tid; idx < 64*256; idx += 256) {
    int i = idx >> 8, col = idx & 255;
    int n = (col >> 1) & 63;
    bool im = col & 1, bwd = col >= 128;
    int d = bwd ? 63-i : i+1;
    Uc[(size_t)h*16384 + idx] = f2b_rne(im ? -RIm[d][n] : RRe[d][n]);
  }
}

// ---------------- lnz: one-pass LN — reads x once, writes zb + xt (both bf16) ----------
__global__ __launch_bounds__(256) void lnz_kernel(
    const float* __restrict__ x, const float* __restrict__ tt,
    const float* __restrict__ ln_g, const float* __restrict__ ln_b,
    ushort* __restrict__ zb, ushort* __restrict__ xt) {
  int b  = blockIdx.x >> 6;
  int l0 = (blockIdx.x & 63) * 32;
  int tid = threadIdx.x;
  int wq = tid >> 6, lane = tid & 63;
  int hodd = lane >> 5, lsub = lane & 31;
  __shared__ ushort XS[256][34];
  __shared__ float SS[8][32], SS2[8][32];
  __shared__ float MU[32], RS[32];
  float s = 0.f, s2 = 0.f;
  for (int it = 0; it < 32; ++it) {
    int h = wq*64 + it*2 + hodd;
    float v = x[(size_t)(b*HH + h)*LL + l0 + lsub] + tt[b*HH + h];
    s += v; s2 = fmaf(v, v, s2);
    XS[h][lsub] = f2b_rne(v);
  }
  SS[wq*2 + hodd][lsub] = s;
  SS2[wq*2 + hodd][lsub] = s2;
  __syncthreads();
  if (tid < 32) {
    float a = 0.f, a2 = 0.f;
    #pragma unroll
    for (int p = 0; p < 8; ++p) { a += SS[p][tid]; a2 += SS2[p][tid]; }
    float m = a * (1.0f/HH);
    float var = a2 * (1.0f/HH) - m*m;
    MU[tid] = m;
    RS[tid] = 1.0f / sqrtf(var + 1e-5f);
  }
  __syncthreads();
  for (int it = 0; it < 16; ++it) {
    int h = wq*64 + it*4 + (lane >> 4);
    int ll = (lane & 15)*2;
    uint u = *reinterpret_cast<const uint*>(&XS[h][ll]);
    float v0, v1; UNPK(u, v0, v1);
    float gg = ln_g[h], bb2 = ln_b[h];
    float z0 = (v0 - MU[ll])   * RS[ll]   * gg + bb2;
    float z1 = (v1 - MU[ll+1]) * RS[ll+1] * gg + bb2;
    size_t off = (size_t)(b*HH + h)*LL + l0 + ll;
    *reinterpret_cast<uint*>(zb + off) = (uint)f2b_rne(z0) | ((uint)f2b_rne(z1) << 16);
    *reinterpret_cast<uint*>(xt + off) = u;
  }
}

// ---------------- ssm_all: G GEMM (LDS) + chunk scan + Y GEMM + GELU, one block per h ----
__global__ __launch_bounds__(512) void ssm_all(
    const ushort* __restrict__ zb, const ushort* __restrict__ Vc,
    const ushort* __restrict__ Mc, const ushort* __restrict__ Uc,
    const float* __restrict__ P, const float* __restrict__ rT,
    ushort* __restrict__ g) {
  int h = blockIdx.x;
  int tid = threadIdx.x, wid = tid >> 6, lane = tid & 63;
  int row16 = lane & 15, kg = lane >> 4;
  __shared__ ushort G[256][260];   // 130 KB: G[bc][comp], overwritten by U in-place

  // ---- phase 1: G = Vc_h @ Z  (16 tiles of 64x64 over 8 waves x 2) ----
  #pragma unroll
  for (int rep = 0; rep < 2; ++rep) {
    int tile = wid + rep*8;
    int comp0 = (tile >> 2)*64, bct = (tile & 3)*64;
    f32x4v acc[4][4];
    #pragma unroll
    for (int fm = 0; fm < 4; ++fm)
      #pragma unroll
      for (int fn = 0; fn < 4; ++fn) acc[fm][fn] = (f32x4v){0.f,0.f,0.f,0.f};
    #pragma unroll
    for (int k0 = 0; k0 < 64; k0 += 32) {
      bf16x8v a[4], bv[4];
      #pragma unroll
      for (int fm = 0; fm < 4; ++fm)
        a[fm] = *reinterpret_cast<const bf16x8v*>(
            Vc + (size_t)h*16384 + (comp0 + fm*16 + row16)*64 + k0 + kg*8);
      #pragma unroll
      for (int fn = 0; fn < 4; ++fn) {
        int bc = bct + fn*16 + row16; int b = bc >> 5, c = bc & 31;
        bv[fn] = *reinterpret_cast<const bf16x8v*>(
            zb + ((size_t)(b*HH + h))*LL + c*64 + k0 + kg*8);
      }
      #pragma unroll
      for (int fm = 0; fm < 4; ++fm)
        #pragma unroll
        for (int fn = 0; fn < 4; ++fn)
          acc[fm][fn] = __builtin_amdgcn_mfma_f32_16x16x32_bf16(a[fm], bv[fn], acc[fm][fn], 0,0,0);
    }
    #pragma unroll
    for (int fm = 0; fm < 4; ++fm)
      #pragma unroll
      for (int fn = 0; fn < 4; ++fn) {
        int bc = bct + fn*16 + row16;
        int comp = comp0 + fm*16 + kg*4;
        union { ushort us[4]; uint2 u2; } pk;
        #pragma unroll
        for (int r = 0; r < 4; ++r) pk.us[r] = f2b_rne(acc[fm][fn][r]);
        *reinterpret_cast<uint2*>(&G[bc][comp]) = pk.u2;
      }
  }
  __syncthreads();

  // ---- phase 2: 16 scan units (b,dir) over 8 waves x 2; U overwrites G in place ----
  #pragma unroll
  for (int rep = 0; rep < 2; ++rep) {
    int unit = wid + rep*8;
    int b = unit & 7, dir = unit >> 3;
    int n = lane;
    float w_re = dir ? P[2*HN + h*64+n] : P[h*64+n];
    float w_im = dir ? P[3*HN + h*64+n] : P[HN + h*64+n];
    float rtr = rT[(h*64+n)*2], rti = rT[(h*64+n)*2+1];
    float sre = 0.f, sim = 0.f;
    if (dir == 0) {
      for (int c = 0; c < 32; ++c) {
        uint* slot = reinterpret_cast<uint*>(&G[b*32 + c][2*n]);
        uint gg = *slot;
        float ure = w_re*sre - w_im*sim;
        float uim = w_re*sim + w_im*sre;
        *slot = (uint)f2b_rne(ure) | ((uint)f2b_rne(uim) << 16);
        float gre, gim; UNPK(gg, gre, gim);
        float nre = rtr*sre - rti*sim + gre;
        float nim = rtr*sim + rti*sre + gim;
        sre = nre; sim = nim;
      }
    } else {
      for (int c = 31; c >= 0; --c) {
        uint* slot = reinterpret_cast<uint*>(&G[b*32 + c][128 + 2*n]);
        uint gg = *slot;
        float ure = w_re*sre - w_im*sim;
        float uim = w_re*sim + w_im*sre;
        *slot = (uint)f2b_rne(ure) | ((uint)f2b_rne(uim) << 16);
        float gre, gim; UNPK(gg, gre, gim);
        float nre = rtr*sre - rti*sim + gre;
        float nim = rtr*sim + rti*sre + gim;
        sre = nre; sim = nim;
      }
    }
  }
  __syncthreads();

  // ---- phase 3: Y = Mc@Z + Uc@U, GELU -> g[b][h][l]; 8 tiles of 32x64, one per wave ----
  {
    int i0 = (wid & 1)*32, bct = (wid >> 1)*64;
    f32x4v acc[2][4];
    #pragma unroll
    for (int fm = 0; fm < 2; ++fm)
      #pragma unroll
      for (int fn = 0; fn < 4; ++fn) acc[fm][fn] = (f32x4v){0.f,0.f,0.f,0.f};
    #pragma unroll
    for (int k0 = 0; k0 < 64; k0 += 32) {
      bf16x8v a[2], bv[4];
      #pragma unroll
      for (int fm = 0; fm < 2; ++fm)
        a[fm] = *reinterpret_cast<const bf16x8v*>(
            Mc + (size_t)h*4096 + (i0 + fm*16 + row16)*64 + k0 + kg*8);
      #pragma unroll
      for (int fn = 0; fn < 4; ++fn) {
        int bc = bct + fn*16 + row16; int b = bc >> 5, c = bc & 31;
        bv[fn] = *reinterpret_cast<const bf16x8v*>(
            zb + ((size_t)(b*HH + h))*LL + c*64 + k0 + kg*8);
      }
      #pragma unroll
      for (int fm = 0; fm < 2; ++fm)
        #pragma unroll
        for (int fn = 0; fn < 4; ++fn)
          acc[fm][fn] = __builtin_amdgcn_mfma_f32_16x16x32_bf16(a[fm], bv[fn], acc[fm][fn], 0,0,0);
    }
    #pragma unroll
    for (int k0 = 0; k0 < 256; k0 += 32) {
      bf16x8v a[2], bv[4];
      #pragma unroll
      for (int fm = 0; fm < 2; ++fm)
        a[fm] = *reinterpret_cast<const bf16x8v*>(
            Uc + (size_t)h*16384 + (i0 + fm*16 + row16)*256 + k0 + kg*8);
      #pragma unroll
      for (int fn = 0; fn < 4; ++fn)
        bv[fn] = *reinterpret_cast<const bf16x8v*>(&G[bct + fn*16 + row16][k0 + kg*8]);
      #pragma unroll
      for (int fm = 0; fm < 2; ++fm)
        #pragma unroll
        for (int fn = 0; fn < 4; ++fn)
          acc[fm][fn] = __builtin_amdgcn_mfma_f32_16x16x32_bf16(a[fm], bv[fn], acc[fm][fn], 0,0,0);
    }
    #pragma unroll
    for (int fm = 0; fm < 2; ++fm)
      #pragma unroll
      for (int fn = 0; fn < 4; ++fn) {
        int bc = bct + fn*16 + row16; int b = bc >> 5, c = bc & 31;
        int i = i0 + fm*16 + kg*4;
        union { ushort us[4]; uint2 u2; } pk;
        #pragma unroll
        for (int r = 0; r < 4; ++r) {
          float v = acc[fm][fn][r];
          float ge = 0.5f * v * (1.0f + erff(v * 0.70710678118654752f));
          pk.us[r] = f2b_rne(ge);
        }
        *reinterpret_cast<uint2*>(&g[((size_t)(b*HH + h))*LL + c*64 + i]) = pk.u2;
      }
  }
}

// ---------------- fused_out: gate GEMM + W1/W2 GEMMs, per (b, 32-l tile) ----------------
__global__ __launch_bounds__(256) void fused_out(
    const ushort* __restrict__ g, const ushort* __restrict__ Wob,
    const ushort* __restrict__ W1b, const ushort* __restrict__ W2b,
    const float* __restrict__ b_out, const float* __restrict__ b1v,
    const float* __restrict__ b2v, const ushort* __restrict__ xt,
    const float* __restrict__ tt,
    float* __restrict__ out1, float* __restrict__ out2) {
  int l0 = blockIdx.x * 32;
  int b  = blockIdx.y;
  int tid = threadIdx.x, wid = tid >> 6, lane = tid & 63;
  int row16 = lane & 15, kg = lane >> 4;
  int o0 = wid * 64;

  __shared__ ushort Tg[32][264];
  __shared__ ushort X[256][40];

  {
    const ushort* gsrc = g + (size_t)b*HH*LL + l0;
    int cq = tid & 7;
    #pragma unroll
    for (int p = 0; p < 8; ++p) {
      int h = p*32 + (tid >> 3);
      uint2 v = *reinterpret_cast<const uint2*>(gsrc + (size_t)h*LL + cq*4);
      union { uint2 u2; ushort us[4]; } pk; pk.u2 = v;
      #pragma unroll
      for (int j = 0; j < 4; ++j) Tg[cq*4 + j][h] = pk.us[j];
    }
  }
  {
    const ushort* xsrc = xt + (size_t)b*HH*LL + l0;
    int cq = tid & 7;
    #pragma unroll
    for (int p = 0; p < 8; ++p) {
      int o = p*32 + (tid >> 3);
      uint2 v = *reinterpret_cast<const uint2*>(xsrc + (size_t)o*LL + cq*4);
      *reinterpret_cast<uint2*>(&X[o][cq*4]) = v;
    }
  }
  float biasA[4][4], bias1[4][4], bias2[4][4];
  #pragma unroll
  for (int fo = 0; fo < 4; ++fo)
    #pragma unroll
    for (int r = 0; r < 4; ++r) {
      int o = o0 + fo*16 + kg*4 + r;
      biasA[fo][r] = b_out[o];
      bias1[fo][r] = b1v[o] - tt[b*HH + o];
      bias2[fo][r] = b2v[o];
    }
  __syncthreads();

  f32x4v accA[4][2];
  #pragma unroll
  for (int fo = 0; fo < 4; ++fo)
    #pragma unroll
    for (int fl = 0; fl < 2; ++fl) accA[fo][fl] = (f32x4v){0.f,0.f,0.f,0.f};
  #pragma unroll
  for (int k0 = 0; k0 < HH; k0 += 32) {
    bf16x8v a[4], bb[2];
    #pragma unroll
    for (int fo = 0; fo < 4; ++fo)
      a[fo] = *reinterpret_cast<const bf16x8v*>(Wob + (size_t)(o0+fo*16+row16)*HH + k0 + kg*8);
    #pragma unroll
    for (int fl = 0; fl < 2; ++fl)
      bb[fl] = *reinterpret_cast<const bf16x8v*>(&Tg[fl*16+row16][k0 + kg*8]);
    #pragma unroll
    for (int fo = 0; fo < 4; ++fo)
      #pragma unroll
      for (int fl = 0; fl < 2; ++fl)
        accA[fo][fl] = __builtin_amdgcn_mfma_f32_16x16x32_bf16(a[fo], bb[fl], accA[fo][fl], 0,0,0);
  }
  uint2 gw[4][2];
  #pragma unroll
  for (int fo = 0; fo < 4; ++fo)
    #pragma unroll
    for (int fl = 0; fl < 2; ++fl) {
      union { ushort us[4]; uint2 u2; } pk;
      #pragma unroll
      for (int r = 0; r < 4; ++r) {
        int o = o0 + fo*16 + kg*4 + r;
        int l = fl*16 + row16;
        float v = accA[fo][fl][r] + biasA[fo][r] + b2f(X[o][l]);
        float gate = tanhf(v) * (1.0f/(1.0f + expf(-v)));
        pk.us[r] = f2b_rne(gate);
      }
      gw[fo][fl] = pk.u2;
    }
  __syncthreads();
  #pragma unroll
  for (int fo = 0; fo < 4; ++fo)
    #pragma unroll
    for (int fl = 0; fl < 2; ++fl)
      *reinterpret_cast<uint2*>(&Tg[fl*16+row16][o0 + fo*16 + kg*4]) = gw[fo][fl];
  __syncthreads();

  {
    f32x4v p[4][2];
    #pragma unroll
    for (int fo = 0; fo < 4; ++fo)
      #pragma unroll
      for (int fl = 0; fl < 2; ++fl) p[fo][fl] = (f32x4v){0.f,0.f,0.f,0.f};
    #pragma unroll
    for (int k0 = 0; k0 < HH; k0 += 32) {
      bf16x8v a[4], bb[2];
      #pragma unroll
      for (int fo = 0; fo < 4; ++fo)
        a[fo] = *reinterpret_cast<const bf16x8v*>(W1b + (size_t)(o0+fo*16+row16)*HH + k0 + kg*8);
      #pragma unroll
      for (int fl = 0; fl < 2; ++fl)
        bb[fl] = *reinterpret_cast<const bf16x8v*>(&Tg[fl*16+row16][k0 + kg*8]);
      #pragma unroll
      for (int fo = 0; fo < 4; ++fo)
        #pragma unroll
        for (int fl = 0; fl < 2; ++fl)
          p[fo][fl] = __builtin_amdgcn_mfma_f32_16x16x32_bf16(a[fo], bb[fl], p[fo][fl], 0,0,0);
    }
    #pragma unroll
    for (int fo = 0; fo < 4; ++fo)
      #pragma unroll
      for (int fl = 0; fl < 2; ++fl) {
        int l = fl*16 + row16;
        #pragma unroll
        for (int r = 0; r < 4; ++r) {
          int o = o0 + fo*16 + kg*4 + r;
          out1[((size_t)(b*HH + o))*LL + l0 + l] = p[fo][fl][r] + bias1[fo][r] + b2f(X[o][l]);
        }
      }
  }
  {
    f32x4v q[4][2];
    #pragma unroll
    for (int fo = 0; fo < 4; ++fo)
      #pragma unroll
      for (int fl = 0; fl < 2; ++fl) q[fo][fl] = (f32x4v){0.f,0.f,0.f,0.f};
    #pragma unroll
    for (int k0 = 0; k0 < HH; k0 += 32) {
      bf16x8v a[4], bb[2];
      #pragma unroll
      for (int fo = 0; fo < 4; ++fo)
        a[fo] = *reinterpret_cast<const bf16x8v*>(W2b + (size_t)(o0+fo*16+row16)*HH + k0 + kg*8);
      #pragma unroll
      for (int fl = 0; fl < 2; ++fl)
        bb[fl] = *reinterpret_cast<const bf16x8v*>(&Tg[fl*16+row16][k0 + kg*8]);
      #pragma unroll
      for (int fo = 0; fo < 4; ++fo)
        #pragma unroll
        for (int fl = 0; fl < 2; ++fl)
          q[fo][fl] = __builtin_amdgcn_mfma_f32_16x16x32_bf16(a[fo], bb[fl], q[fo][fl], 0,0,0);
    }
    #pragma unroll
    for (int fo = 0; fo < 4; ++fo)
      #pragma unroll
      for (int fl = 0; fl < 2; ++fl) {
        int l = fl*16 + row16;
        #pragma unroll
        for (int r = 0; r < 4; ++r) {
          int o = o0 + fo*16 + kg*4 + r;
          out2[((size_t)(b*HH + o))*LL + l0 + l] = q[fo][fl][r] + bias2[fo][r];
        }
      }
  }
}

extern "C" void kernel_launch(void* const* d_in, const int* in_sizes, int n_in,
                              void* d_out, int out_size, void* d_ws, size_t ws_size,
                              hipStream_t stream) {
  const float* x    = (const float*)d_in[0];
  const float* t    = (const float*)d_in[1];
  const float* W_t  = (const float*)d_in[2];
  const float* b_t  = (const float*)d_in[3];
  const float* ln_g = (const float*)d_in[4];
  const float* ln_b = (const float*)d_in[5];
  const float* log_dt = (const float*)d_in[6];
  const float* log_A_real = (const float*)d_in[7];
  const float* A_imag = (const float*)d_in[8];
  const float* B_re = (const float*)d_in[9];
  const float* B_im = (const float*)d_in[10];
  const float* C_re = (const float*)d_in[11];
  const float* C_im = (const float*)d_in[12];
  const float* Dp   = (const float*)d_in[13];
  const float* W_out= (const float*)d_in[14];
  const float* b_out= (const float*)d_in[15];
  const float* W1   = (const float*)d_in[16];
  const float* b1   = (const float*)d_in[17];
  const float* W2   = (const float*)d_in[18];
  const float* b2   = (const float*)d_in[19];

  float* out1 = (float*)d_out;
  float* out2 = out1 + ELEMS;

  // ws: P(4HN) | tt | rT(2HN) | zb | Mc | Vc | Uc | g | Wob | W1b | W2b | xt
  float* P    = (float*)d_ws;
  float* tt   = P + 4*HN;
  float* rT   = tt + BB*HH;
  ushort* zb  = (ushort*)(rT + 2*HN);
  ushort* Mc  = zb + ELEMS;
  ushort* Vc  = Mc + (size_t)4096*HH;
  ushort* Uc  = Vc + (size_t)16384*HH;
  ushort* g   = Uc + (size_t)16384*HH;
  ushort* Wob = g + ELEMS;
  ushort* W1b = Wob + HH*HH;
  ushort* W2b = W1b + HH*HH;
  ushort* xt  = W2b + HH*HH;

  init_kernel<<<BB + 192 + HH, 256, 0, stream>>>(
      t, W_t, b_t, log_dt, log_A_real, A_imag, B_re, B_im, C_re, C_im, Dp,
      W_out, W1, W2, P, tt, Wob, W1b, W2b, Mc, Vc, Uc, rT);
  lnz_kernel<<<BB*64, 256, 0, stream>>>(x, tt, ln_g, ln_b, zb, xt);
  ssm_all<<<HH, 512, 0, stream>>>(zb, Vc, Mc, Uc, P, rT, g);
  fused_out<<<dim3(LL/32, BB), 256, 0, stream>>>(g, Wob, W1b, W2b, b_out, b1, b2,
                                                 xt, tt, out1, out2);
}